// Round 4
// baseline (1691.709 us; speedup 1.0000x reference)
//
#include <hip/hip_runtime.h>
#include <math.h>

// Problem constants
#define BB 16
#define LL 5000
#define DIN 12
#define HH 256
#define NN 32
#define NLAYER 4
#define LC 125               // chunk length
#define NCH 40               // chunks per batch row (40*125 = 5000)
#define COLS (BB*NCH)        // 640 chunk-columns; col = b*40+c, row = col*125+t
#define NROWS (BB*LL)        // 80000 token rows
#define KU 192               // Ubig inner dim: 128 (tau, padded) + 64 (state re/im)

typedef __attribute__((ext_vector_type(8))) _Float16 f16x8;
typedef __attribute__((ext_vector_type(4))) float f32x4;

// fast tanh-GELU (matches jax.nn.gelu approximate): a*sigmoid(2*inner)
__device__ __forceinline__ float fast_gelu(float a) {
  float z = fmaf(0.0713548163f * a, a * a, 1.5957691216f * a);
  float e = __expf(-z);
  return a * __builtin_amdgcn_rcpf(1.0f + e);
}

__device__ __forceinline__ unsigned pk2h(float a, float b) {
  union { _Float16 h[2]; unsigned u; } x;
  x.h[0] = (_Float16)a; x.h[1] = (_Float16)b;
  return x.u;
}

__device__ __forceinline__ float2 upk2(unsigned u) {
  union { unsigned u; _Float16 h[2]; } x;
  x.u = u;
  return make_float2((float)x.h[0], (float)x.h[1]);
}

// ---------------------------------------------------------------------------
// Per-layer precompute of the chunked-convolution operators (fp16):
//   Tc[h][t=0..127][k=0..191] : k<128 -> Toeplitz K[t-k] (+D on diag); k>=128 ->
//                               boundary Bnd[t][n2] = {Re, -Im}(Ct2_n * w_n^{t+1})
//   V[h][n2=0..63][tau=0..127]: {Re,Im}(w_n^{124-tau})   (chunk-state operator)
//   WLc[h][n2]                : w^125 (combine step)
// ---------------------------------------------------------------------------
__global__ __launch_bounds__(128) void paramT_kernel(
    const float* __restrict__ log_dt, const float* __restrict__ logA_re,
    const float* __restrict__ A_im, const float* __restrict__ Cp,
    const float* __restrict__ Dv, int l,
    _Float16* __restrict__ Tc, _Float16* __restrict__ V, float* __restrict__ WLc) {
  int h = blockIdx.x;
  int t = threadIdx.x;
  __shared__ float s_are[NN], s_aim[NN], s_cre[NN], s_cim[NN];
  __shared__ float s_K[LC];
  if (t < NN) {
    int n = t;
    int idx = (l * HH + h) * NN + n;
    float dt = expf(log_dt[l * HH + h]);
    float Are = -expf(logA_re[idx]);
    float Aim = A_im[idx];
    float are = Are * dt, aim = Aim * dt;
    float e = expf(are);
    float wre = e * cosf(aim), wim = e * sinf(aim);
    float cr = Cp[2 * idx], ci = Cp[2 * idx + 1];
    float nre = wre - 1.0f, nim = wim;
    float tre = cr * nre - ci * nim;
    float tim = cr * nim + ci * nre;
    float inv = 1.0f / (Are * Are + Aim * Aim);
    s_are[n] = are; s_aim[n] = aim;
    s_cre[n] = 2.0f * (tre * Are + tim * Aim) * inv;
    s_cim[n] = 2.0f * (tim * Are - tre * Aim) * inv;
    float eL = expf(125.0f * are);
    float ang = 125.0f * aim;
    WLc[h * 64 + 2 * n] = eL * cosf(ang);
    WLc[h * 64 + 2 * n + 1] = eL * sinf(ang);
  }
  __syncthreads();
  if (t < LC) {
    float ksum = 0.0f;
    unsigned* brow = (unsigned*)(Tc + ((size_t)h * 128 + t) * KU + 128);
    for (int n = 0; n < NN; n++) {
      float are = s_are[n], aim = s_aim[n];
      float cre = s_cre[n], cim = s_cim[n];
      float ft = (float)t;
      float E = expf(are * ft);
      float a = aim * ft;
      float wtre = E * cosf(a), wtim = E * sinf(a);        // w^t
      ksum = fmaf(cre, wtre, ksum);
      ksum = fmaf(-cim, wtim, ksum);
      float ew = expf(are);
      float wre = ew * cosf(aim), wim = ew * sinf(aim);    // w
      float wpre = wtre * wre - wtim * wim;                // w^{t+1}
      float wpim = wtre * wim + wtim * wre;
      float bre = cre * wpre - cim * wpim;                 // Re(Ct2*w^{t+1})
      float bim = -(cre * wpim + cim * wpre);              // -Im(Ct2*w^{t+1})
      brow[n] = pk2h(bre, bim);
      float fk = (float)(124 - t);
      float E2 = expf(are * fk);
      float a2 = aim * fk;
      V[((size_t)h * 64 + 2 * n) * 128 + t] = (_Float16)(E2 * cosf(a2));
      V[((size_t)h * 64 + 2 * n + 1) * 128 + t] = (_Float16)(E2 * sinf(a2));
    }
    s_K[t] = ksum;
  } else {
    for (int n2 = 0; n2 < 64; n2++) V[((size_t)h * 64 + n2) * 128 + t] = (_Float16)0.0f;
    unsigned* brow = (unsigned*)(Tc + ((size_t)h * 128 + t) * KU + 128);
    for (int q = 0; q < 32; q++) brow[q] = 0u;
  }
  __syncthreads();
  float D = Dv[l * HH + h];
  unsigned* row = (unsigned*)(Tc + ((size_t)h * 128 + t) * KU);
  for (int q = 0; q < 64; q++) {  // tau = 2q, 2q+1
    float v0 = 0.0f, v1 = 0.0f;
    if (t < LC) {
      int d0 = t - 2 * q;
      int d1 = d0 - 1;
      if (d0 >= 0) v0 = s_K[d0] + (d0 == 0 ? D : 0.0f);
      if (d1 >= 0) v1 = s_K[d1] + (d1 == 0 ? D : 0.0f);
    }
    row[q] = pk2h(v0, v1);
  }
}

// ---------------------------------------------------------------------------
// W_glu transpose+cast to fp16: Wt[l][col(512)][k(256)]
// ---------------------------------------------------------------------------
__global__ __launch_bounds__(256) void wt_kernel(
    const float* __restrict__ W, _Float16* __restrict__ Wt) {
  int gid = blockIdx.x * 256 + threadIdx.x;   // NLAYER*512 = 2048
  int l = gid >> 9, col = gid & 511;
  const float* w = W + (size_t)l * HH * 512 + col;
  _Float16* o = Wt + (size_t)gid * HH;
  for (int k = 0; k < HH; k++) o[k] = (_Float16)(w[(size_t)k * 512]);
}

// ---------------------------------------------------------------------------
// Input projection -> fp16 stream. Thread = h-pair, 2 rows per block pass.
// ---------------------------------------------------------------------------
__global__ __launch_bounds__(256) void proj_kernel(
    const float* __restrict__ x, const float* __restrict__ Win,
    const float* __restrict__ bin, _Float16* __restrict__ X) {
  int tp = threadIdx.x & 127, rs = threadIdx.x >> 7;
  int h0 = 2 * tp;
  float w0[DIN], w1[DIN];
#pragma unroll
  for (int k = 0; k < DIN; k++) {
    w0[k] = Win[k * HH + h0];
    w1[k] = Win[k * HH + h0 + 1];
  }
  float b0 = bin[h0], b1 = bin[h0 + 1];
  for (int row = blockIdx.x * 2 + rs; row < NROWS; row += gridDim.x * 2) {
    float a0 = b0, a1 = b1;
#pragma unroll
    for (int k = 0; k < DIN; k++) {
      float xv = x[(size_t)row * DIN + k];
      a0 = fmaf(xv, w0[k], a0);
      a1 = fmaf(xv, w1[k], a1);
    }
    *(unsigned*)(X + (size_t)row * HH + h0) = pk2h(a0, a1);
  }
}

// ---------------------------------------------------------------------------
// Final LayerNorm: fp16 stream in, f32 out. One row per wave.
// ---------------------------------------------------------------------------
__global__ __launch_bounds__(256) void ln_kernel(
    const _Float16* __restrict__ in, float* __restrict__ out,
    const float* __restrict__ g, const float* __restrict__ b) {
  int wave = threadIdx.x >> 6, lane = threadIdx.x & 63;
  int row = blockIdx.x * 4 + wave;
  uint2 pv = *(const uint2*)(in + (size_t)row * HH + 4 * lane);
  float2 v01 = upk2(pv.x), v23 = upk2(pv.y);
  float s = v01.x + v01.y + v23.x + v23.y;
  float q = v01.x * v01.x + v01.y * v01.y + v23.x * v23.x + v23.y * v23.y;
#pragma unroll
  for (int m = 1; m < 64; m <<= 1) { s += __shfl_xor(s, m); q += __shfl_xor(q, m); }
  float mean = s * (1.0f / HH);
  float var = q * (1.0f / HH) - mean * mean;
  float rstd = rsqrtf(var + 1e-5f);
  float4 gg = ((const float4*)g)[lane];
  float4 bb = ((const float4*)b)[lane];
  float4 o;
  o.x = (v01.x - mean) * rstd * gg.x + bb.x;
  o.y = (v01.y - mean) * rstd * gg.y + bb.y;
  o.z = (v23.x - mean) * rstd * gg.z + bb.z;
  o.w = (v23.y - mean) * rstd * gg.w + bb.w;
  ((float4*)(out + (size_t)row * HH))[lane] = o;
}

// ---------------------------------------------------------------------------
// Per-layer LN (in place on fp16 stream: x -> z) fused with transposed fp16
// export U[h][col][tau] for tau=0..127 (125..127 zero). One block per col.
// ---------------------------------------------------------------------------
__global__ __launch_bounds__(256) void lnU_kernel(
    _Float16* __restrict__ stream, _Float16* __restrict__ U,
    const float* __restrict__ g, const float* __restrict__ b) {
  __shared__ unsigned short Ut[128][260];   // [tau][h], padded stride
  int col = blockIdx.x;
  int wave = threadIdx.x >> 6, lane = threadIdx.x & 63;
  for (int idx = threadIdx.x; idx < 3 * 260; idx += 256) {
    int r = idx / 260;
    Ut[125 + r][idx - r * 260] = 0;
  }
  float4 gg = ((const float4*)g)[lane];
  float4 bb = ((const float4*)b)[lane];
  size_t base = (size_t)col * LC * HH;
  for (int it = 0; it < 32; it++) {
    int tau = it * 4 + wave;
    if (tau < LC) {
      uint2 pv = *(const uint2*)(stream + base + (size_t)tau * HH + 4 * lane);
      float2 v01 = upk2(pv.x), v23 = upk2(pv.y);
      float s = v01.x + v01.y + v23.x + v23.y;
      float q = v01.x * v01.x + v01.y * v01.y + v23.x * v23.x + v23.y * v23.y;
#pragma unroll
      for (int m = 1; m < 64; m <<= 1) { s += __shfl_xor(s, m); q += __shfl_xor(q, m); }
      float mean = s * (1.0f / HH);
      float var = q * (1.0f / HH) - mean * mean;
      float rstd = rsqrtf(var + 1e-5f);
      float o0 = (v01.x - mean) * rstd * gg.x + bb.x;
      float o1 = (v01.y - mean) * rstd * gg.y + bb.y;
      float o2 = (v23.x - mean) * rstd * gg.z + bb.z;
      float o3 = (v23.y - mean) * rstd * gg.w + bb.w;
      uint2 p;
      p.x = pk2h(o0, o1);
      p.y = pk2h(o2, o3);
      *(uint2*)(stream + base + (size_t)tau * HH + 4 * lane) = p;  // residual = z
      *(uint2*)&Ut[tau][4 * lane] = p;
    }
  }
  __syncthreads();
  // export transposed: per h, 64 u32 words (128 tau)
  for (int rep = 0; rep < 8; rep++) {
    int linear = rep * 256 + threadIdx.x;
    int h = linear >> 3, ub = linear & 7;
    unsigned* dst = (unsigned*)(U + ((size_t)h * COLS + col) * KU);
#pragma unroll
    for (int s2 = 0; s2 < 8; s2++) {
      int u = ub + s2 * 8;
      unsigned val = (unsigned)Ut[2 * u][h] | ((unsigned)Ut[2 * u + 1][h] << 16);
      dst[u] = val;
    }
  }
}

// ---------------------------------------------------------------------------
// gemmA: per h, P[n2][col] = V[h](64x128) @ U[h](128 x col). P stored f32
// transposed: P[h][col][n2]. Grid x=colblock, y=h (L2 reuse of V[h]).
// ---------------------------------------------------------------------------
__global__ __launch_bounds__(256) void gemmA_kernel(
    const _Float16* __restrict__ V, const _Float16* __restrict__ U,
    float* __restrict__ P) {
  __shared__ _Float16 As[64 * 72];
  __shared__ _Float16 Bs[64 * 72];
  int h = blockIdx.y, c0 = blockIdx.x * 64;
  int t = threadIdx.x;
  int w = t >> 6, lane = t & 63, lr = lane & 15, quad = lane >> 4;
  int mh = w & 1, nh = w >> 1;
  f32x4 acc[2][2];
#pragma unroll
  for (int i = 0; i < 2; i++)
#pragma unroll
    for (int j = 0; j < 2; j++) acc[i][j] = (f32x4)(0.0f);

  for (int kt = 0; kt < 128; kt += 64) {
#pragma unroll
    for (int i = 0; i < 2; i++) {
      int idx = t + 256 * i;
      int m = idx >> 3, q = idx & 7;
      *(uint4*)&As[m * 72 + q * 8] =
          *(const uint4*)(V + ((size_t)h * 64 + m) * 128 + kt + q * 8);
      *(uint4*)&Bs[m * 72 + q * 8] =
          *(const uint4*)(U + ((size_t)h * COLS + c0 + m) * KU + kt + q * 8);
    }
    __syncthreads();
#pragma unroll
    for (int ks = 0; ks < 2; ks++) {
      f16x8 af[2], bf[2];
#pragma unroll
      for (int i = 0; i < 2; i++)
        af[i] = *(const f16x8*)&As[(mh * 32 + i * 16 + lr) * 72 + ks * 32 + quad * 8];
#pragma unroll
      for (int j = 0; j < 2; j++)
        bf[j] = *(const f16x8*)&Bs[(nh * 32 + j * 16 + lr) * 72 + ks * 32 + quad * 8];
#pragma unroll
      for (int i = 0; i < 2; i++)
#pragma unroll
        for (int j = 0; j < 2; j++)
          acc[i][j] = __builtin_amdgcn_mfma_f32_16x16x32_f16(af[i], bf[j], acc[i][j], 0, 0, 0);
    }
    __syncthreads();
  }
#pragma unroll
  for (int i = 0; i < 2; i++) {
#pragma unroll
    for (int j = 0; j < 2; j++) {
      int n2 = mh * 32 + i * 16 + quad * 4;
      int col = c0 + nh * 32 + j * 16 + lr;
      *(f32x4*)(P + ((size_t)h * COLS + col) * 64 + n2) = acc[i][j];
    }
  }
}

// ---------------------------------------------------------------------------
// combine: serial scan over chunks per (b,h,n): carry' = w^125*carry + P[c].
// Writes exclusive-prefix carry (fp16) into Ubig[h][col][128+n2].
// ---------------------------------------------------------------------------
__global__ __launch_bounds__(256) void combine_kernel(
    const float* __restrict__ P, _Float16* __restrict__ U,
    const float* __restrict__ WLc) {
  int h = blockIdx.x >> 1;
  int bh = blockIdx.x & 1;
  int n = threadIdx.x & 31;
  int b = bh * 8 + (threadIdx.x >> 5);
  float wre = WLc[h * 64 + 2 * n], wim = WLc[h * 64 + 2 * n + 1];
  const float* p = P + ((size_t)h * COLS + (size_t)b * NCH) * 64 + 2 * n;
  _Float16* u = U + ((size_t)h * COLS + (size_t)b * NCH) * KU + 128 + 2 * n;
  float cre = 0.0f, cim = 0.0f;
#pragma unroll 4
  for (int c = 0; c < NCH; c++) {
    float2 v = *(const float2*)(p + (size_t)c * 64);
    *(unsigned*)(u + (size_t)c * KU) = pk2h(cre, cim);
    float nre = fmaf(wre, cre, v.x) - wim * cim;
    float nim = fmaf(wre, cim, v.y) + wim * cre;
    cre = nre; cim = nim;
  }
}

// ---------------------------------------------------------------------------
// gemmC: per h, Y[t=128][col] = Tc[h](128x192) @ [u; s0](192 x col), fused
// GELU, fp16 out Yt[h][col][t]. T14 register prefetch of next K-tile.
// ---------------------------------------------------------------------------
__global__ __launch_bounds__(256) void gemmC_kernel(
    const _Float16* __restrict__ Tc, const _Float16* __restrict__ U,
    _Float16* __restrict__ Yt) {
  __shared__ _Float16 As[128 * 72];
  __shared__ _Float16 Bs[64 * 72];
  int h = blockIdx.y, c0 = blockIdx.x * 64;
  int t = threadIdx.x;
  int w = t >> 6, lane = t & 63, lr = lane & 15, quad = lane >> 4;
  f32x4 acc[2][4];
#pragma unroll
  for (int i = 0; i < 2; i++)
#pragma unroll
    for (int j = 0; j < 4; j++) acc[i][j] = (f32x4)(0.0f);

  uint4 pa[4], pb[2];
  auto loadA = [&](int kt) {
#pragma unroll
    for (int i = 0; i < 4; i++) {
      int idx = t + 256 * i;
      int m = idx >> 3, q = idx & 7;
      pa[i] = *(const uint4*)(Tc + ((size_t)h * 128 + m) * KU + kt + q * 8);
    }
  };
  auto loadB = [&](int kt) {
#pragma unroll
    for (int i = 0; i < 2; i++) {
      int idx = t + 256 * i;
      int jj = idx >> 3, q = idx & 7;
      pb[i] = *(const uint4*)(U + ((size_t)h * COLS + c0 + jj) * KU + kt + q * 8);
    }
  };
  loadA(0); loadB(0);

  for (int it = 0; it < 3; it++) {
#pragma unroll
    for (int i = 0; i < 4; i++) {
      int idx = t + 256 * i;
      int m = idx >> 3, q = idx & 7;
      *(uint4*)&As[m * 72 + q * 8] = pa[i];
    }
#pragma unroll
    for (int i = 0; i < 2; i++) {
      int idx = t + 256 * i;
      int jj = idx >> 3, q = idx & 7;
      *(uint4*)&Bs[jj * 72 + q * 8] = pb[i];
    }
    __syncthreads();
    if (it < 2) { loadA(64 * (it + 1)); loadB(64 * (it + 1)); }
#pragma unroll
    for (int ks = 0; ks < 2; ks++) {
      f16x8 af[2], bf[4];
#pragma unroll
      for (int i = 0; i < 2; i++)
        af[i] = *(const f16x8*)&As[(w * 32 + i * 16 + lr) * 72 + ks * 32 + quad * 8];
#pragma unroll
      for (int j = 0; j < 4; j++)
        bf[j] = *(const f16x8*)&Bs[(j * 16 + lr) * 72 + ks * 32 + quad * 8];
#pragma unroll
      for (int i = 0; i < 2; i++)
#pragma unroll
        for (int j = 0; j < 4; j++)
          acc[i][j] = __builtin_amdgcn_mfma_f32_16x16x32_f16(af[i], bf[j], acc[i][j], 0, 0, 0);
    }
    if (it < 2) __syncthreads();
  }
#pragma unroll
  for (int i = 0; i < 2; i++) {
#pragma unroll
    for (int j = 0; j < 4; j++) {
      int tb = w * 32 + i * 16 + quad * 4;
      int col = c0 + j * 16 + lr;
      f32x4 a = acc[i][j];
      uint2 r;
      r.x = pk2h(fast_gelu(a[0]), fast_gelu(a[1]));
      r.y = pk2h(fast_gelu(a[2]), fast_gelu(a[3]));
      *(uint2*)(Yt + ((size_t)h * COLS + col) * 128 + tb) = r;
    }
  }
}

// ---------------------------------------------------------------------------
// Yt[h][col][128] -> row-major Y[row=col*125+t][h] (fp16), LDS-tiled transpose.
// ---------------------------------------------------------------------------
__global__ __launch_bounds__(256) void ytr_kernel(
    const _Float16* __restrict__ Yt, _Float16* __restrict__ Y) {
  __shared__ unsigned short Yl[128][136];
  int col = blockIdx.x, hh = blockIdx.y;
#pragma unroll
  for (int rep = 0; rep < 8; rep++) {
    int cid = rep * 256 + threadIdx.x;
    int hl = cid >> 4, q = cid & 15;
    *(uint4*)&Yl[hl][q * 8] =
        *(const uint4*)(Yt + ((size_t)(hh * 128 + hl) * COLS + col) * 128 + q * 8);
  }
  __syncthreads();
#pragma unroll
  for (int rep = 0; rep < 8; rep++) {
    int sid = rep * 256 + threadIdx.x;
    int tl = sid >> 4, uq = sid & 15;
    if (tl < LC) {
      uint4 r;
      unsigned v[4];
#pragma unroll
      for (int k = 0; k < 4; k++)
        v[k] = (unsigned)Yl[uq * 8 + 2 * k][tl] | ((unsigned)Yl[uq * 8 + 2 * k + 1][tl] << 16);
      r.x = v[0]; r.y = v[1]; r.z = v[2]; r.w = v[3];
      *(uint4*)(Y + ((size_t)col * LC + tl) * HH + hh * 128 + uq * 8) = r;
    }
  }
}

// ---------------------------------------------------------------------------
// GLU FFN via fp16 MFMA, M=128 tile, T14 register prefetch. The stream holds
// z (post-LN, written by lnU); update in place: X = g1*sigmoid(g2) + z.
// Epilogue stages g1*sig in LDS (f32, reusing As/Bs via dynamic smem) then
// one fully-coalesced pass: uint4 z-reads + uint4 fp16 stores (no write amp).
// ---------------------------------------------------------------------------
__global__ __launch_bounds__(256, 4) void gemm_glu_mfma(
    const _Float16* __restrict__ Y, const _Float16* __restrict__ Wt,
    const float* __restrict__ bg, _Float16* Xio) {
  extern __shared__ char smem[];
  _Float16* As = (_Float16*)smem;        // 128*72 fp16 = 18432 B
  _Float16* Bs = As + 128 * 72;          // 128*72 fp16 = 18432 B
  float* gl = (float*)smem;              // epilogue reuse: 128*68 f32 = 34816 B
  int t = threadIdx.x;
  int r0 = blockIdx.x * 128, c0 = blockIdx.y * 64;
  int w = t >> 6, lane = t & 63;
  int lr = lane & 15, quad = lane >> 4;
  int rh = w & 1, ch = w >> 1;
  f32x4 acc[4][4];
#pragma unroll
  for (int i = 0; i < 4; i++)
#pragma unroll
    for (int j = 0; j < 4; j++) acc[i][j] = (f32x4)(0.0f);

  int jb[4] = {ch * 32, ch * 32 + 16, 64 + ch * 32, 80 + ch * 32};

  uint4 pa[4], pb[4];
  auto loadA = [&](int kt) {
#pragma unroll
    for (int i = 0; i < 4; i++) {
      int idx = t + 256 * i;
      int m = idx >> 3, q = idx & 7;
      pa[i] = *(const uint4*)(Y + (size_t)(r0 + m) * HH + kt + q * 8);
    }
  };
  auto loadB = [&](int kt) {
#pragma unroll
    for (int i = 0; i < 4; i++) {
      int idx = t + 256 * i;
      int jj = idx >> 3, q = idx & 7;
      int colw = (jj < 64) ? (c0 + jj) : (192 + c0 + jj);
      pb[i] = *(const uint4*)(Wt + (size_t)colw * HH + kt + q * 8);
    }
  };
  loadA(0); loadB(0);

  for (int it = 0; it < 4; it++) {
#pragma unroll
    for (int i = 0; i < 4; i++) {
      int idx = t + 256 * i;
      int m = idx >> 3, q = idx & 7;
      *(uint4*)&As[m * 72 + q * 8] = pa[i];
    }
#pragma unroll
    for (int i = 0; i < 4; i++) {
      int idx = t + 256 * i;
      int jj = idx >> 3, q = idx & 7;
      *(uint4*)&Bs[jj * 72 + q * 8] = pb[i];
    }
    __syncthreads();
    if (it < 3) { loadA(64 * (it + 1)); loadB(64 * (it + 1)); }
#pragma unroll
    for (int ks = 0; ks < 2; ks++) {
      f16x8 af[4], bf[4];
#pragma unroll
      for (int i = 0; i < 4; i++)
        af[i] = *(const f16x8*)&As[(rh * 64 + i * 16 + lr) * 72 + ks * 32 + quad * 8];
#pragma unroll
      for (int j = 0; j < 4; j++)
        bf[j] = *(const f16x8*)&Bs[(jb[j] + lr) * 72 + ks * 32 + quad * 8];
#pragma unroll
      for (int i = 0; i < 4; i++)
#pragma unroll
        for (int j = 0; j < 4; j++)
          acc[i][j] = __builtin_amdgcn_mfma_f32_16x16x32_f16(af[i], bf[j], acc[i][j], 0, 0, 0);
    }
    if (it < 3) __syncthreads();
  }
  __syncthreads();  // all waves done reading As/Bs before gl overwrite

  // Stage g = g1*sigmoid(g2) into gl[128][68] (f32)
#pragma unroll
  for (int i = 0; i < 4; i++) {
#pragma unroll
    for (int r = 0; r < 4; r++) {
      int rowl = rh * 64 + i * 16 + quad * 4 + r;
#pragma unroll
      for (int jp = 0; jp < 2; jp++) {
        int hl = ch * 32 + jp * 16 + lr;
        int h = c0 + hl;
        float g1 = acc[i][jp][r] + bg[h];
        float g2 = acc[i][jp + 2][r] + bg[256 + h];
        float sig = __builtin_amdgcn_rcpf(1.0f + __expf(-g2));
        gl[rowl * 68 + hl] = g1 * sig;
      }
    }
  }
  __syncthreads();

  // Coalesced residual-add pass: 1024 chunks of (row, 8 h-values)
#pragma unroll
  for (int rep = 0; rep < 4; rep++) {
    int lin = rep * 256 + t;
    int rowl = lin >> 3, hc = lin & 7;
    int row = r0 + rowl;
    int hb = c0 + hc * 8;
    uint4 zv = *(const uint4*)(Xio + (size_t)row * HH + hb);
    float2 z01 = upk2(zv.x), z23 = upk2(zv.y), z45 = upk2(zv.z), z67 = upk2(zv.w);
    const float* gp = &gl[rowl * 68 + hc * 8];
    uint4 r;
    r.x = pk2h(gp[0] + z01.x, gp[1] + z01.y);
    r.y = pk2h(gp[2] + z23.x, gp[3] + z23.y);
    r.z = pk2h(gp[4] + z45.x, gp[5] + z45.y);
    r.w = pk2h(gp[6] + z67.x, gp[7] + z67.y);
    *(uint4*)(Xio + (size_t)row * HH + hb) = r;
  }
}

// ---------------------------------------------------------------------------
extern "C" void kernel_launch(void* const* d_in, const int* in_sizes, int n_in,
                              void* d_out, int out_size, void* d_ws, size_t ws_size,
                              hipStream_t stream) {
  const float* x      = (const float*)d_in[0];
  const float* Win    = (const float*)d_in[1];
  const float* bin    = (const float*)d_in[2];
  const float* ln_g   = (const float*)d_in[3];
  const float* ln_b   = (const float*)d_in[4];
  const float* log_dt = (const float*)d_in[5];
  const float* logA   = (const float*)d_in[6];
  const float* A_im   = (const float*)d_in[7];
  const float* Cp     = (const float*)d_in[8];
  const float* Dv     = (const float*)d_in[9];
  const float* Wglu   = (const float*)d_in[10];
  const float* bglu   = (const float*)d_in[11];
  const float* fn_g   = (const float*)d_in[12];
  const float* fn_b   = (const float*)d_in[13];
  float* out = (float*)d_out;
  float* ws = (float*)d_ws;

  // Workspace layout (float units)
  _Float16* Xs = (_Float16*)ws;                        // fp16 token stream (z/x in place)
  float* Pf = ws + (size_t)NROWS * HH;                 // f32 chunk states
  _Float16* Tc = (_Float16*)(Pf + (size_t)HH * COLS * 64);
  _Float16* V  = Tc + (size_t)HH * 128 * KU;
  _Float16* U  = V + (size_t)HH * 64 * 128;
  _Float16* Wt = U + (size_t)HH * COLS * KU;
  float* WLc = (float*)(Wt + (size_t)NLAYER * 512 * HH);
  _Float16* Yt = (_Float16*)Pf;                        // fp16 alias (disjoint lifetime)
  _Float16* Y  = (_Float16*)d_out;                     // row-major activations for GLU

  wt_kernel<<<(NLAYER * 512) / 256, 256, 0, stream>>>(Wglu, Wt);
  proj_kernel<<<2048, 256, 0, stream>>>(x, Win, bin, Xs);

  for (int l = 0; l < NLAYER; l++) {
    paramT_kernel<<<HH, 128, 0, stream>>>(log_dt, logA, A_im, Cp, Dv, l, Tc, V, WLc);
    lnU_kernel<<<COLS, 256, 0, stream>>>(Xs, U, ln_g + l * HH, ln_b + l * HH);
    gemmA_kernel<<<dim3(COLS / 64, HH), 256, 0, stream>>>(V, U, Pf);
    combine_kernel<<<HH * 2, 256, 0, stream>>>(Pf, U, WLc);
    gemmC_kernel<<<dim3(COLS / 64, HH), 256, 0, stream>>>(Tc, U, Yt);
    ytr_kernel<<<dim3(COLS, 2), 256, 0, stream>>>(Yt, Y);
    gemm_glu_mfma<<<dim3(NROWS / 128, 4), 256, 36864, stream>>>(
        Y, Wt + (size_t)l * 512 * HH, bglu + (size_t)l * 2 * HH, Xs);
  }
  ln_kernel<<<NROWS / 4, 256, 0, stream>>>(Xs, out, fn_g, fn_b);
}

// Round 5
// 1486.450 us; speedup vs baseline: 1.1381x; 1.1381x over previous
//
#include <hip/hip_runtime.h>
#include <math.h>

// Problem constants
#define BB 16
#define LL 5000
#define DIN 12
#define HH 256
#define NN 32
#define NLAYER 4
#define LC 125               // chunk length
#define NCH 40               // chunks per batch row (40*125 = 5000)
#define COLS (BB*NCH)        // 640 chunk-columns; col = b*40+c, row = col*125+t
#define NROWS (BB*LL)        // 80000 token rows
#define KU 192               // Ubig inner dim: 128 (tau, padded) + 64 (state re/im)

typedef __attribute__((ext_vector_type(8))) _Float16 f16x8;
typedef __attribute__((ext_vector_type(4))) float f32x4;

// fast tanh-GELU (matches jax.nn.gelu approximate): a*sigmoid(2*inner)
__device__ __forceinline__ float fast_gelu(float a) {
  float z = fmaf(0.0713548163f * a, a * a, 1.5957691216f * a);
  float e = __expf(-z);
  return a * __builtin_amdgcn_rcpf(1.0f + e);
}

__device__ __forceinline__ unsigned pk2h(float a, float b) {
  union { _Float16 h[2]; unsigned u; } x;
  x.h[0] = (_Float16)a; x.h[1] = (_Float16)b;
  return x.u;
}

__device__ __forceinline__ float2 upk2(unsigned u) {
  union { unsigned u; _Float16 h[2]; } x;
  x.u = u;
  return make_float2((float)x.h[0], (float)x.h[1]);
}

// ---------------------------------------------------------------------------
// Per-layer precompute of the chunked-convolution operators (fp16):
//   Tc[h][t=0..127][k=0..191] : k<128 -> Toeplitz K[t-k] (+D on diag); k>=128 ->
//                               boundary Bnd[t][n2] = {Re, -Im}(Ct2_n * w_n^{t+1})
//   V[h][n2=0..63][tau=0..127]: {Re,Im}(w_n^{124-tau})   (chunk-state operator)
//   WLc[h][n2]                : w^125 (combine step)
// ---------------------------------------------------------------------------
__global__ __launch_bounds__(128) void paramT_kernel(
    const float* __restrict__ log_dt, const float* __restrict__ logA_re,
    const float* __restrict__ A_im, const float* __restrict__ Cp,
    const float* __restrict__ Dv, int l,
    _Float16* __restrict__ Tc, _Float16* __restrict__ V, float* __restrict__ WLc) {
  int h = blockIdx.x;
  int t = threadIdx.x;
  __shared__ float s_are[NN], s_aim[NN], s_cre[NN], s_cim[NN];
  __shared__ float s_K[LC];
  if (t < NN) {
    int n = t;
    int idx = (l * HH + h) * NN + n;
    float dt = expf(log_dt[l * HH + h]);
    float Are = -expf(logA_re[idx]);
    float Aim = A_im[idx];
    float are = Are * dt, aim = Aim * dt;
    float e = expf(are);
    float wre = e * cosf(aim), wim = e * sinf(aim);
    float cr = Cp[2 * idx], ci = Cp[2 * idx + 1];
    float nre = wre - 1.0f, nim = wim;
    float tre = cr * nre - ci * nim;
    float tim = cr * nim + ci * nre;
    float inv = 1.0f / (Are * Are + Aim * Aim);
    s_are[n] = are; s_aim[n] = aim;
    s_cre[n] = 2.0f * (tre * Are + tim * Aim) * inv;
    s_cim[n] = 2.0f * (tim * Are - tre * Aim) * inv;
    float eL = expf(125.0f * are);
    float ang = 125.0f * aim;
    WLc[h * 64 + 2 * n] = eL * cosf(ang);
    WLc[h * 64 + 2 * n + 1] = eL * sinf(ang);
  }
  __syncthreads();
  if (t < LC) {
    float ksum = 0.0f;
    unsigned* brow = (unsigned*)(Tc + ((size_t)h * 128 + t) * KU + 128);
    for (int n = 0; n < NN; n++) {
      float are = s_are[n], aim = s_aim[n];
      float cre = s_cre[n], cim = s_cim[n];
      float ft = (float)t;
      float E = expf(are * ft);
      float a = aim * ft;
      float wtre = E * cosf(a), wtim = E * sinf(a);        // w^t
      ksum = fmaf(cre, wtre, ksum);
      ksum = fmaf(-cim, wtim, ksum);
      float ew = expf(are);
      float wre = ew * cosf(aim), wim = ew * sinf(aim);    // w
      float wpre = wtre * wre - wtim * wim;                // w^{t+1}
      float wpim = wtre * wim + wtim * wre;
      float bre = cre * wpre - cim * wpim;                 // Re(Ct2*w^{t+1})
      float bim = -(cre * wpim + cim * wpre);              // -Im(Ct2*w^{t+1})
      brow[n] = pk2h(bre, bim);
      float fk = (float)(124 - t);
      float E2 = expf(are * fk);
      float a2 = aim * fk;
      V[((size_t)h * 64 + 2 * n) * 128 + t] = (_Float16)(E2 * cosf(a2));
      V[((size_t)h * 64 + 2 * n + 1) * 128 + t] = (_Float16)(E2 * sinf(a2));
    }
    s_K[t] = ksum;
  } else {
    for (int n2 = 0; n2 < 64; n2++) V[((size_t)h * 64 + n2) * 128 + t] = (_Float16)0.0f;
    unsigned* brow = (unsigned*)(Tc + ((size_t)h * 128 + t) * KU + 128);
    for (int q = 0; q < 32; q++) brow[q] = 0u;
  }
  __syncthreads();
  float D = Dv[l * HH + h];
  unsigned* row = (unsigned*)(Tc + ((size_t)h * 128 + t) * KU);
  for (int q = 0; q < 64; q++) {  // tau = 2q, 2q+1
    float v0 = 0.0f, v1 = 0.0f;
    if (t < LC) {
      int d0 = t - 2 * q;
      int d1 = d0 - 1;
      if (d0 >= 0) v0 = s_K[d0] + (d0 == 0 ? D : 0.0f);
      if (d1 >= 0) v1 = s_K[d1] + (d1 == 0 ? D : 0.0f);
    }
    row[q] = pk2h(v0, v1);
  }
}

// ---------------------------------------------------------------------------
// W_glu transpose+cast to fp16: Wt[l][col(512)][k(256)]
// ---------------------------------------------------------------------------
__global__ __launch_bounds__(256) void wt_kernel(
    const float* __restrict__ W, _Float16* __restrict__ Wt) {
  int gid = blockIdx.x * 256 + threadIdx.x;   // NLAYER*512 = 2048
  int l = gid >> 9, col = gid & 511;
  const float* w = W + (size_t)l * HH * 512 + col;
  _Float16* o = Wt + (size_t)gid * HH;
  for (int k = 0; k < HH; k++) o[k] = (_Float16)(w[(size_t)k * 512]);
}

// ---------------------------------------------------------------------------
// Input projection -> fp16 stream. Thread = h-pair, 2 rows per block pass.
// ---------------------------------------------------------------------------
__global__ __launch_bounds__(256) void proj_kernel(
    const float* __restrict__ x, const float* __restrict__ Win,
    const float* __restrict__ bin, _Float16* __restrict__ X) {
  int tp = threadIdx.x & 127, rs = threadIdx.x >> 7;
  int h0 = 2 * tp;
  float w0[DIN], w1[DIN];
#pragma unroll
  for (int k = 0; k < DIN; k++) {
    w0[k] = Win[k * HH + h0];
    w1[k] = Win[k * HH + h0 + 1];
  }
  float b0 = bin[h0], b1 = bin[h0 + 1];
  for (int row = blockIdx.x * 2 + rs; row < NROWS; row += gridDim.x * 2) {
    float a0 = b0, a1 = b1;
#pragma unroll
    for (int k = 0; k < DIN; k++) {
      float xv = x[(size_t)row * DIN + k];
      a0 = fmaf(xv, w0[k], a0);
      a1 = fmaf(xv, w1[k], a1);
    }
    *(unsigned*)(X + (size_t)row * HH + h0) = pk2h(a0, a1);
  }
}

// ---------------------------------------------------------------------------
// Final LayerNorm: fp16 stream in, f32 out. One row per wave.
// ---------------------------------------------------------------------------
__global__ __launch_bounds__(256) void ln_kernel(
    const _Float16* __restrict__ in, float* __restrict__ out,
    const float* __restrict__ g, const float* __restrict__ b) {
  int wave = threadIdx.x >> 6, lane = threadIdx.x & 63;
  int row = blockIdx.x * 4 + wave;
  uint2 pv = *(const uint2*)(in + (size_t)row * HH + 4 * lane);
  float2 v01 = upk2(pv.x), v23 = upk2(pv.y);
  float s = v01.x + v01.y + v23.x + v23.y;
  float q = v01.x * v01.x + v01.y * v01.y + v23.x * v23.x + v23.y * v23.y;
#pragma unroll
  for (int m = 1; m < 64; m <<= 1) { s += __shfl_xor(s, m); q += __shfl_xor(q, m); }
  float mean = s * (1.0f / HH);
  float var = q * (1.0f / HH) - mean * mean;
  float rstd = rsqrtf(var + 1e-5f);
  float4 gg = ((const float4*)g)[lane];
  float4 bb = ((const float4*)b)[lane];
  float4 o;
  o.x = (v01.x - mean) * rstd * gg.x + bb.x;
  o.y = (v01.y - mean) * rstd * gg.y + bb.y;
  o.z = (v23.x - mean) * rstd * gg.z + bb.z;
  o.w = (v23.y - mean) * rstd * gg.w + bb.w;
  ((float4*)(out + (size_t)row * HH))[lane] = o;
}

// ---------------------------------------------------------------------------
// Per-layer LN (in place on fp16 stream: x -> z) fused with transposed fp16
// export U[h][col][tau] for tau=0..127 (125..127 zero). One block per col.
// ---------------------------------------------------------------------------
__global__ __launch_bounds__(256) void lnU_kernel(
    _Float16* __restrict__ stream, _Float16* __restrict__ U,
    const float* __restrict__ g, const float* __restrict__ b) {
  __shared__ unsigned short Ut[128][260];   // [tau][h], padded stride
  int col = blockIdx.x;
  int wave = threadIdx.x >> 6, lane = threadIdx.x & 63;
  for (int idx = threadIdx.x; idx < 3 * 260; idx += 256) {
    int r = idx / 260;
    Ut[125 + r][idx - r * 260] = 0;
  }
  float4 gg = ((const float4*)g)[lane];
  float4 bb = ((const float4*)b)[lane];
  size_t base = (size_t)col * LC * HH;
  for (int it = 0; it < 32; it++) {
    int tau = it * 4 + wave;
    if (tau < LC) {
      uint2 pv = *(const uint2*)(stream + base + (size_t)tau * HH + 4 * lane);
      float2 v01 = upk2(pv.x), v23 = upk2(pv.y);
      float s = v01.x + v01.y + v23.x + v23.y;
      float q = v01.x * v01.x + v01.y * v01.y + v23.x * v23.x + v23.y * v23.y;
#pragma unroll
      for (int m = 1; m < 64; m <<= 1) { s += __shfl_xor(s, m); q += __shfl_xor(q, m); }
      float mean = s * (1.0f / HH);
      float var = q * (1.0f / HH) - mean * mean;
      float rstd = rsqrtf(var + 1e-5f);
      float o0 = (v01.x - mean) * rstd * gg.x + bb.x;
      float o1 = (v01.y - mean) * rstd * gg.y + bb.y;
      float o2 = (v23.x - mean) * rstd * gg.z + bb.z;
      float o3 = (v23.y - mean) * rstd * gg.w + bb.w;
      uint2 p;
      p.x = pk2h(o0, o1);
      p.y = pk2h(o2, o3);
      *(uint2*)(stream + base + (size_t)tau * HH + 4 * lane) = p;  // residual = z
      *(uint2*)&Ut[tau][4 * lane] = p;
    }
  }
  __syncthreads();
  // export transposed: per h, 64 u32 words (128 tau)
  for (int rep = 0; rep < 8; rep++) {
    int linear = rep * 256 + threadIdx.x;
    int h = linear >> 3, ub = linear & 7;
    unsigned* dst = (unsigned*)(U + ((size_t)h * COLS + col) * KU);
#pragma unroll
    for (int s2 = 0; s2 < 8; s2++) {
      int u = ub + s2 * 8;
      unsigned val = (unsigned)Ut[2 * u][h] | ((unsigned)Ut[2 * u + 1][h] << 16);
      dst[u] = val;
    }
  }
}

// ---------------------------------------------------------------------------
// gemmA: per h, P[n2][col] = V[h](64x128) @ U[h](128 x col). P stored f32
// transposed: P[h][col][n2]. Grid x=colblock, y=h (L2 reuse of V[h]).
// ---------------------------------------------------------------------------
__global__ __launch_bounds__(256) void gemmA_kernel(
    const _Float16* __restrict__ V, const _Float16* __restrict__ U,
    float* __restrict__ P) {
  __shared__ _Float16 As[64 * 72];
  __shared__ _Float16 Bs[64 * 72];
  int h = blockIdx.y, c0 = blockIdx.x * 64;
  int t = threadIdx.x;
  int w = t >> 6, lane = t & 63, lr = lane & 15, quad = lane >> 4;
  int mh = w & 1, nh = w >> 1;
  f32x4 acc[2][2];
#pragma unroll
  for (int i = 0; i < 2; i++)
#pragma unroll
    for (int j = 0; j < 2; j++) acc[i][j] = (f32x4)(0.0f);

  for (int kt = 0; kt < 128; kt += 64) {
#pragma unroll
    for (int i = 0; i < 2; i++) {
      int idx = t + 256 * i;
      int m = idx >> 3, q = idx & 7;
      *(uint4*)&As[m * 72 + q * 8] =
          *(const uint4*)(V + ((size_t)h * 64 + m) * 128 + kt + q * 8);
      *(uint4*)&Bs[m * 72 + q * 8] =
          *(const uint4*)(U + ((size_t)h * COLS + c0 + m) * KU + kt + q * 8);
    }
    __syncthreads();
#pragma unroll
    for (int ks = 0; ks < 2; ks++) {
      f16x8 af[2], bf[2];
#pragma unroll
      for (int i = 0; i < 2; i++)
        af[i] = *(const f16x8*)&As[(mh * 32 + i * 16 + lr) * 72 + ks * 32 + quad * 8];
#pragma unroll
      for (int j = 0; j < 2; j++)
        bf[j] = *(const f16x8*)&Bs[(nh * 32 + j * 16 + lr) * 72 + ks * 32 + quad * 8];
#pragma unroll
      for (int i = 0; i < 2; i++)
#pragma unroll
        for (int j = 0; j < 2; j++)
          acc[i][j] = __builtin_amdgcn_mfma_f32_16x16x32_f16(af[i], bf[j], acc[i][j], 0, 0, 0);
    }
    __syncthreads();
  }
#pragma unroll
  for (int i = 0; i < 2; i++) {
#pragma unroll
    for (int j = 0; j < 2; j++) {
      int n2 = mh * 32 + i * 16 + quad * 4;
      int col = c0 + nh * 32 + j * 16 + lr;
      *(f32x4*)(P + ((size_t)h * COLS + col) * 64 + n2) = acc[i][j];
    }
  }
}

// ---------------------------------------------------------------------------
// combine: serial scan over chunks per (b,h,n): carry' = w^125*carry + P[c].
// Writes exclusive-prefix carry (fp16) into Ubig[h][col][128+n2].
// ---------------------------------------------------------------------------
__global__ __launch_bounds__(256) void combine_kernel(
    const float* __restrict__ P, _Float16* __restrict__ U,
    const float* __restrict__ WLc) {
  int h = blockIdx.x >> 1;
  int bh = blockIdx.x & 1;
  int n = threadIdx.x & 31;
  int b = bh * 8 + (threadIdx.x >> 5);
  float wre = WLc[h * 64 + 2 * n], wim = WLc[h * 64 + 2 * n + 1];
  const float* p = P + ((size_t)h * COLS + (size_t)b * NCH) * 64 + 2 * n;
  _Float16* u = U + ((size_t)h * COLS + (size_t)b * NCH) * KU + 128 + 2 * n;
  float cre = 0.0f, cim = 0.0f;
#pragma unroll 4
  for (int c = 0; c < NCH; c++) {
    float2 v = *(const float2*)(p + (size_t)c * 64);
    *(unsigned*)(u + (size_t)c * KU) = pk2h(cre, cim);
    float nre = fmaf(wre, cre, v.x) - wim * cim;
    float nim = fmaf(wre, cim, v.y) + wim * cre;
    cre = nre; cim = nim;
  }
}

// ---------------------------------------------------------------------------
// gemmC: per h, Y[t=128][col] = Tc[h](128x192) @ [u; s0](192 x col), fused
// GELU, fp16 out Yt[h][col][t]. T14 register prefetch of next K-tile.
// ---------------------------------------------------------------------------
__global__ __launch_bounds__(256) void gemmC_kernel(
    const _Float16* __restrict__ Tc, const _Float16* __restrict__ U,
    _Float16* __restrict__ Yt) {
  __shared__ _Float16 As[128 * 72];
  __shared__ _Float16 Bs[64 * 72];
  int h = blockIdx.y, c0 = blockIdx.x * 64;
  int t = threadIdx.x;
  int w = t >> 6, lane = t & 63, lr = lane & 15, quad = lane >> 4;
  f32x4 acc[2][4];
#pragma unroll
  for (int i = 0; i < 2; i++)
#pragma unroll
    for (int j = 0; j < 4; j++) acc[i][j] = (f32x4)(0.0f);

  uint4 pa[4], pb[2];
  auto loadA = [&](int kt) {
#pragma unroll
    for (int i = 0; i < 4; i++) {
      int idx = t + 256 * i;
      int m = idx >> 3, q = idx & 7;
      pa[i] = *(const uint4*)(Tc + ((size_t)h * 128 + m) * KU + kt + q * 8);
    }
  };
  auto loadB = [&](int kt) {
#pragma unroll
    for (int i = 0; i < 2; i++) {
      int idx = t + 256 * i;
      int jj = idx >> 3, q = idx & 7;
      pb[i] = *(const uint4*)(U + ((size_t)h * COLS + c0 + jj) * KU + kt + q * 8);
    }
  };
  loadA(0); loadB(0);

  for (int it = 0; it < 3; it++) {
#pragma unroll
    for (int i = 0; i < 4; i++) {
      int idx = t + 256 * i;
      int m = idx >> 3, q = idx & 7;
      *(uint4*)&As[m * 72 + q * 8] = pa[i];
    }
#pragma unroll
    for (int i = 0; i < 2; i++) {
      int idx = t + 256 * i;
      int jj = idx >> 3, q = idx & 7;
      *(uint4*)&Bs[jj * 72 + q * 8] = pb[i];
    }
    __syncthreads();
    if (it < 2) { loadA(64 * (it + 1)); loadB(64 * (it + 1)); }
#pragma unroll
    for (int ks = 0; ks < 2; ks++) {
      f16x8 af[2], bf[4];
#pragma unroll
      for (int i = 0; i < 2; i++)
        af[i] = *(const f16x8*)&As[(w * 32 + i * 16 + lr) * 72 + ks * 32 + quad * 8];
#pragma unroll
      for (int j = 0; j < 4; j++)
        bf[j] = *(const f16x8*)&Bs[(j * 16 + lr) * 72 + ks * 32 + quad * 8];
#pragma unroll
      for (int i = 0; i < 2; i++)
#pragma unroll
        for (int j = 0; j < 4; j++)
          acc[i][j] = __builtin_amdgcn_mfma_f32_16x16x32_f16(af[i], bf[j], acc[i][j], 0, 0, 0);
    }
    if (it < 2) __syncthreads();
  }
#pragma unroll
  for (int i = 0; i < 2; i++) {
#pragma unroll
    for (int j = 0; j < 4; j++) {
      int tb = w * 32 + i * 16 + quad * 4;
      int col = c0 + j * 16 + lr;
      f32x4 a = acc[i][j];
      uint2 r;
      r.x = pk2h(fast_gelu(a[0]), fast_gelu(a[1]));
      r.y = pk2h(fast_gelu(a[2]), fast_gelu(a[3]));
      *(uint2*)(Yt + ((size_t)h * COLS + col) * 128 + tb) = r;
    }
  }
}

// ---------------------------------------------------------------------------
// Yt[h][col][128] -> row-major Y[row=col*125+t][h] (fp16), LDS-tiled transpose.
// ---------------------------------------------------------------------------
__global__ __launch_bounds__(256) void ytr_kernel(
    const _Float16* __restrict__ Yt, _Float16* __restrict__ Y) {
  __shared__ unsigned short Yl[128][136];
  int col = blockIdx.x, hh = blockIdx.y;
#pragma unroll
  for (int rep = 0; rep < 8; rep++) {
    int cid = rep * 256 + threadIdx.x;
    int hl = cid >> 4, q = cid & 15;
    *(uint4*)&Yl[hl][q * 8] =
        *(const uint4*)(Yt + ((size_t)(hh * 128 + hl) * COLS + col) * 128 + q * 8);
  }
  __syncthreads();
#pragma unroll
  for (int rep = 0; rep < 8; rep++) {
    int sid = rep * 256 + threadIdx.x;
    int tl = sid >> 4, uq = sid & 15;
    if (tl < LC) {
      uint4 r;
      unsigned v[4];
#pragma unroll
      for (int k = 0; k < 4; k++)
        v[k] = (unsigned)Yl[uq * 8 + 2 * k][tl] | ((unsigned)Yl[uq * 8 + 2 * k + 1][tl] << 16);
      r.x = v[0]; r.y = v[1]; r.z = v[2]; r.w = v[3];
      *(uint4*)(Y + ((size_t)col * LC + tl) * HH + hh * 128 + uq * 8) = r;
    }
  }
}

// ---------------------------------------------------------------------------
// GLU FFN via fp16 MFMA, M=128 tile, T14 register prefetch. The stream holds
// z (post-LN, written by lnU); update in place: X = g1*sigmoid(g2) + z.
// Epilogue stages g1*sig in LDS (f32, reusing As/Bs via dynamic smem) then
// one fully-coalesced pass: uint4 z-reads + uint4 fp16 stores (no write amp).
// NOTE: plain __launch_bounds__(256) — a min-waves clamp (256,4) capped the
// unified VGPR+AGPR budget at 128/wave and spilled ~420 MB/dispatch to scratch.
// ---------------------------------------------------------------------------
__global__ __launch_bounds__(256) void gemm_glu_mfma(
    const _Float16* __restrict__ Y, const _Float16* __restrict__ Wt,
    const float* __restrict__ bg, _Float16* Xio) {
  extern __shared__ char smem[];
  _Float16* As = (_Float16*)smem;        // 128*72 fp16 = 18432 B
  _Float16* Bs = As + 128 * 72;          // 128*72 fp16 = 18432 B
  float* gl = (float*)smem;              // epilogue reuse: 128*68 f32 = 34816 B
  int t = threadIdx.x;
  int r0 = blockIdx.x * 128, c0 = blockIdx.y * 64;
  int w = t >> 6, lane = t & 63;
  int lr = lane & 15, quad = lane >> 4;
  int rh = w & 1, ch = w >> 1;
  f32x4 acc[4][4];
#pragma unroll
  for (int i = 0; i < 4; i++)
#pragma unroll
    for (int j = 0; j < 4; j++) acc[i][j] = (f32x4)(0.0f);

  int jb[4] = {ch * 32, ch * 32 + 16, 64 + ch * 32, 80 + ch * 32};

  uint4 pa[4], pb[4];
  auto loadA = [&](int kt) {
#pragma unroll
    for (int i = 0; i < 4; i++) {
      int idx = t + 256 * i;
      int m = idx >> 3, q = idx & 7;
      pa[i] = *(const uint4*)(Y + (size_t)(r0 + m) * HH + kt + q * 8);
    }
  };
  auto loadB = [&](int kt) {
#pragma unroll
    for (int i = 0; i < 4; i++) {
      int idx = t + 256 * i;
      int jj = idx >> 3, q = idx & 7;
      int colw = (jj < 64) ? (c0 + jj) : (192 + c0 + jj);
      pb[i] = *(const uint4*)(Wt + (size_t)colw * HH + kt + q * 8);
    }
  };
  loadA(0); loadB(0);

  for (int it = 0; it < 4; it++) {
#pragma unroll
    for (int i = 0; i < 4; i++) {
      int idx = t + 256 * i;
      int m = idx >> 3, q = idx & 7;
      *(uint4*)&As[m * 72 + q * 8] = pa[i];
    }
#pragma unroll
    for (int i = 0; i < 4; i++) {
      int idx = t + 256 * i;
      int jj = idx >> 3, q = idx & 7;
      *(uint4*)&Bs[jj * 72 + q * 8] = pb[i];
    }
    __syncthreads();
    if (it < 3) { loadA(64 * (it + 1)); loadB(64 * (it + 1)); }
#pragma unroll
    for (int ks = 0; ks < 2; ks++) {
      f16x8 af[4], bf[4];
#pragma unroll
      for (int i = 0; i < 4; i++)
        af[i] = *(const f16x8*)&As[(rh * 64 + i * 16 + lr) * 72 + ks * 32 + quad * 8];
#pragma unroll
      for (int j = 0; j < 4; j++)
        bf[j] = *(const f16x8*)&Bs[(jb[j] + lr) * 72 + ks * 32 + quad * 8];
#pragma unroll
      for (int i = 0; i < 4; i++)
#pragma unroll
        for (int j = 0; j < 4; j++)
          acc[i][j] = __builtin_amdgcn_mfma_f32_16x16x32_f16(af[i], bf[j], acc[i][j], 0, 0, 0);
    }
    if (it < 3) __syncthreads();
  }
  __syncthreads();  // all waves done reading As/Bs before gl overwrite

  // Stage g = g1*sigmoid(g2) into gl[128][68] (f32)
#pragma unroll
  for (int i = 0; i < 4; i++) {
#pragma unroll
    for (int r = 0; r < 4; r++) {
      int rowl = rh * 64 + i * 16 + quad * 4 + r;
#pragma unroll
      for (int jp = 0; jp < 2; jp++) {
        int hl = ch * 32 + jp * 16 + lr;
        int h = c0 + hl;
        float g1 = acc[i][jp][r] + bg[h];
        float g2 = acc[i][jp + 2][r] + bg[256 + h];
        float sig = __builtin_amdgcn_rcpf(1.0f + __expf(-g2));
        gl[rowl * 68 + hl] = g1 * sig;
      }
    }
  }
  __syncthreads();

  // Coalesced residual-add pass: 1024 chunks of (row, 8 h-values)
#pragma unroll
  for (int rep = 0; rep < 4; rep++) {
    int lin = rep * 256 + t;
    int rowl = lin >> 3, hc = lin & 7;
    int row = r0 + rowl;
    int hb = c0 + hc * 8;
    uint4 zv = *(const uint4*)(Xio + (size_t)row * HH + hb);
    float2 z01 = upk2(zv.x), z23 = upk2(zv.y), z45 = upk2(zv.z), z67 = upk2(zv.w);
    const float* gp = &gl[rowl * 68 + hc * 8];
    uint4 r;
    r.x = pk2h(gp[0] + z01.x, gp[1] + z01.y);
    r.y = pk2h(gp[2] + z23.x, gp[3] + z23.y);
    r.z = pk2h(gp[4] + z45.x, gp[5] + z45.y);
    r.w = pk2h(gp[6] + z67.x, gp[7] + z67.y);
    *(uint4*)(Xio + (size_t)row * HH + hb) = r;
  }
}

// ---------------------------------------------------------------------------
extern "C" void kernel_launch(void* const* d_in, const int* in_sizes, int n_in,
                              void* d_out, int out_size, void* d_ws, size_t ws_size,
                              hipStream_t stream) {
  const float* x      = (const float*)d_in[0];
  const float* Win    = (const float*)d_in[1];
  const float* bin    = (const float*)d_in[2];
  const float* ln_g   = (const float*)d_in[3];
  const float* ln_b   = (const float*)d_in[4];
  const float* log_dt = (const float*)d_in[5];
  const float* logA   = (const float*)d_in[6];
  const float* A_im   = (const float*)d_in[7];
  const float* Cp     = (const float*)d_in[8];
  const float* Dv     = (const float*)d_in[9];
  const float* Wglu   = (const float*)d_in[10];
  const float* bglu   = (const float*)d_in[11];
  const float* fn_g   = (const float*)d_in[12];
  const float* fn_b   = (const float*)d_in[13];
  float* out = (float*)d_out;
  float* ws = (float*)d_ws;

  // Workspace layout (float units)
  _Float16* Xs = (_Float16*)ws;                        // fp16 token stream (z/x in place)
  float* Pf = ws + (size_t)NROWS * HH;                 // f32 chunk states
  _Float16* Tc = (_Float16*)(Pf + (size_t)HH * COLS * 64);
  _Float16* V  = Tc + (size_t)HH * 128 * KU;
  _Float16* U  = V + (size_t)HH * 64 * 128;
  _Float16* Wt = U + (size_t)HH * COLS * KU;
  float* WLc = (float*)(Wt + (size_t)NLAYER * 512 * HH);
  _Float16* Yt = (_Float16*)Pf;                        // fp16 alias (disjoint lifetime)
  _Float16* Y  = (_Float16*)d_out;                     // row-major activations for GLU

  wt_kernel<<<(NLAYER * 512) / 256, 256, 0, stream>>>(Wglu, Wt);
  proj_kernel<<<2048, 256, 0, stream>>>(x, Win, bin, Xs);

  for (int l = 0; l < NLAYER; l++) {
    paramT_kernel<<<HH, 128, 0, stream>>>(log_dt, logA, A_im, Cp, Dv, l, Tc, V, WLc);
    lnU_kernel<<<COLS, 256, 0, stream>>>(Xs, U, ln_g + l * HH, ln_b + l * HH);
    gemmA_kernel<<<dim3(COLS / 64, HH), 256, 0, stream>>>(V, U, Pf);
    combine_kernel<<<HH * 2, 256, 0, stream>>>(Pf, U, WLc);
    gemmC_kernel<<<dim3(COLS / 64, HH), 256, 0, stream>>>(Tc, U, Yt);
    ytr_kernel<<<dim3(COLS, 2), 256, 0, stream>>>(Yt, Y);
    gemm_glu_mfma<<<dim3(NROWS / 128, 4), 256, 36864, stream>>>(
        Y, Wt + (size_t)l * 512 * HH, bglu + (size_t)l * 2 * HH, Xs);
  }
  ln_kernel<<<NROWS / 4, 256, 0, stream>>>(Xs, out, fn_g, fn_b);
}

// Round 6
// 1075.565 us; speedup vs baseline: 1.5729x; 1.3820x over previous
//
#include <hip/hip_runtime.h>
#include <math.h>

// Problem constants
#define BB 16
#define LL 5000
#define DIN 12
#define HH 256
#define NN 32
#define NLAYER 4
#define LC 125               // chunk length
#define NCH 40               // chunks per batch row (40*125 = 5000)
#define COLS (BB*NCH)        // 640 chunk-columns; col = b*40+c, row = col*125+t
#define NROWS (BB*LL)        // 80000 token rows
#define KU 192               // Ubig inner dim: 128 (tau, padded) + 64 (state re/im)

typedef __attribute__((ext_vector_type(8))) _Float16 f16x8;
typedef __attribute__((ext_vector_type(4))) float f32x4;

// fast tanh-GELU (matches jax.nn.gelu approximate): a*sigmoid(2*inner)
__device__ __forceinline__ float fast_gelu(float a) {
  float z = fmaf(0.0713548163f * a, a * a, 1.5957691216f * a);
  float e = __expf(-z);
  return a * __builtin_amdgcn_rcpf(1.0f + e);
}

__device__ __forceinline__ unsigned pk2h(float a, float b) {
  union { _Float16 h[2]; unsigned u; } x;
  x.h[0] = (_Float16)a; x.h[1] = (_Float16)b;
  return x.u;
}

__device__ __forceinline__ float2 upk2(unsigned u) {
  union { unsigned u; _Float16 h[2]; } x;
  x.u = u;
  return make_float2((float)x.h[0], (float)x.h[1]);
}

// ---------------------------------------------------------------------------
// Per-layer precompute of the chunked-convolution operators (fp16):
//   Tc[h][t=0..127][k=0..191] : k<128 -> Toeplitz K[t-k] (+D on diag); k>=128 ->
//                               boundary Bnd[t][n2] = {Re, -Im}(Ct2_n * w_n^{t+1})
//   V[h][n2=0..63][tau=0..127]: {Re,Im}(w_n^{124-tau})   (chunk-state operator)
//   WLc[h][n2]                : w^125 (combine step)
// ---------------------------------------------------------------------------
__global__ __launch_bounds__(128) void paramT_kernel(
    const float* __restrict__ log_dt, const float* __restrict__ logA_re,
    const float* __restrict__ A_im, const float* __restrict__ Cp,
    const float* __restrict__ Dv, int l,
    _Float16* __restrict__ Tc, _Float16* __restrict__ V, float* __restrict__ WLc) {
  int h = blockIdx.x;
  int t = threadIdx.x;
  __shared__ float s_are[NN], s_aim[NN], s_cre[NN], s_cim[NN];
  __shared__ float s_K[LC];
  if (t < NN) {
    int n = t;
    int idx = (l * HH + h) * NN + n;
    float dt = expf(log_dt[l * HH + h]);
    float Are = -expf(logA_re[idx]);
    float Aim = A_im[idx];
    float are = Are * dt, aim = Aim * dt;
    float e = expf(are);
    float wre = e * cosf(aim), wim = e * sinf(aim);
    float cr = Cp[2 * idx], ci = Cp[2 * idx + 1];
    float nre = wre - 1.0f, nim = wim;
    float tre = cr * nre - ci * nim;
    float tim = cr * nim + ci * nre;
    float inv = 1.0f / (Are * Are + Aim * Aim);
    s_are[n] = are; s_aim[n] = aim;
    s_cre[n] = 2.0f * (tre * Are + tim * Aim) * inv;
    s_cim[n] = 2.0f * (tim * Are - tre * Aim) * inv;
    float eL = expf(125.0f * are);
    float ang = 125.0f * aim;
    WLc[h * 64 + 2 * n] = eL * cosf(ang);
    WLc[h * 64 + 2 * n + 1] = eL * sinf(ang);
  }
  __syncthreads();
  if (t < LC) {
    float ksum = 0.0f;
    unsigned* brow = (unsigned*)(Tc + ((size_t)h * 128 + t) * KU + 128);
    for (int n = 0; n < NN; n++) {
      float are = s_are[n], aim = s_aim[n];
      float cre = s_cre[n], cim = s_cim[n];
      float ft = (float)t;
      float E = expf(are * ft);
      float a = aim * ft;
      float wtre = E * cosf(a), wtim = E * sinf(a);        // w^t
      ksum = fmaf(cre, wtre, ksum);
      ksum = fmaf(-cim, wtim, ksum);
      float ew = expf(are);
      float wre = ew * cosf(aim), wim = ew * sinf(aim);    // w
      float wpre = wtre * wre - wtim * wim;                // w^{t+1}
      float wpim = wtre * wim + wtim * wre;
      float bre = cre * wpre - cim * wpim;                 // Re(Ct2*w^{t+1})
      float bim = -(cre * wpim + cim * wpre);              // -Im(Ct2*w^{t+1})
      brow[n] = pk2h(bre, bim);
      float fk = (float)(124 - t);
      float E2 = expf(are * fk);
      float a2 = aim * fk;
      V[((size_t)h * 64 + 2 * n) * 128 + t] = (_Float16)(E2 * cosf(a2));
      V[((size_t)h * 64 + 2 * n + 1) * 128 + t] = (_Float16)(E2 * sinf(a2));
    }
    s_K[t] = ksum;
  } else {
    for (int n2 = 0; n2 < 64; n2++) V[((size_t)h * 64 + n2) * 128 + t] = (_Float16)0.0f;
    unsigned* brow = (unsigned*)(Tc + ((size_t)h * 128 + t) * KU + 128);
    for (int q = 0; q < 32; q++) brow[q] = 0u;
  }
  __syncthreads();
  float D = Dv[l * HH + h];
  unsigned* row = (unsigned*)(Tc + ((size_t)h * 128 + t) * KU);
  for (int q = 0; q < 64; q++) {  // tau = 2q, 2q+1
    float v0 = 0.0f, v1 = 0.0f;
    if (t < LC) {
      int d0 = t - 2 * q;
      int d1 = d0 - 1;
      if (d0 >= 0) v0 = s_K[d0] + (d0 == 0 ? D : 0.0f);
      if (d1 >= 0) v1 = s_K[d1] + (d1 == 0 ? D : 0.0f);
    }
    row[q] = pk2h(v0, v1);
  }
}

// ---------------------------------------------------------------------------
// W_glu transpose+cast to fp16: Wt[l][col(512)][k(256)]
// ---------------------------------------------------------------------------
__global__ __launch_bounds__(256) void wt_kernel(
    const float* __restrict__ W, _Float16* __restrict__ Wt) {
  int gid = blockIdx.x * 256 + threadIdx.x;   // NLAYER*512 = 2048
  int l = gid >> 9, col = gid & 511;
  const float* w = W + (size_t)l * HH * 512 + col;
  _Float16* o = Wt + (size_t)gid * HH;
  for (int k = 0; k < HH; k++) o[k] = (_Float16)(w[(size_t)k * 512]);
}

// ---------------------------------------------------------------------------
// Input projection -> fp16 stream. Thread = h-pair, 2 rows per block pass.
// ---------------------------------------------------------------------------
__global__ __launch_bounds__(256) void proj_kernel(
    const float* __restrict__ x, const float* __restrict__ Win,
    const float* __restrict__ bin, _Float16* __restrict__ X) {
  int tp = threadIdx.x & 127, rs = threadIdx.x >> 7;
  int h0 = 2 * tp;
  float w0[DIN], w1[DIN];
#pragma unroll
  for (int k = 0; k < DIN; k++) {
    w0[k] = Win[k * HH + h0];
    w1[k] = Win[k * HH + h0 + 1];
  }
  float b0 = bin[h0], b1 = bin[h0 + 1];
  for (int row = blockIdx.x * 2 + rs; row < NROWS; row += gridDim.x * 2) {
    float a0 = b0, a1 = b1;
#pragma unroll
    for (int k = 0; k < DIN; k++) {
      float xv = x[(size_t)row * DIN + k];
      a0 = fmaf(xv, w0[k], a0);
      a1 = fmaf(xv, w1[k], a1);
    }
    *(unsigned*)(X + (size_t)row * HH + h0) = pk2h(a0, a1);
  }
}

// ---------------------------------------------------------------------------
// Final LayerNorm: fp16 stream in, f32 out. One row per wave.
// ---------------------------------------------------------------------------
__global__ __launch_bounds__(256) void ln_kernel(
    const _Float16* __restrict__ in, float* __restrict__ out,
    const float* __restrict__ g, const float* __restrict__ b) {
  int wave = threadIdx.x >> 6, lane = threadIdx.x & 63;
  int row = blockIdx.x * 4 + wave;
  uint2 pv = *(const uint2*)(in + (size_t)row * HH + 4 * lane);
  float2 v01 = upk2(pv.x), v23 = upk2(pv.y);
  float s = v01.x + v01.y + v23.x + v23.y;
  float q = v01.x * v01.x + v01.y * v01.y + v23.x * v23.x + v23.y * v23.y;
#pragma unroll
  for (int m = 1; m < 64; m <<= 1) { s += __shfl_xor(s, m); q += __shfl_xor(q, m); }
  float mean = s * (1.0f / HH);
  float var = q * (1.0f / HH) - mean * mean;
  float rstd = rsqrtf(var + 1e-5f);
  float4 gg = ((const float4*)g)[lane];
  float4 bb = ((const float4*)b)[lane];
  float4 o;
  o.x = (v01.x - mean) * rstd * gg.x + bb.x;
  o.y = (v01.y - mean) * rstd * gg.y + bb.y;
  o.z = (v23.x - mean) * rstd * gg.z + bb.z;
  o.w = (v23.y - mean) * rstd * gg.w + bb.w;
  ((float4*)(out + (size_t)row * HH))[lane] = o;
}

// ---------------------------------------------------------------------------
// Per-layer LN (in place on fp16 stream: x -> z) fused with transposed fp16
// export U[h][col][tau] for tau=0..127 (125..127 zero). One block per col.
// ---------------------------------------------------------------------------
__global__ __launch_bounds__(256) void lnU_kernel(
    _Float16* __restrict__ stream, _Float16* __restrict__ U,
    const float* __restrict__ g, const float* __restrict__ b) {
  __shared__ unsigned short Ut[128][260];   // [tau][h], padded stride
  int col = blockIdx.x;
  int wave = threadIdx.x >> 6, lane = threadIdx.x & 63;
  for (int idx = threadIdx.x; idx < 3 * 260; idx += 256) {
    int r = idx / 260;
    Ut[125 + r][idx - r * 260] = 0;
  }
  float4 gg = ((const float4*)g)[lane];
  float4 bb = ((const float4*)b)[lane];
  size_t base = (size_t)col * LC * HH;
  for (int it = 0; it < 32; it++) {
    int tau = it * 4 + wave;
    if (tau < LC) {
      uint2 pv = *(const uint2*)(stream + base + (size_t)tau * HH + 4 * lane);
      float2 v01 = upk2(pv.x), v23 = upk2(pv.y);
      float s = v01.x + v01.y + v23.x + v23.y;
      float q = v01.x * v01.x + v01.y * v01.y + v23.x * v23.x + v23.y * v23.y;
#pragma unroll
      for (int m = 1; m < 64; m <<= 1) { s += __shfl_xor(s, m); q += __shfl_xor(q, m); }
      float mean = s * (1.0f / HH);
      float var = q * (1.0f / HH) - mean * mean;
      float rstd = rsqrtf(var + 1e-5f);
      float o0 = (v01.x - mean) * rstd * gg.x + bb.x;
      float o1 = (v01.y - mean) * rstd * gg.y + bb.y;
      float o2 = (v23.x - mean) * rstd * gg.z + bb.z;
      float o3 = (v23.y - mean) * rstd * gg.w + bb.w;
      uint2 p;
      p.x = pk2h(o0, o1);
      p.y = pk2h(o2, o3);
      *(uint2*)(stream + base + (size_t)tau * HH + 4 * lane) = p;  // residual = z
      *(uint2*)&Ut[tau][4 * lane] = p;
    }
  }
  __syncthreads();
  // export transposed: per h, 64 u32 words (128 tau)
  for (int rep = 0; rep < 8; rep++) {
    int linear = rep * 256 + threadIdx.x;
    int h = linear >> 3, ub = linear & 7;
    unsigned* dst = (unsigned*)(U + ((size_t)h * COLS + col) * KU);
#pragma unroll
    for (int s2 = 0; s2 < 8; s2++) {
      int u = ub + s2 * 8;
      unsigned val = (unsigned)Ut[2 * u][h] | ((unsigned)Ut[2 * u + 1][h] << 16);
      dst[u] = val;
    }
  }
}

// ---------------------------------------------------------------------------
// gemmA: per h, P[n2][col] = V[h](64x128) @ U[h](128 x col). P stored f32
// transposed: P[h][col][n2]. Round-1 grid: x=h, y=colblock.
// ---------------------------------------------------------------------------
__global__ __launch_bounds__(256) void gemmA_kernel(
    const _Float16* __restrict__ V, const _Float16* __restrict__ U,
    float* __restrict__ P) {
  __shared__ _Float16 As[64 * 72];
  __shared__ _Float16 Bs[64 * 72];
  int h = blockIdx.x, c0 = blockIdx.y * 64;
  int t = threadIdx.x;
  int w = t >> 6, lane = t & 63, lr = lane & 15, quad = lane >> 4;
  int mh = w & 1, nh = w >> 1;
  f32x4 acc[2][2];
#pragma unroll
  for (int i = 0; i < 2; i++)
#pragma unroll
    for (int j = 0; j < 2; j++) acc[i][j] = (f32x4)(0.0f);

  for (int kt = 0; kt < 128; kt += 64) {
#pragma unroll
    for (int i = 0; i < 2; i++) {
      int idx = t + 256 * i;
      int m = idx >> 3, q = idx & 7;
      *(uint4*)&As[m * 72 + q * 8] =
          *(const uint4*)(V + ((size_t)h * 64 + m) * 128 + kt + q * 8);
      *(uint4*)&Bs[m * 72 + q * 8] =
          *(const uint4*)(U + ((size_t)h * COLS + c0 + m) * KU + kt + q * 8);
    }
    __syncthreads();
#pragma unroll
    for (int ks = 0; ks < 2; ks++) {
      f16x8 af[2], bf[2];
#pragma unroll
      for (int i = 0; i < 2; i++)
        af[i] = *(const f16x8*)&As[(mh * 32 + i * 16 + lr) * 72 + ks * 32 + quad * 8];
#pragma unroll
      for (int j = 0; j < 2; j++)
        bf[j] = *(const f16x8*)&Bs[(nh * 32 + j * 16 + lr) * 72 + ks * 32 + quad * 8];
#pragma unroll
      for (int i = 0; i < 2; i++)
#pragma unroll
        for (int j = 0; j < 2; j++)
          acc[i][j] = __builtin_amdgcn_mfma_f32_16x16x32_f16(af[i], bf[j], acc[i][j], 0, 0, 0);
    }
    __syncthreads();
  }
#pragma unroll
  for (int i = 0; i < 2; i++) {
#pragma unroll
    for (int j = 0; j < 2; j++) {
      int n2 = mh * 32 + i * 16 + quad * 4;
      int col = c0 + nh * 32 + j * 16 + lr;
      *(f32x4*)(P + ((size_t)h * COLS + col) * 64 + n2) = acc[i][j];
    }
  }
}

// ---------------------------------------------------------------------------
// combine: serial scan over chunks per (b,h,n): carry' = w^125*carry + P[c].
// Writes exclusive-prefix carry (fp16) into Ubig[h][col][128+n2].
// ---------------------------------------------------------------------------
__global__ __launch_bounds__(256) void combine_kernel(
    const float* __restrict__ P, _Float16* __restrict__ U,
    const float* __restrict__ WLc) {
  int h = blockIdx.x >> 1;
  int bh = blockIdx.x & 1;
  int n = threadIdx.x & 31;
  int b = bh * 8 + (threadIdx.x >> 5);
  float wre = WLc[h * 64 + 2 * n], wim = WLc[h * 64 + 2 * n + 1];
  const float* p = P + ((size_t)h * COLS + (size_t)b * NCH) * 64 + 2 * n;
  _Float16* u = U + ((size_t)h * COLS + (size_t)b * NCH) * KU + 128 + 2 * n;
  float cre = 0.0f, cim = 0.0f;
#pragma unroll 4
  for (int c = 0; c < NCH; c++) {
    float2 v = *(const float2*)(p + (size_t)c * 64);
    *(unsigned*)(u + (size_t)c * KU) = pk2h(cre, cim);
    float nre = fmaf(wre, cre, v.x) - wim * cim;
    float nim = fmaf(wre, cim, v.y) + wim * cre;
    cre = nre; cim = nim;
  }
}

// ---------------------------------------------------------------------------
// gemmC: per h, Y[t=128][col] = Tc[h](128x192) @ [u; s0](192 x col), fused
// GELU, fp16 out Yt[h][col][t]. Round-1 synchronous staging (no T14).
// ---------------------------------------------------------------------------
__global__ __launch_bounds__(256) void gemmC_kernel(
    const _Float16* __restrict__ Tc, const _Float16* __restrict__ U,
    _Float16* __restrict__ Yt) {
  __shared__ _Float16 As[128 * 72];
  __shared__ _Float16 Bs[64 * 72];
  int h = blockIdx.x, c0 = blockIdx.y * 64;
  int t = threadIdx.x;
  int w = t >> 6, lane = t & 63, lr = lane & 15, quad = lane >> 4;
  f32x4 acc[2][4];
#pragma unroll
  for (int i = 0; i < 2; i++)
#pragma unroll
    for (int j = 0; j < 4; j++) acc[i][j] = (f32x4)(0.0f);

  for (int kt = 0; kt < KU; kt += 64) {
#pragma unroll
    for (int i = 0; i < 4; i++) {
      int idx = t + 256 * i;
      int m = idx >> 3, q = idx & 7;
      *(uint4*)&As[m * 72 + q * 8] =
          *(const uint4*)(Tc + ((size_t)h * 128 + m) * KU + kt + q * 8);
    }
#pragma unroll
    for (int i = 0; i < 2; i++) {
      int idx = t + 256 * i;
      int jj = idx >> 3, q = idx & 7;
      *(uint4*)&Bs[jj * 72 + q * 8] =
          *(const uint4*)(U + ((size_t)h * COLS + c0 + jj) * KU + kt + q * 8);
    }
    __syncthreads();
#pragma unroll
    for (int ks = 0; ks < 2; ks++) {
      f16x8 af[2], bf[4];
#pragma unroll
      for (int i = 0; i < 2; i++)
        af[i] = *(const f16x8*)&As[(w * 32 + i * 16 + lr) * 72 + ks * 32 + quad * 8];
#pragma unroll
      for (int j = 0; j < 4; j++)
        bf[j] = *(const f16x8*)&Bs[(j * 16 + lr) * 72 + ks * 32 + quad * 8];
#pragma unroll
      for (int i = 0; i < 2; i++)
#pragma unroll
        for (int j = 0; j < 4; j++)
          acc[i][j] = __builtin_amdgcn_mfma_f32_16x16x32_f16(af[i], bf[j], acc[i][j], 0, 0, 0);
    }
    __syncthreads();
  }
#pragma unroll
  for (int i = 0; i < 2; i++) {
#pragma unroll
    for (int j = 0; j < 4; j++) {
      int tb = w * 32 + i * 16 + quad * 4;
      int col = c0 + j * 16 + lr;
      f32x4 a = acc[i][j];
      uint2 r;
      r.x = pk2h(fast_gelu(a[0]), fast_gelu(a[1]));
      r.y = pk2h(fast_gelu(a[2]), fast_gelu(a[3]));
      *(uint2*)(Yt + ((size_t)h * COLS + col) * 128 + tb) = r;
    }
  }
}

// ---------------------------------------------------------------------------
// Yt[h][col][128] -> row-major Y[row=col*125+t][h] (fp16), LDS-tiled transpose.
// ---------------------------------------------------------------------------
__global__ __launch_bounds__(256) void ytr_kernel(
    const _Float16* __restrict__ Yt, _Float16* __restrict__ Y) {
  __shared__ unsigned short Yl[128][136];
  int col = blockIdx.x, hh = blockIdx.y;
#pragma unroll
  for (int rep = 0; rep < 8; rep++) {
    int cid = rep * 256 + threadIdx.x;
    int hl = cid >> 4, q = cid & 15;
    *(uint4*)&Yl[hl][q * 8] =
        *(const uint4*)(Yt + ((size_t)(hh * 128 + hl) * COLS + col) * 128 + q * 8);
  }
  __syncthreads();
#pragma unroll
  for (int rep = 0; rep < 8; rep++) {
    int sid = rep * 256 + threadIdx.x;
    int tl = sid >> 4, uq = sid & 15;
    if (tl < LC) {
      uint4 r;
      unsigned v[4];
#pragma unroll
      for (int k = 0; k < 4; k++)
        v[k] = (unsigned)Yl[uq * 8 + 2 * k][tl] | ((unsigned)Yl[uq * 8 + 2 * k + 1][tl] << 16);
      r.x = v[0]; r.y = v[1]; r.z = v[2]; r.w = v[3];
      *(uint4*)(Y + ((size_t)col * LC + tl) * HH + hh * 128 + uq * 8) = r;
    }
  }
}

// ---------------------------------------------------------------------------
// GLU FFN via fp16 MFMA, M=128 tile, round-1 SYNCHRONOUS staging (no T14 —
// prefetch regs held across barriers caused scratch spill, r4/r5 counters).
// Stream holds z (post-LN); update in place: X = g1*sigmoid(g2) + z.
// Epilogue stages g1*sig in LDS (aliasing As/Bs, static union) then one
// coalesced pass: uint4 z-reads + uint4 fp16 stores (128 B aligned spans).
// ---------------------------------------------------------------------------
__global__ __launch_bounds__(256) void gemm_glu_mfma(
    const _Float16* __restrict__ Y, const _Float16* __restrict__ Wt,
    const float* __restrict__ bg, _Float16* __restrict__ Xio) {
  __shared__ uint4 smemq[2304];          // 36864 B static
  _Float16* As = (_Float16*)smemq;       // 128*72 fp16 = 18432 B
  _Float16* Bs = As + 128 * 72;          // 128*72 fp16 = 18432 B
  float* gl = (float*)smemq;             // epilogue alias: 128*68 f32 = 34816 B
  int t = threadIdx.x;
  int r0 = blockIdx.x * 128, c0 = blockIdx.y * 64;
  int w = t >> 6, lane = t & 63;
  int lr = lane & 15, quad = lane >> 4;
  int rh = w & 1, ch = w >> 1;
  f32x4 acc[4][4];
#pragma unroll
  for (int i = 0; i < 4; i++)
#pragma unroll
    for (int j = 0; j < 4; j++) acc[i][j] = (f32x4)(0.0f);

  int jb[4] = {ch * 32, ch * 32 + 16, 64 + ch * 32, 80 + ch * 32};

  for (int kt = 0; kt < HH; kt += 64) {
#pragma unroll
    for (int i = 0; i < 4; i++) {
      int idx = t + 256 * i;
      int m = idx >> 3, q = idx & 7;
      *(uint4*)&As[m * 72 + q * 8] =
          *(const uint4*)(Y + (size_t)(r0 + m) * HH + kt + q * 8);
    }
#pragma unroll
    for (int i = 0; i < 4; i++) {
      int idx = t + 256 * i;
      int jj = idx >> 3, q = idx & 7;
      int colw = (jj < 64) ? (c0 + jj) : (192 + c0 + jj);
      *(uint4*)&Bs[jj * 72 + q * 8] =
          *(const uint4*)(Wt + (size_t)colw * HH + kt + q * 8);
    }
    __syncthreads();
#pragma unroll
    for (int ks = 0; ks < 2; ks++) {
      f16x8 af[4], bf[4];
#pragma unroll
      for (int i = 0; i < 4; i++)
        af[i] = *(const f16x8*)&As[(rh * 64 + i * 16 + lr) * 72 + ks * 32 + quad * 8];
#pragma unroll
      for (int j = 0; j < 4; j++)
        bf[j] = *(const f16x8*)&Bs[(jb[j] + lr) * 72 + ks * 32 + quad * 8];
#pragma unroll
      for (int i = 0; i < 4; i++)
#pragma unroll
        for (int j = 0; j < 4; j++)
          acc[i][j] = __builtin_amdgcn_mfma_f32_16x16x32_f16(af[i], bf[j], acc[i][j], 0, 0, 0);
    }
    __syncthreads();
  }

  // Stage g = g1*sigmoid(g2) into gl[128][68] (f32); As/Bs reads all complete
  // (trailing barrier of last K iteration).
#pragma unroll
  for (int i = 0; i < 4; i++) {
#pragma unroll
    for (int r = 0; r < 4; r++) {
      int rowl = rh * 64 + i * 16 + quad * 4 + r;
#pragma unroll
      for (int jp = 0; jp < 2; jp++) {
        int hl = ch * 32 + jp * 16 + lr;
        int h = c0 + hl;
        float g1 = acc[i][jp][r] + bg[h];
        float g2 = acc[i][jp + 2][r] + bg[256 + h];
        float sig = __builtin_amdgcn_rcpf(1.0f + __expf(-g2));
        gl[rowl * 68 + hl] = g1 * sig;
      }
    }
  }
  __syncthreads();

  // Coalesced residual-add pass: 1024 chunks of (row, 8 h-values)
#pragma unroll
  for (int rep = 0; rep < 4; rep++) {
    int lin = rep * 256 + t;
    int rowl = lin >> 3, hc = lin & 7;
    int row = r0 + rowl;
    int hb = c0 + hc * 8;
    uint4 zv = *(const uint4*)(Xio + (size_t)row * HH + hb);
    float2 z01 = upk2(zv.x), z23 = upk2(zv.y), z45 = upk2(zv.z), z67 = upk2(zv.w);
    const float* gp = &gl[rowl * 68 + hc * 8];
    uint4 r;
    r.x = pk2h(gp[0] + z01.x, gp[1] + z01.y);
    r.y = pk2h(gp[2] + z23.x, gp[3] + z23.y);
    r.z = pk2h(gp[4] + z45.x, gp[5] + z45.y);
    r.w = pk2h(gp[6] + z67.x, gp[7] + z67.y);
    *(uint4*)(Xio + (size_t)row * HH + hb) = r;
  }
}

// ---------------------------------------------------------------------------
extern "C" void kernel_launch(void* const* d_in, const int* in_sizes, int n_in,
                              void* d_out, int out_size, void* d_ws, size_t ws_size,
                              hipStream_t stream) {
  const float* x      = (const float*)d_in[0];
  const float* Win    = (const float*)d_in[1];
  const float* bin    = (const float*)d_in[2];
  const float* ln_g   = (const float*)d_in[3];
  const float* ln_b   = (const float*)d_in[4];
  const float* log_dt = (const float*)d_in[5];
  const float* logA   = (const float*)d_in[6];
  const float* A_im   = (const float*)d_in[7];
  const float* Cp     = (const float*)d_in[8];
  const float* Dv     = (const float*)d_in[9];
  const float* Wglu   = (const float*)d_in[10];
  const float* bglu   = (const float*)d_in[11];
  const float* fn_g   = (const float*)d_in[12];
  const float* fn_b   = (const float*)d_in[13];
  float* out = (float*)d_out;
  float* ws = (float*)d_ws;

  // Workspace layout (float units)
  _Float16* Xs = (_Float16*)ws;                        // fp16 token stream (z/x in place)
  float* Pf = ws + (size_t)NROWS * HH;                 // f32 chunk states
  _Float16* Tc = (_Float16*)(Pf + (size_t)HH * COLS * 64);
  _Float16* V  = Tc + (size_t)HH * 128 * KU;
  _Float16* U  = V + (size_t)HH * 64 * 128;
  _Float16* Wt = U + (size_t)HH * COLS * KU;
  float* WLc = (float*)(Wt + (size_t)NLAYER * 512 * HH);
  _Float16* Yt = (_Float16*)Pf;                        // fp16 alias (disjoint lifetime)
  _Float16* Y  = (_Float16*)d_out;                     // row-major activations for GLU

  wt_kernel<<<(NLAYER * 512) / 256, 256, 0, stream>>>(Wglu, Wt);
  proj_kernel<<<2048, 256, 0, stream>>>(x, Win, bin, Xs);

  for (int l = 0; l < NLAYER; l++) {
    paramT_kernel<<<HH, 128, 0, stream>>>(log_dt, logA, A_im, Cp, Dv, l, Tc, V, WLc);
    lnU_kernel<<<COLS, 256, 0, stream>>>(Xs, U, ln_g + l * HH, ln_b + l * HH);
    gemmA_kernel<<<dim3(HH, COLS / 64), 256, 0, stream>>>(V, U, Pf);
    combine_kernel<<<HH * 2, 256, 0, stream>>>(Pf, U, WLc);
    gemmC_kernel<<<dim3(HH, COLS / 64), 256, 0, stream>>>(Tc, U, Yt);
    ytr_kernel<<<dim3(COLS, 2), 256, 0, stream>>>(Yt, Y);
    gemm_glu_mfma<<<dim3(NROWS / 128, 4), 256, 0, stream>>>(
        Y, Wt + (size_t)l * 512 * HH, bglu + (size_t)l * 2 * HH, Xs);
  }
  ln_kernel<<<NROWS / 4, 256, 0, stream>>>(Xs, out, fn_g, fn_b);
}

// Round 7
// 1018.808 us; speedup vs baseline: 1.6605x; 1.0557x over previous
//
#include <hip/hip_runtime.h>
#include <math.h>

// Problem constants
#define BB 16
#define LL 5000
#define DIN 12
#define HH 256
#define NN 32
#define NLAYER 4
#define LC 128               // chunk length (last chunk per batch row = 8)
#define NCH 40               // chunks per batch row (39*128 + 8 = 5000)
#define TAIL 8               // length of last chunk
#define COLS (BB*NCH)        // 640 chunk-columns; col = b*40 + pt
#define NROWS (BB*LL)        // 80000 token rows
#define KU 192               // Ubig inner dim: 128 (tau) + 64 (state re/im)

typedef __attribute__((ext_vector_type(8))) _Float16 f16x8;
typedef __attribute__((ext_vector_type(4))) float f32x4;

// fast tanh-GELU (matches jax.nn.gelu approximate): a*sigmoid(2*inner)
__device__ __forceinline__ float fast_gelu(float a) {
  float z = fmaf(0.0713548163f * a, a * a, 1.5957691216f * a);
  float e = __expf(-z);
  return a * __builtin_amdgcn_rcpf(1.0f + e);
}

__device__ __forceinline__ unsigned pk2h(float a, float b) {
  union { _Float16 h[2]; unsigned u; } x;
  x.h[0] = (_Float16)a; x.h[1] = (_Float16)b;
  return x.u;
}

__device__ __forceinline__ float2 upk2(unsigned u) {
  union { unsigned u; _Float16 h[2]; } x;
  x.u = u;
  return make_float2((float)x.h[0], (float)x.h[1]);
}

// ---------------------------------------------------------------------------
// Per-layer precompute (LC=128, all 128 rows/cols valid — no padding):
//   Tc[h][t][k] : k<128 -> Toeplitz K[t-k] (+D diag); k>=128 -> Bnd[t][n2]
//   V[h][n2][tau] = {Re,Im}(w^{127-tau});  WLc[h][n2] = w^128
// ---------------------------------------------------------------------------
__global__ __launch_bounds__(128) void paramT_kernel(
    const float* __restrict__ log_dt, const float* __restrict__ logA_re,
    const float* __restrict__ A_im, const float* __restrict__ Cp,
    const float* __restrict__ Dv, int l,
    _Float16* __restrict__ Tc, _Float16* __restrict__ V, float* __restrict__ WLc) {
  int h = blockIdx.x;
  int t = threadIdx.x;           // 0..127, all valid
  __shared__ float s_are[NN], s_aim[NN], s_cre[NN], s_cim[NN];
  __shared__ float s_K[128];
  if (t < NN) {
    int n = t;
    int idx = (l * HH + h) * NN + n;
    float dt = expf(log_dt[l * HH + h]);
    float Are = -expf(logA_re[idx]);
    float Aim = A_im[idx];
    float are = Are * dt, aim = Aim * dt;
    float e = expf(are);
    float wre = e * cosf(aim), wim = e * sinf(aim);
    float cr = Cp[2 * idx], ci = Cp[2 * idx + 1];
    float nre = wre - 1.0f, nim = wim;
    float tre = cr * nre - ci * nim;
    float tim = cr * nim + ci * nre;
    float inv = 1.0f / (Are * Are + Aim * Aim);
    s_are[n] = are; s_aim[n] = aim;
    s_cre[n] = 2.0f * (tre * Are + tim * Aim) * inv;
    s_cim[n] = 2.0f * (tim * Are - tre * Aim) * inv;
    float eL = expf(128.0f * are);
    float ang = 128.0f * aim;
    WLc[h * 64 + 2 * n] = eL * cosf(ang);
    WLc[h * 64 + 2 * n + 1] = eL * sinf(ang);
  }
  __syncthreads();
  {
    float ksum = 0.0f;
    unsigned* brow = (unsigned*)(Tc + ((size_t)h * 128 + t) * KU + 128);
    for (int n = 0; n < NN; n++) {
      float are = s_are[n], aim = s_aim[n];
      float cre = s_cre[n], cim = s_cim[n];
      float ft = (float)t;
      float E = expf(are * ft);
      float a = aim * ft;
      float wtre = E * cosf(a), wtim = E * sinf(a);        // w^t
      ksum = fmaf(cre, wtre, ksum);
      ksum = fmaf(-cim, wtim, ksum);
      float ew = expf(are);
      float wre = ew * cosf(aim), wim = ew * sinf(aim);    // w
      float wpre = wtre * wre - wtim * wim;                // w^{t+1}
      float wpim = wtre * wim + wtim * wre;
      float bre = cre * wpre - cim * wpim;                 // Re(Ct2*w^{t+1})
      float bim = -(cre * wpim + cim * wpre);              // -Im(Ct2*w^{t+1})
      brow[n] = pk2h(bre, bim);
      float fk = (float)(127 - t);
      float E2 = expf(are * fk);
      float a2 = aim * fk;
      V[((size_t)h * 64 + 2 * n) * 128 + t] = (_Float16)(E2 * cosf(a2));
      V[((size_t)h * 64 + 2 * n + 1) * 128 + t] = (_Float16)(E2 * sinf(a2));
    }
    s_K[t] = ksum;
  }
  __syncthreads();
  float D = Dv[l * HH + h];
  unsigned* row = (unsigned*)(Tc + ((size_t)h * 128 + t) * KU);
  for (int q = 0; q < 64; q++) {  // tau = 2q, 2q+1
    float v0 = 0.0f, v1 = 0.0f;
    int d0 = t - 2 * q;
    int d1 = d0 - 1;
    if (d0 >= 0) v0 = s_K[d0] + (d0 == 0 ? D : 0.0f);
    if (d1 >= 0) v1 = s_K[d1] + (d1 == 0 ? D : 0.0f);
    row[q] = pk2h(v0, v1);
  }
}

// ---------------------------------------------------------------------------
// W_glu transpose+cast to fp16: Wt[l][col(512)][k(256)]
// ---------------------------------------------------------------------------
__global__ __launch_bounds__(256) void wt_kernel(
    const float* __restrict__ W, _Float16* __restrict__ Wt) {
  int gid = blockIdx.x * 256 + threadIdx.x;   // NLAYER*512 = 2048
  int l = gid >> 9, col = gid & 511;
  const float* w = W + (size_t)l * HH * 512 + col;
  _Float16* o = Wt + (size_t)gid * HH;
  for (int k = 0; k < HH; k++) o[k] = (_Float16)(w[(size_t)k * 512]);
}

// ---------------------------------------------------------------------------
// Input projection -> fp16 stream. Thread = h-pair, 2 rows per block pass.
// ---------------------------------------------------------------------------
__global__ __launch_bounds__(256) void proj_kernel(
    const float* __restrict__ x, const float* __restrict__ Win,
    const float* __restrict__ bin, _Float16* __restrict__ X) {
  int tp = threadIdx.x & 127, rs = threadIdx.x >> 7;
  int h0 = 2 * tp;
  float w0[DIN], w1[DIN];
#pragma unroll
  for (int k = 0; k < DIN; k++) {
    w0[k] = Win[k * HH + h0];
    w1[k] = Win[k * HH + h0 + 1];
  }
  float b0 = bin[h0], b1 = bin[h0 + 1];
  for (int row = blockIdx.x * 2 + rs; row < NROWS; row += gridDim.x * 2) {
    float a0 = b0, a1 = b1;
#pragma unroll
    for (int k = 0; k < DIN; k++) {
      float xv = x[(size_t)row * DIN + k];
      a0 = fmaf(xv, w0[k], a0);
      a1 = fmaf(xv, w1[k], a1);
    }
    *(unsigned*)(X + (size_t)row * HH + h0) = pk2h(a0, a1);
  }
}

// ---------------------------------------------------------------------------
// Final LayerNorm: fp16 stream in, f32 out. One row per wave.
// ---------------------------------------------------------------------------
__global__ __launch_bounds__(256) void ln_kernel(
    const _Float16* __restrict__ in, float* __restrict__ out,
    const float* __restrict__ g, const float* __restrict__ b) {
  int wave = threadIdx.x >> 6, lane = threadIdx.x & 63;
  int row = blockIdx.x * 4 + wave;
  uint2 pv = *(const uint2*)(in + (size_t)row * HH + 4 * lane);
  float2 v01 = upk2(pv.x), v23 = upk2(pv.y);
  float s = v01.x + v01.y + v23.x + v23.y;
  float q = v01.x * v01.x + v01.y * v01.y + v23.x * v23.x + v23.y * v23.y;
#pragma unroll
  for (int m = 1; m < 64; m <<= 1) { s += __shfl_xor(s, m); q += __shfl_xor(q, m); }
  float mean = s * (1.0f / HH);
  float var = q * (1.0f / HH) - mean * mean;
  float rstd = rsqrtf(var + 1e-5f);
  float4 gg = ((const float4*)g)[lane];
  float4 bb = ((const float4*)b)[lane];
  float4 o;
  o.x = (v01.x - mean) * rstd * gg.x + bb.x;
  o.y = (v01.y - mean) * rstd * gg.y + bb.y;
  o.z = (v23.x - mean) * rstd * gg.z + bb.z;
  o.w = (v23.y - mean) * rstd * gg.w + bb.w;
  ((float4*)(out + (size_t)row * HH))[lane] = o;
}

// ---------------------------------------------------------------------------
// Per-layer LN (in place on fp16 stream: x -> z) fused with transposed fp16
// export U[h][col][tau]. col = b*40 + c; len = (c==39) ? 8 : 128; tau >= len
// zero-padded. One block per chunk-column.
// ---------------------------------------------------------------------------
__global__ __launch_bounds__(256) void lnU_kernel(
    _Float16* __restrict__ stream, _Float16* __restrict__ U,
    const float* __restrict__ g, const float* __restrict__ b) {
  __shared__ unsigned short Ut[128][260];   // [tau][h], padded stride
  int col = blockIdx.x;
  int bI = col / NCH, cI = col % NCH;
  int len = (cI == NCH - 1) ? TAIL : 128;
  int wave = threadIdx.x >> 6, lane = threadIdx.x & 63;
  if (len < 128) {
    for (int idx = threadIdx.x; idx < (128 - len) * 260; idx += 256) {
      int r = idx / 260;
      Ut[len + r][idx - r * 260] = 0;
    }
  }
  float4 gg = ((const float4*)g)[lane];
  float4 bv = ((const float4*)b)[lane];
  size_t base = ((size_t)bI * LL + (size_t)cI * 128) * HH;
  for (int it = 0; it < 32; it++) {
    int tau = it * 4 + wave;
    if (tau < len) {
      uint2 pv = *(const uint2*)(stream + base + (size_t)tau * HH + 4 * lane);
      float2 v01 = upk2(pv.x), v23 = upk2(pv.y);
      float s = v01.x + v01.y + v23.x + v23.y;
      float q = v01.x * v01.x + v01.y * v01.y + v23.x * v23.x + v23.y * v23.y;
#pragma unroll
      for (int m = 1; m < 64; m <<= 1) { s += __shfl_xor(s, m); q += __shfl_xor(q, m); }
      float mean = s * (1.0f / HH);
      float var = q * (1.0f / HH) - mean * mean;
      float rstd = rsqrtf(var + 1e-5f);
      float o0 = (v01.x - mean) * rstd * gg.x + bv.x;
      float o1 = (v01.y - mean) * rstd * gg.y + bv.y;
      float o2 = (v23.x - mean) * rstd * gg.z + bv.z;
      float o3 = (v23.y - mean) * rstd * gg.w + bv.w;
      uint2 p;
      p.x = pk2h(o0, o1);
      p.y = pk2h(o2, o3);
      *(uint2*)(stream + base + (size_t)tau * HH + 4 * lane) = p;  // residual = z
      *(uint2*)&Ut[tau][4 * lane] = p;
    }
  }
  __syncthreads();
  // export transposed: per h, 64 u32 words (128 tau)
  for (int rep = 0; rep < 8; rep++) {
    int linear = rep * 256 + threadIdx.x;
    int h = linear >> 3, ub = linear & 7;
    unsigned* dst = (unsigned*)(U + ((size_t)h * COLS + col) * KU);
#pragma unroll
    for (int s2 = 0; s2 < 8; s2++) {
      int u = ub + s2 * 8;
      unsigned val = (unsigned)Ut[2 * u][h] | ((unsigned)Ut[2 * u + 1][h] << 16);
      dst[u] = val;
    }
  }
}

// ---------------------------------------------------------------------------
// gemmA: per h, P[n2][col] = V[h](64x128) @ U[h](128 x col). P stored fp16
// transposed: P[h][col][n2].
// ---------------------------------------------------------------------------
__global__ __launch_bounds__(256) void gemmA_kernel(
    const _Float16* __restrict__ V, const _Float16* __restrict__ U,
    _Float16* __restrict__ P) {
  __shared__ _Float16 As[64 * 72];
  __shared__ _Float16 Bs[64 * 72];
  int h = blockIdx.x, c0 = blockIdx.y * 64;
  int t = threadIdx.x;
  int w = t >> 6, lane = t & 63, lr = lane & 15, quad = lane >> 4;
  int mh = w & 1, nh = w >> 1;
  f32x4 acc[2][2];
#pragma unroll
  for (int i = 0; i < 2; i++)
#pragma unroll
    for (int j = 0; j < 2; j++) acc[i][j] = (f32x4)(0.0f);

  for (int kt = 0; kt < 128; kt += 64) {
#pragma unroll
    for (int i = 0; i < 2; i++) {
      int idx = t + 256 * i;
      int m = idx >> 3, q = idx & 7;
      *(uint4*)&As[m * 72 + q * 8] =
          *(const uint4*)(V + ((size_t)h * 64 + m) * 128 + kt + q * 8);
      *(uint4*)&Bs[m * 72 + q * 8] =
          *(const uint4*)(U + ((size_t)h * COLS + c0 + m) * KU + kt + q * 8);
    }
    __syncthreads();
#pragma unroll
    for (int ks = 0; ks < 2; ks++) {
      f16x8 af[2], bf[2];
#pragma unroll
      for (int i = 0; i < 2; i++)
        af[i] = *(const f16x8*)&As[(mh * 32 + i * 16 + lr) * 72 + ks * 32 + quad * 8];
#pragma unroll
      for (int j = 0; j < 2; j++)
        bf[j] = *(const f16x8*)&Bs[(nh * 32 + j * 16 + lr) * 72 + ks * 32 + quad * 8];
#pragma unroll
      for (int i = 0; i < 2; i++)
#pragma unroll
        for (int j = 0; j < 2; j++)
          acc[i][j] = __builtin_amdgcn_mfma_f32_16x16x32_f16(af[i], bf[j], acc[i][j], 0, 0, 0);
    }
    __syncthreads();
  }
#pragma unroll
  for (int i = 0; i < 2; i++) {
#pragma unroll
    for (int j = 0; j < 2; j++) {
      int n2 = mh * 32 + i * 16 + quad * 4;
      int col = c0 + nh * 32 + j * 16 + lr;
      f32x4 a = acc[i][j];
      uint2 r;
      r.x = pk2h(a[0], a[1]);
      r.y = pk2h(a[2], a[3]);
      *(uint2*)(P + ((size_t)h * COLS + col) * 64 + n2) = r;
    }
  }
}

// ---------------------------------------------------------------------------
// combine: serial scan over chunks per (b,h,n): carry' = w^128*carry + P[c].
// Writes exclusive-prefix carry (fp16) into Ubig[h][col][128+n2].
// (Tail-chunk P[39] only affects the discarded post-loop carry.)
// ---------------------------------------------------------------------------
__global__ __launch_bounds__(256) void combine_kernel(
    const _Float16* __restrict__ P, _Float16* __restrict__ U,
    const float* __restrict__ WLc) {
  int h = blockIdx.x >> 1;
  int bh = blockIdx.x & 1;
  int n = threadIdx.x & 31;
  int b = bh * 8 + (threadIdx.x >> 5);
  float wre = WLc[h * 64 + 2 * n], wim = WLc[h * 64 + 2 * n + 1];
  const _Float16* p = P + ((size_t)h * COLS + (size_t)b * NCH) * 64 + 2 * n;
  _Float16* u = U + ((size_t)h * COLS + (size_t)b * NCH) * KU + 128 + 2 * n;
  float cre = 0.0f, cim = 0.0f;
#pragma unroll 4
  for (int c = 0; c < NCH; c++) {
    float2 v = upk2(*(const unsigned*)(p + (size_t)c * 64));
    *(unsigned*)(u + (size_t)c * KU) = pk2h(cre, cim);
    float nre = fmaf(wre, cre, v.x) - wim * cim;
    float nim = fmaf(wre, cim, v.y) + wim * cre;
    cre = nre; cim = nim;
  }
}

// ---------------------------------------------------------------------------
// gemmC: per h, Y[t=128][col] = Tc[h](128x192) @ [u; s0](192 x col), fused
// GELU, fp16 out Yt[h][col][t].
// ---------------------------------------------------------------------------
__global__ __launch_bounds__(256) void gemmC_kernel(
    const _Float16* __restrict__ Tc, const _Float16* __restrict__ U,
    _Float16* __restrict__ Yt) {
  __shared__ _Float16 As[128 * 72];
  __shared__ _Float16 Bs[64 * 72];
  int h = blockIdx.x, c0 = blockIdx.y * 64;
  int t = threadIdx.x;
  int w = t >> 6, lane = t & 63, lr = lane & 15, quad = lane >> 4;
  f32x4 acc[2][4];
#pragma unroll
  for (int i = 0; i < 2; i++)
#pragma unroll
    for (int j = 0; j < 4; j++) acc[i][j] = (f32x4)(0.0f);

  for (int kt = 0; kt < KU; kt += 64) {
#pragma unroll
    for (int i = 0; i < 4; i++) {
      int idx = t + 256 * i;
      int m = idx >> 3, q = idx & 7;
      *(uint4*)&As[m * 72 + q * 8] =
          *(const uint4*)(Tc + ((size_t)h * 128 + m) * KU + kt + q * 8);
    }
#pragma unroll
    for (int i = 0; i < 2; i++) {
      int idx = t + 256 * i;
      int jj = idx >> 3, q = idx & 7;
      *(uint4*)&Bs[jj * 72 + q * 8] =
          *(const uint4*)(U + ((size_t)h * COLS + c0 + jj) * KU + kt + q * 8);
    }
    __syncthreads();
#pragma unroll
    for (int ks = 0; ks < 2; ks++) {
      f16x8 af[2], bf[4];
#pragma unroll
      for (int i = 0; i < 2; i++)
        af[i] = *(const f16x8*)&As[(w * 32 + i * 16 + lr) * 72 + ks * 32 + quad * 8];
#pragma unroll
      for (int j = 0; j < 4; j++)
        bf[j] = *(const f16x8*)&Bs[(j * 16 + lr) * 72 + ks * 32 + quad * 8];
#pragma unroll
      for (int i = 0; i < 2; i++)
#pragma unroll
        for (int j = 0; j < 4; j++)
          acc[i][j] = __builtin_amdgcn_mfma_f32_16x16x32_f16(af[i], bf[j], acc[i][j], 0, 0, 0);
    }
    __syncthreads();
  }
#pragma unroll
  for (int i = 0; i < 2; i++) {
#pragma unroll
    for (int j = 0; j < 4; j++) {
      int tb = w * 32 + i * 16 + quad * 4;
      int col = c0 + j * 16 + lr;
      f32x4 a = acc[i][j];
      uint2 r;
      r.x = pk2h(fast_gelu(a[0]), fast_gelu(a[1]));
      r.y = pk2h(fast_gelu(a[2]), fast_gelu(a[3]));
      *(uint2*)(Yt + ((size_t)h * COLS + col) * 128 + tb) = r;
    }
  }
}

// ---------------------------------------------------------------------------
// GLU FFN via fp16 MFMA. With LC=128, one block = one chunk column: A operand
// read DIRECTLY from Yt[h][col][t] (t-contiguous 16B loads) and transposed
// into LDS As[t][h] via shfl-pairing + b32 writes, XOR-swizzled:
//   byte(t, h) = t*128 + ((h>>3) ^ (t&7) ^ ((t>>3)&7))*16 + (h&7)*2
// (conflict-free on write: 32 active lanes -> 16 banks 2-way; conflict-free
// on fragment read: 8 swizzle slots x 4 banks). ytr kernel is deleted.
// Stream holds z; X = g1*sigmoid(g2) + z in place, LDS-staged epilogue.
// ---------------------------------------------------------------------------
__global__ __launch_bounds__(256) void gemm_glu_mfma(
    const _Float16* __restrict__ Yt, const _Float16* __restrict__ Wt,
    const float* __restrict__ bg, _Float16* __restrict__ Xio) {
  __shared__ uint4 smemq[2304];                 // 36864 B
  _Float16* As = (_Float16*)smemq;              // 128 t x 64 h swizzled, 16384 B
  _Float16* Bs = (_Float16*)smemq + 128 * 64;   // 128 col x 72, 18432 B
  float* gl = (float*)smemq;                    // epilogue alias: 128*68*4 = 34816 B
  int t = threadIdx.x;
  int col = blockIdx.x;                         // 0..639
  int bI = col / NCH, pt = col % NCH;
  int len = (pt == NCH - 1) ? TAIL : 128;
  size_t row0 = (size_t)bI * LL + (size_t)pt * 128;
  int c0 = blockIdx.y * 64;
  int w = t >> 6, lane = t & 63;
  int lr = lane & 15, quad = lane >> 4;
  int rh = w & 1, ch = w >> 1;
  int oct = lane & 15, hq = lane >> 4;
  f32x4 acc[4][4];
#pragma unroll
  for (int i = 0; i < 4; i++)
#pragma unroll
    for (int j = 0; j < 4; j++) acc[i][j] = (f32x4)(0.0f);

  int jb[4] = {ch * 32, ch * 32 + 16, 64 + ch * 32, 80 + ch * 32};

  for (int kt = 0; kt < HH; kt += 64) {
    // --- A: transpose-stage Yt[kt..kt+63][col][0..127] into As[t][h] ---
#pragma unroll
    for (int p = 0; p < 4; p++) {
      int hl = p * 16 + w * 4 + hq;   // 0..63
      uint4 v = *(const uint4*)(Yt + ((size_t)(kt + hl) * COLS + col) * 128 + oct * 8);
      uint4 pv;
      pv.x = __shfl_xor((int)v.x, 16);
      pv.y = __shfl_xor((int)v.y, 16);
      pv.z = __shfl_xor((int)v.z, 16);
      pv.w = __shfl_xor((int)v.w, 16);
      if ((hq & 1) == 0) {            // even h writes the {h, h+1} pair
        const unsigned short* sv = (const unsigned short*)&v;
        const unsigned short* qv = (const unsigned short*)&pv;
        int h8 = hl >> 3;
        int hb2 = (hl & 7) * 2;
#pragma unroll
        for (int j = 0; j < 8; j++) {
          int tt = oct * 8 + j;
          int so = h8 ^ (tt & 7) ^ ((tt >> 3) & 7);
          *(unsigned*)((char*)As + tt * 128 + so * 16 + hb2) =
              (unsigned)sv[j] | ((unsigned)qv[j] << 16);
        }
      }
    }
    // --- B: Wt staging (unchanged, padded stride 72) ---
#pragma unroll
    for (int i = 0; i < 4; i++) {
      int idx = t + 256 * i;
      int jj = idx >> 3, q = idx & 7;
      int colw = (jj < 64) ? (c0 + jj) : (192 + c0 + jj);
      *(uint4*)&Bs[jj * 72 + q * 8] =
          *(const uint4*)(Wt + (size_t)colw * HH + kt + q * 8);
    }
    __syncthreads();
#pragma unroll
    for (int ks = 0; ks < 2; ks++) {
      f16x8 af[4], bf[4];
#pragma unroll
      for (int i = 0; i < 4; i++) {
        int tt = rh * 64 + i * 16 + lr;
        int so = (ks * 4 + quad) ^ (tt & 7) ^ ((tt >> 3) & 7);
        af[i] = *(const f16x8*)((const char*)As + tt * 128 + so * 16);
      }
#pragma unroll
      for (int j = 0; j < 4; j++)
        bf[j] = *(const f16x8*)&Bs[(jb[j] + lr) * 72 + ks * 32 + quad * 8];
#pragma unroll
      for (int i = 0; i < 4; i++)
#pragma unroll
        for (int j = 0; j < 4; j++)
          acc[i][j] = __builtin_amdgcn_mfma_f32_16x16x32_f16(af[i], bf[j], acc[i][j], 0, 0, 0);
    }
    __syncthreads();
  }

  // Stage g = g1*sigmoid(g2) into gl[128][68] (f32)
#pragma unroll
  for (int i = 0; i < 4; i++) {
#pragma unroll
    for (int r = 0; r < 4; r++) {
      int rowl = rh * 64 + i * 16 + quad * 4 + r;
#pragma unroll
      for (int jp = 0; jp < 2; jp++) {
        int hl = ch * 32 + jp * 16 + lr;
        int h = c0 + hl;
        float g1 = acc[i][jp][r] + bg[h];
        float g2 = acc[i][jp + 2][r] + bg[256 + h];
        float sig = __builtin_amdgcn_rcpf(1.0f + __expf(-g2));
        gl[rowl * 68 + hl] = g1 * sig;
      }
    }
  }
  __syncthreads();

  // Coalesced residual-add pass (guard tail rows)
#pragma unroll
  for (int rep = 0; rep < 4; rep++) {
    int lin = rep * 256 + t;
    int rowl = lin >> 3, hc = lin & 7;
    if (rowl < len) {
      size_t row = row0 + rowl;
      int hb = c0 + hc * 8;
      uint4 zv = *(const uint4*)(Xio + row * HH + hb);
      float2 z01 = upk2(zv.x), z23 = upk2(zv.y), z45 = upk2(zv.z), z67 = upk2(zv.w);
      const float* gp = &gl[rowl * 68 + hc * 8];
      uint4 r;
      r.x = pk2h(gp[0] + z01.x, gp[1] + z01.y);
      r.y = pk2h(gp[2] + z23.x, gp[3] + z23.y);
      r.z = pk2h(gp[4] + z45.x, gp[5] + z45.y);
      r.w = pk2h(gp[6] + z67.x, gp[7] + z67.y);
      *(uint4*)(Xio + row * HH + hb) = r;
    }
  }
}

// ---------------------------------------------------------------------------
extern "C" void kernel_launch(void* const* d_in, const int* in_sizes, int n_in,
                              void* d_out, int out_size, void* d_ws, size_t ws_size,
                              hipStream_t stream) {
  const float* x      = (const float*)d_in[0];
  const float* Win    = (const float*)d_in[1];
  const float* bin    = (const float*)d_in[2];
  const float* ln_g   = (const float*)d_in[3];
  const float* ln_b   = (const float*)d_in[4];
  const float* log_dt = (const float*)d_in[5];
  const float* logA   = (const float*)d_in[6];
  const float* A_im   = (const float*)d_in[7];
  const float* Cp     = (const float*)d_in[8];
  const float* Dv     = (const float*)d_in[9];
  const float* Wglu   = (const float*)d_in[10];
  const float* bglu   = (const float*)d_in[11];
  const float* fn_g   = (const float*)d_in[12];
  const float* fn_b   = (const float*)d_in[13];
  float* out = (float*)d_out;
  float* ws = (float*)d_ws;

  // Workspace layout (float units; offsets unchanged from round 6)
  _Float16* Xs = (_Float16*)ws;                        // fp16 token stream (z/x in place)
  float* Pf = ws + (size_t)NROWS * HH;                 // P/Yt region (10.5M floats)
  _Float16* Tc = (_Float16*)(Pf + (size_t)HH * COLS * 64);
  _Float16* V  = Tc + (size_t)HH * 128 * KU;
  _Float16* U  = V + (size_t)HH * 64 * 128;
  _Float16* Wt = U + (size_t)HH * COLS * KU;
  float* WLc = (float*)(Wt + (size_t)NLAYER * 512 * HH);
  _Float16* P16 = (_Float16*)Pf;                       // fp16 chunk states (21 MB)
  _Float16* Yt  = (_Float16*)Pf;                       // fp16 [h][col][128] (42 MB, after combine)

  wt_kernel<<<(NLAYER * 512) / 256, 256, 0, stream>>>(Wglu, Wt);
  proj_kernel<<<2048, 256, 0, stream>>>(x, Win, bin, Xs);

  for (int l = 0; l < NLAYER; l++) {
    paramT_kernel<<<HH, 128, 0, stream>>>(log_dt, logA, A_im, Cp, Dv, l, Tc, V, WLc);
    lnU_kernel<<<COLS, 256, 0, stream>>>(Xs, U, ln_g + l * HH, ln_b + l * HH);
    gemmA_kernel<<<dim3(HH, COLS / 64), 256, 0, stream>>>(V, U, P16);
    combine_kernel<<<HH * 2, 256, 0, stream>>>(P16, U, WLc);
    gemmC_kernel<<<dim3(HH, COLS / 64), 256, 0, stream>>>(Tc, U, Yt);
    gemm_glu_mfma<<<dim3(COLS, 4), 256, 0, stream>>>(
        Yt, Wt + (size_t)l * 512 * HH, bglu + (size_t)l * 2 * HH, Xs);
  }
  ln_kernel<<<NROWS / 4, 256, 0, stream>>>(Xs, out, fn_g, fn_b);
}

// Round 8
// 901.932 us; speedup vs baseline: 1.8757x; 1.1296x over previous
//
#include <hip/hip_runtime.h>
#include <math.h>

// Problem constants
#define BB 16
#define LL 5000
#define DIN 12
#define HH 256
#define NN 32
#define NLAYER 4
#define LC 128               // chunk length (last chunk per batch row = 8)
#define NCH 40               // chunks per batch row (39*128 + 8 = 5000)
#define TAIL 8               // length of last chunk
#define COLS (BB*NCH)        // 640 chunk-columns; col = b*40 + pt
#define NROWS (BB*LL)        // 80000 token rows
#define KU 192               // Ubig inner dim: 128 (tau) + 64 (state re/im)

typedef __attribute__((ext_vector_type(8))) _Float16 f16x8;
typedef __attribute__((ext_vector_type(4))) float f32x4;

// fast tanh-GELU (matches jax.nn.gelu approximate): a*sigmoid(2*inner)
__device__ __forceinline__ float fast_gelu(float a) {
  float z = fmaf(0.0713548163f * a, a * a, 1.5957691216f * a);
  float e = __expf(-z);
  return a * __builtin_amdgcn_rcpf(1.0f + e);
}

__device__ __forceinline__ unsigned pk2h(float a, float b) {
  union { _Float16 h[2]; unsigned u; } x;
  x.h[0] = (_Float16)a; x.h[1] = (_Float16)b;
  return x.u;
}

__device__ __forceinline__ float2 upk2(unsigned u) {
  union { unsigned u; _Float16 h[2]; } x;
  x.u = u;
  return make_float2((float)x.h[0], (float)x.h[1]);
}

// ---------------------------------------------------------------------------
// Per-layer precompute (LC=128):
//   Tc[h][t][k] : k<128 -> Toeplitz K[t-k] (+D diag); k>=128 -> Bnd[t][n2]
//   V[h][n2][tau] = {Re,Im}(w^{127-tau});  WLc[h][n2] = w^128
// ---------------------------------------------------------------------------
__global__ __launch_bounds__(128) void paramT_kernel(
    const float* __restrict__ log_dt, const float* __restrict__ logA_re,
    const float* __restrict__ A_im, const float* __restrict__ Cp,
    const float* __restrict__ Dv, int l,
    _Float16* __restrict__ Tc, _Float16* __restrict__ V, float* __restrict__ WLc) {
  int h = blockIdx.x;
  int t = threadIdx.x;           // 0..127
  __shared__ float s_are[NN], s_aim[NN], s_cre[NN], s_cim[NN];
  __shared__ float s_K[128];
  if (t < NN) {
    int n = t;
    int idx = (l * HH + h) * NN + n;
    float dt = expf(log_dt[l * HH + h]);
    float Are = -expf(logA_re[idx]);
    float Aim = A_im[idx];
    float are = Are * dt, aim = Aim * dt;
    float e = expf(are);
    float wre = e * cosf(aim), wim = e * sinf(aim);
    float cr = Cp[2 * idx], ci = Cp[2 * idx + 1];
    float nre = wre - 1.0f, nim = wim;
    float tre = cr * nre - ci * nim;
    float tim = cr * nim + ci * nre;
    float inv = 1.0f / (Are * Are + Aim * Aim);
    s_are[n] = are; s_aim[n] = aim;
    s_cre[n] = 2.0f * (tre * Are + tim * Aim) * inv;
    s_cim[n] = 2.0f * (tim * Are - tre * Aim) * inv;
    float eL = expf(128.0f * are);
    float ang = 128.0f * aim;
    WLc[h * 64 + 2 * n] = eL * cosf(ang);
    WLc[h * 64 + 2 * n + 1] = eL * sinf(ang);
  }
  __syncthreads();
  {
    float ksum = 0.0f;
    unsigned* brow = (unsigned*)(Tc + ((size_t)h * 128 + t) * KU + 128);
    for (int n = 0; n < NN; n++) {
      float are = s_are[n], aim = s_aim[n];
      float cre = s_cre[n], cim = s_cim[n];
      float ft = (float)t;
      float E = expf(are * ft);
      float a = aim * ft;
      float wtre = E * cosf(a), wtim = E * sinf(a);        // w^t
      ksum = fmaf(cre, wtre, ksum);
      ksum = fmaf(-cim, wtim, ksum);
      float ew = expf(are);
      float wre = ew * cosf(aim), wim = ew * sinf(aim);    // w
      float wpre = wtre * wre - wtim * wim;                // w^{t+1}
      float wpim = wtre * wim + wtim * wre;
      float bre = cre * wpre - cim * wpim;
      float bim = -(cre * wpim + cim * wpre);
      brow[n] = pk2h(bre, bim);
      float fk = (float)(127 - t);
      float E2 = expf(are * fk);
      float a2 = aim * fk;
      V[((size_t)h * 64 + 2 * n) * 128 + t] = (_Float16)(E2 * cosf(a2));
      V[((size_t)h * 64 + 2 * n + 1) * 128 + t] = (_Float16)(E2 * sinf(a2));
    }
    s_K[t] = ksum;
  }
  __syncthreads();
  float D = Dv[l * HH + h];
  unsigned* row = (unsigned*)(Tc + ((size_t)h * 128 + t) * KU);
  for (int q = 0; q < 64; q++) {
    float v0 = 0.0f, v1 = 0.0f;
    int d0 = t - 2 * q;
    int d1 = d0 - 1;
    if (d0 >= 0) v0 = s_K[d0] + (d0 == 0 ? D : 0.0f);
    if (d1 >= 0) v1 = s_K[d1] + (d1 == 0 ? D : 0.0f);
    row[q] = pk2h(v0, v1);
  }
}

// ---------------------------------------------------------------------------
// W_glu transpose+cast to fp16: Wt[l][col(512)][k(256)]
// ---------------------------------------------------------------------------
__global__ __launch_bounds__(256) void wt_kernel(
    const float* __restrict__ W, _Float16* __restrict__ Wt) {
  int gid = blockIdx.x * 256 + threadIdx.x;
  int l = gid >> 9, col = gid & 511;
  const float* w = W + (size_t)l * HH * 512 + col;
  _Float16* o = Wt + (size_t)gid * HH;
  for (int k = 0; k < HH; k++) o[k] = (_Float16)(w[(size_t)k * 512]);
}

// ---------------------------------------------------------------------------
// Input projection -> fp16 stream.
// ---------------------------------------------------------------------------
__global__ __launch_bounds__(256) void proj_kernel(
    const float* __restrict__ x, const float* __restrict__ Win,
    const float* __restrict__ bin, _Float16* __restrict__ X) {
  int tp = threadIdx.x & 127, rs = threadIdx.x >> 7;
  int h0 = 2 * tp;
  float w0[DIN], w1[DIN];
#pragma unroll
  for (int k = 0; k < DIN; k++) {
    w0[k] = Win[k * HH + h0];
    w1[k] = Win[k * HH + h0 + 1];
  }
  float b0 = bin[h0], b1 = bin[h0 + 1];
  for (int row = blockIdx.x * 2 + rs; row < NROWS; row += gridDim.x * 2) {
    float a0 = b0, a1 = b1;
#pragma unroll
    for (int k = 0; k < DIN; k++) {
      float xv = x[(size_t)row * DIN + k];
      a0 = fmaf(xv, w0[k], a0);
      a1 = fmaf(xv, w1[k], a1);
    }
    *(unsigned*)(X + (size_t)row * HH + h0) = pk2h(a0, a1);
  }
}

// ---------------------------------------------------------------------------
// Final LayerNorm: fp16 stream in, f32 out.
// ---------------------------------------------------------------------------
__global__ __launch_bounds__(256) void ln_kernel(
    const _Float16* __restrict__ in, float* __restrict__ out,
    const float* __restrict__ g, const float* __restrict__ b) {
  int wave = threadIdx.x >> 6, lane = threadIdx.x & 63;
  int row = blockIdx.x * 4 + wave;
  uint2 pv = *(const uint2*)(in + (size_t)row * HH + 4 * lane);
  float2 v01 = upk2(pv.x), v23 = upk2(pv.y);
  float s = v01.x + v01.y + v23.x + v23.y;
  float q = v01.x * v01.x + v01.y * v01.y + v23.x * v23.x + v23.y * v23.y;
#pragma unroll
  for (int m = 1; m < 64; m <<= 1) { s += __shfl_xor(s, m); q += __shfl_xor(q, m); }
  float mean = s * (1.0f / HH);
  float var = q * (1.0f / HH) - mean * mean;
  float rstd = rsqrtf(var + 1e-5f);
  float4 gg = ((const float4*)g)[lane];
  float4 bb = ((const float4*)b)[lane];
  float4 o;
  o.x = (v01.x - mean) * rstd * gg.x + bb.x;
  o.y = (v01.y - mean) * rstd * gg.y + bb.y;
  o.z = (v23.x - mean) * rstd * gg.z + bb.z;
  o.w = (v23.y - mean) * rstd * gg.w + bb.w;
  ((float4*)(out + (size_t)row * HH))[lane] = o;
}

// ---------------------------------------------------------------------------
// Per-layer LN (in place on fp16 stream: x -> z) + transposed fp16 export
// U[h][col][tau]. Ut split into two 64-tau halves (33 KB LDS -> 4 blocks/CU).
// ---------------------------------------------------------------------------
__global__ __launch_bounds__(256) void lnU_kernel(
    _Float16* __restrict__ stream, _Float16* __restrict__ U,
    const float* __restrict__ g, const float* __restrict__ b) {
  __shared__ unsigned short Ut[64][260];   // [tau-local][h], padded stride
  int col = blockIdx.x;
  int bI = col / NCH, cI = col % NCH;
  int len = (cI == NCH - 1) ? TAIL : 128;
  int wave = threadIdx.x >> 6, lane = threadIdx.x & 63;
  float4 gg = ((const float4*)g)[lane];
  float4 bv = ((const float4*)b)[lane];
  size_t base = ((size_t)bI * LL + (size_t)cI * 128) * HH;
#pragma unroll
  for (int half = 0; half < 2; half++) {
    if (half) __syncthreads();           // previous export done before overwrite
    int t0 = half * 64;
    int lenh = len - t0;
    lenh = lenh < 0 ? 0 : (lenh > 64 ? 64 : lenh);
    for (int idx = threadIdx.x; idx < (64 - lenh) * 260; idx += 256) {
      int r = idx / 260;
      Ut[lenh + r][idx - r * 260] = 0;
    }
    for (int it = 0; it < 16; it++) {
      int tl = it * 4 + wave;
      if (tl < lenh) {
        int tau = t0 + tl;
        uint2 pv = *(const uint2*)(stream + base + (size_t)tau * HH + 4 * lane);
        float2 v01 = upk2(pv.x), v23 = upk2(pv.y);
        float s = v01.x + v01.y + v23.x + v23.y;
        float q = v01.x * v01.x + v01.y * v01.y + v23.x * v23.x + v23.y * v23.y;
#pragma unroll
        for (int m = 1; m < 64; m <<= 1) { s += __shfl_xor(s, m); q += __shfl_xor(q, m); }
        float mean = s * (1.0f / HH);
        float var = q * (1.0f / HH) - mean * mean;
        float rstd = rsqrtf(var + 1e-5f);
        float o0 = (v01.x - mean) * rstd * gg.x + bv.x;
        float o1 = (v01.y - mean) * rstd * gg.y + bv.y;
        float o2 = (v23.x - mean) * rstd * gg.z + bv.z;
        float o3 = (v23.y - mean) * rstd * gg.w + bv.w;
        uint2 p;
        p.x = pk2h(o0, o1);
        p.y = pk2h(o2, o3);
        *(uint2*)(stream + base + (size_t)tau * HH + 4 * lane) = p;  // residual = z
        *(uint2*)&Ut[tl][4 * lane] = p;
      }
    }
    __syncthreads();
    // export this half: per h, 32 u32 words (64 tau)
    for (int rep = 0; rep < 8; rep++) {
      int linear = rep * 256 + threadIdx.x;
      int h = linear >> 3, ub = linear & 7;
      unsigned* dst = (unsigned*)(U + ((size_t)h * COLS + col) * KU) + half * 32;
#pragma unroll
      for (int s2 = 0; s2 < 4; s2++) {
        int u = ub + s2 * 8;
        dst[u] = (unsigned)Ut[2 * u][h] | ((unsigned)Ut[2 * u + 1][h] << 16);
      }
    }
  }
}

// ---------------------------------------------------------------------------
// gemmA: per h, P[n2][col] = V[h](64x128) @ U[h](128 x col). 128-col B-tile.
// P stored fp16 transposed: P[h][col][n2].
// ---------------------------------------------------------------------------
__global__ __launch_bounds__(256) void gemmA_kernel(
    const _Float16* __restrict__ V, const _Float16* __restrict__ U,
    _Float16* __restrict__ P) {
  __shared__ _Float16 As[64 * 72];
  __shared__ _Float16 Bs[128 * 72];
  int h = blockIdx.x, c0 = blockIdx.y * 128;
  int t = threadIdx.x;
  int w = t >> 6, lane = t & 63, lr = lane & 15, quad = lane >> 4;
  int mh = w & 1, nh = w >> 1;
  f32x4 acc[2][4];
#pragma unroll
  for (int i = 0; i < 2; i++)
#pragma unroll
    for (int j = 0; j < 4; j++) acc[i][j] = (f32x4)(0.0f);

  for (int kt = 0; kt < 128; kt += 64) {
#pragma unroll
    for (int i = 0; i < 2; i++) {
      int idx = t + 256 * i;
      int m = idx >> 3, q = idx & 7;
      *(uint4*)&As[m * 72 + q * 8] =
          *(const uint4*)(V + ((size_t)h * 64 + m) * 128 + kt + q * 8);
    }
#pragma unroll
    for (int i = 0; i < 4; i++) {
      int idx = t + 256 * i;
      int jj = idx >> 3, q = idx & 7;
      *(uint4*)&Bs[jj * 72 + q * 8] =
          *(const uint4*)(U + ((size_t)h * COLS + c0 + jj) * KU + kt + q * 8);
    }
    __syncthreads();
#pragma unroll
    for (int ks = 0; ks < 2; ks++) {
      f16x8 af[2], bf[4];
#pragma unroll
      for (int i = 0; i < 2; i++)
        af[i] = *(const f16x8*)&As[(mh * 32 + i * 16 + lr) * 72 + ks * 32 + quad * 8];
#pragma unroll
      for (int j = 0; j < 4; j++)
        bf[j] = *(const f16x8*)&Bs[(nh * 64 + j * 16 + lr) * 72 + ks * 32 + quad * 8];
#pragma unroll
      for (int i = 0; i < 2; i++)
#pragma unroll
        for (int j = 0; j < 4; j++)
          acc[i][j] = __builtin_amdgcn_mfma_f32_16x16x32_f16(af[i], bf[j], acc[i][j], 0, 0, 0);
    }
    __syncthreads();
  }
#pragma unroll
  for (int i = 0; i < 2; i++) {
#pragma unroll
    for (int j = 0; j < 4; j++) {
      int n2 = mh * 32 + i * 16 + quad * 4;
      int colx = c0 + nh * 64 + j * 16 + lr;
      f32x4 a = acc[i][j];
      uint2 r;
      r.x = pk2h(a[0], a[1]);
      r.y = pk2h(a[2], a[3]);
      *(uint2*)(P + ((size_t)h * COLS + colx) * 64 + n2) = r;
    }
  }
}

// ---------------------------------------------------------------------------
// combine: serial scan over chunks per (b,h,n): carry' = w^128*carry + P[c].
// Writes exclusive-prefix carry (fp16) into Ubig[h][col][128+n2].
// ---------------------------------------------------------------------------
__global__ __launch_bounds__(256) void combine_kernel(
    const _Float16* __restrict__ P, _Float16* __restrict__ U,
    const float* __restrict__ WLc) {
  int h = blockIdx.x >> 1;
  int bh = blockIdx.x & 1;
  int n = threadIdx.x & 31;
  int b = bh * 8 + (threadIdx.x >> 5);
  float wre = WLc[h * 64 + 2 * n], wim = WLc[h * 64 + 2 * n + 1];
  const _Float16* p = P + ((size_t)h * COLS + (size_t)b * NCH) * 64 + 2 * n;
  _Float16* u = U + ((size_t)h * COLS + (size_t)b * NCH) * KU + 128 + 2 * n;
  float cre = 0.0f, cim = 0.0f;
#pragma unroll 4
  for (int c = 0; c < NCH; c++) {
    float2 v = upk2(*(const unsigned*)(p + (size_t)c * 64));
    *(unsigned*)(u + (size_t)c * KU) = pk2h(cre, cim);
    float nre = fmaf(wre, cre, v.x) - wim * cim;
    float nim = fmaf(wre, cim, v.y) + wim * cre;
    cre = nre; cim = nim;
  }
}

// ---------------------------------------------------------------------------
// gemmC: per h, Y[t=128][col] = Tc[h](128x192) @ [u; s0](192 x col), fused
// GELU, fp16 out Yt[h][col][t]. 128-col B-tile.
// ---------------------------------------------------------------------------
__global__ __launch_bounds__(256) void gemmC_kernel(
    const _Float16* __restrict__ Tc, const _Float16* __restrict__ U,
    _Float16* __restrict__ Yt) {
  __shared__ _Float16 As[128 * 72];
  __shared__ _Float16 Bs[128 * 72];
  int h = blockIdx.x, c0 = blockIdx.y * 128;
  int t = threadIdx.x;
  int w = t >> 6, lane = t & 63, lr = lane & 15, quad = lane >> 4;
  f32x4 acc[2][8];
#pragma unroll
  for (int i = 0; i < 2; i++)
#pragma unroll
    for (int j = 0; j < 8; j++) acc[i][j] = (f32x4)(0.0f);

  for (int kt = 0; kt < KU; kt += 64) {
#pragma unroll
    for (int i = 0; i < 4; i++) {
      int idx = t + 256 * i;
      int m = idx >> 3, q = idx & 7;
      *(uint4*)&As[m * 72 + q * 8] =
          *(const uint4*)(Tc + ((size_t)h * 128 + m) * KU + kt + q * 8);
    }
#pragma unroll
    for (int i = 0; i < 4; i++) {
      int idx = t + 256 * i;
      int jj = idx >> 3, q = idx & 7;
      *(uint4*)&Bs[jj * 72 + q * 8] =
          *(const uint4*)(U + ((size_t)h * COLS + c0 + jj) * KU + kt + q * 8);
    }
    __syncthreads();
#pragma unroll
    for (int ks = 0; ks < 2; ks++) {
      f16x8 af[2], bf[8];
#pragma unroll
      for (int i = 0; i < 2; i++)
        af[i] = *(const f16x8*)&As[(w * 32 + i * 16 + lr) * 72 + ks * 32 + quad * 8];
#pragma unroll
      for (int j = 0; j < 8; j++)
        bf[j] = *(const f16x8*)&Bs[(j * 16 + lr) * 72 + ks * 32 + quad * 8];
#pragma unroll
      for (int i = 0; i < 2; i++)
#pragma unroll
        for (int j = 0; j < 8; j++)
          acc[i][j] = __builtin_amdgcn_mfma_f32_16x16x32_f16(af[i], bf[j], acc[i][j], 0, 0, 0);
    }
    __syncthreads();
  }
#pragma unroll
  for (int i = 0; i < 2; i++) {
#pragma unroll
    for (int j = 0; j < 8; j++) {
      int tb = w * 32 + i * 16 + quad * 4;
      int colx = c0 + j * 16 + lr;
      f32x4 a = acc[i][j];
      uint2 r;
      r.x = pk2h(fast_gelu(a[0]), fast_gelu(a[1]));
      r.y = pk2h(fast_gelu(a[2]), fast_gelu(a[3]));
      *(uint2*)(Yt + ((size_t)h * COLS + colx) * 128 + tb) = r;
    }
  }
}

// ---------------------------------------------------------------------------
// GLU FFN via fp16 MFMA. A operand read from Yt[h][col][t] and transposed
// into LDS As[t][h] (swizzled). All 64 lanes write 4 b32 each: even-hq lanes
// take t=j..j+3, odd take j+4..j+7 of the shared (h,h+1) pair (the j^4 flips
// swizzle bit2 -> even/odd lanes use disjoint bank halves: 2-way, free).
// Swizzle: slot so = h8 ^ (t&7) ^ g(t>>3), g(x) = (x + (x>>3)) & 7.
// Stream holds z; X = g1*sigmoid(g2) + z in place, LDS-staged epilogue.
// ---------------------------------------------------------------------------
__global__ __launch_bounds__(256) void gemm_glu_mfma(
    const _Float16* __restrict__ Yt, const _Float16* __restrict__ Wt,
    const float* __restrict__ bg, _Float16* __restrict__ Xio) {
  __shared__ uint4 smemq[2304];                 // 36864 B
  _Float16* As = (_Float16*)smemq;              // 128 t x 64 h swizzled, 16384 B
  _Float16* Bs = (_Float16*)smemq + 128 * 64;   // 128 col x 72, 18432 B
  float* gl = (float*)smemq;                    // epilogue alias: 34816 B
  int t = threadIdx.x;
  int col = blockIdx.x;                         // 0..639
  int bI = col / NCH, pt = col % NCH;
  int len = (pt == NCH - 1) ? TAIL : 128;
  size_t row0 = (size_t)bI * LL + (size_t)pt * 128;
  int c0 = blockIdx.y * 64;
  int w = t >> 6, lane = t & 63;
  int lr = lane & 15, quad = lane >> 4;
  int rh = w & 1, ch = w >> 1;
  int oct = lane & 15, hq = lane >> 4;
  int godd = hq & 1;
  int jbase = godd * 4;
  int goct = (oct + (oct >> 3)) & 7;
  f32x4 acc[4][4];
#pragma unroll
  for (int i = 0; i < 4; i++)
#pragma unroll
    for (int j = 0; j < 4; j++) acc[i][j] = (f32x4)(0.0f);

  int jb[4] = {ch * 32, ch * 32 + 16, 64 + ch * 32, 80 + ch * 32};

  for (int kt = 0; kt < HH; kt += 64) {
    // --- A: transpose-stage Yt[kt..kt+63][col][0..127] into As[t][h] ---
#pragma unroll
    for (int p = 0; p < 4; p++) {
      int hl = p * 16 + w * 4 + hq;   // 0..63 (tile-local h)
      uint4 v = *(const uint4*)(Yt + ((size_t)(kt + hl) * COLS + col) * 128 + oct * 8);
      uint4 pv;
      pv.x = __shfl_xor((int)v.x, 16);
      pv.y = __shfl_xor((int)v.y, 16);
      pv.z = __shfl_xor((int)v.z, 16);
      pv.w = __shfl_xor((int)v.w, 16);
      // low-h / high-h words for this lane's 4 t's (t = oct*8 + jbase + 0..3)
      unsigned a0 = godd ? pv.z : v.x;
      unsigned a1 = godd ? pv.w : v.y;
      unsigned b0 = godd ? v.z : pv.x;
      unsigned b1 = godd ? v.w : pv.y;
      unsigned p0 = (a0 & 0xffffu) | (b0 << 16);
      unsigned p1 = (a0 >> 16) | (b0 & 0xffff0000u);
      unsigned p2 = (a1 & 0xffffu) | (b1 << 16);
      unsigned p3 = (a1 >> 16) | (b1 & 0xffff0000u);
      int soc = (hl >> 3) ^ goct;
      char* basep = (char*)As + oct * 1024 + (hl & 6) * 2;
      { int j = jbase;     *(unsigned*)(basep + j * 128 + ((soc ^ j) * 16)) = p0; }
      { int j = jbase + 1; *(unsigned*)(basep + j * 128 + ((soc ^ j) * 16)) = p1; }
      { int j = jbase + 2; *(unsigned*)(basep + j * 128 + ((soc ^ j) * 16)) = p2; }
      { int j = jbase + 3; *(unsigned*)(basep + j * 128 + ((soc ^ j) * 16)) = p3; }
    }
    // --- B: Wt staging (padded stride 72) ---
#pragma unroll
    for (int i = 0; i < 4; i++) {
      int idx = t + 256 * i;
      int jj = idx >> 3, q = idx & 7;
      int colw = (jj < 64) ? (c0 + jj) : (192 + c0 + jj);
      *(uint4*)&Bs[jj * 72 + q * 8] =
          *(const uint4*)(Wt + (size_t)colw * HH + kt + q * 8);
    }
    __syncthreads();
#pragma unroll
    for (int ks = 0; ks < 2; ks++) {
      f16x8 af[4], bf[4];
#pragma unroll
      for (int i = 0; i < 4; i++) {
        int tt = rh * 64 + i * 16 + lr;
        int ttg = tt >> 3;
        int so = (ks * 4 + quad) ^ (tt & 7) ^ ((ttg + (ttg >> 3)) & 7);
        af[i] = *(const f16x8*)((const char*)As + tt * 128 + so * 16);
      }
#pragma unroll
      for (int j = 0; j < 4; j++)
        bf[j] = *(const f16x8*)&Bs[(jb[j] + lr) * 72 + ks * 32 + quad * 8];
#pragma unroll
      for (int i = 0; i < 4; i++)
#pragma unroll
        for (int j = 0; j < 4; j++)
          acc[i][j] = __builtin_amdgcn_mfma_f32_16x16x32_f16(af[i], bf[j], acc[i][j], 0, 0, 0);
    }
    __syncthreads();
  }

  // Stage g = g1*sigmoid(g2) into gl[128][68] (f32)
#pragma unroll
  for (int i = 0; i < 4; i++) {
#pragma unroll
    for (int r = 0; r < 4; r++) {
      int rowl = rh * 64 + i * 16 + quad * 4 + r;
#pragma unroll
      for (int jp = 0; jp < 2; jp++) {
        int hl = ch * 32 + jp * 16 + lr;
        int h = c0 + hl;
        float g1 = acc[i][jp][r] + bg[h];
        float g2 = acc[i][jp + 2][r] + bg[256 + h];
        float sig = __builtin_amdgcn_rcpf(1.0f + __expf(-g2));
        gl[rowl * 68 + hl] = g1 * sig;
      }
    }
  }
  __syncthreads();

  // Coalesced residual-add pass (guard tail rows)
#pragma unroll
  for (int rep = 0; rep < 4; rep++) {
    int lin = rep * 256 + t;
    int rowl = lin >> 3, hc = lin & 7;
    if (rowl < len) {
      size_t row = row0 + rowl;
      int hb = c0 + hc * 8;
      uint4 zv = *(const uint4*)(Xio + row * HH + hb);
      float2 z01 = upk2(zv.x), z23 = upk2(zv.y), z45 = upk2(zv.z), z67 = upk2(zv.w);
      const float* gp = &gl[rowl * 68 + hc * 8];
      uint4 r;
      r.x = pk2h(gp[0] + z01.x, gp[1] + z01.y);
      r.y = pk2h(gp[2] + z23.x, gp[3] + z23.y);
      r.z = pk2h(gp[4] + z45.x, gp[5] + z45.y);
      r.w = pk2h(gp[6] + z67.x, gp[7] + z67.y);
      *(uint4*)(Xio + row * HH + hb) = r;
    }
  }
}

// ---------------------------------------------------------------------------
extern "C" void kernel_launch(void* const* d_in, const int* in_sizes, int n_in,
                              void* d_out, int out_size, void* d_ws, size_t ws_size,
                              hipStream_t stream) {
  const float* x      = (const float*)d_in[0];
  const float* Win    = (const float*)d_in[1];
  const float* bin    = (const float*)d_in[2];
  const float* ln_g   = (const float*)d_in[3];
  const float* ln_b   = (const float*)d_in[4];
  const float* log_dt = (const float*)d_in[5];
  const float* logA   = (const float*)d_in[6];
  const float* A_im   = (const float*)d_in[7];
  const float* Cp     = (const float*)d_in[8];
  const float* Dv     = (const float*)d_in[9];
  const float* Wglu   = (const float*)d_in[10];
  const float* bglu   = (const float*)d_in[11];
  const float* fn_g   = (const float*)d_in[12];
  const float* fn_b   = (const float*)d_in[13];
  float* out = (float*)d_out;
  float* ws = (float*)d_ws;

  // Workspace layout (float units; unchanged)
  _Float16* Xs = (_Float16*)ws;                        // fp16 token stream
  float* Pf = ws + (size_t)NROWS * HH;                 // P/Yt region
  _Float16* Tc = (_Float16*)(Pf + (size_t)HH * COLS * 64);
  _Float16* V  = Tc + (size_t)HH * 128 * KU;
  _Float16* U  = V + (size_t)HH * 64 * 128;
  _Float16* Wt = U + (size_t)HH * COLS * KU;
  float* WLc = (float*)(Wt + (size_t)NLAYER * 512 * HH);
  _Float16* P16 = (_Float16*)Pf;                       // fp16 chunk states
  _Float16* Yt  = (_Float16*)Pf;                       // fp16 [h][col][128]

  wt_kernel<<<(NLAYER * 512) / 256, 256, 0, stream>>>(Wglu, Wt);
  proj_kernel<<<2048, 256, 0, stream>>>(x, Win, bin, Xs);

  for (int l = 0; l < NLAYER; l++) {
    paramT_kernel<<<HH, 128, 0, stream>>>(log_dt, logA, A_im, Cp, Dv, l, Tc, V, WLc);
    lnU_kernel<<<COLS, 256, 0, stream>>>(Xs, U, ln_g + l * HH, ln_b + l * HH);
    gemmA_kernel<<<dim3(HH, COLS / 128), 256, 0, stream>>>(V, U, P16);
    combine_kernel<<<HH * 2, 256, 0, stream>>>(P16, U, WLc);
    gemmC_kernel<<<dim3(HH, COLS / 128), 256, 0, stream>>>(Tc, U, Yt);
    gemm_glu_mfma<<<dim3(COLS, 4), 256, 0, stream>>>(
        Yt, Wt + (size_t)l * 512 * HH, bglu + (size_t)l * 2 * HH, Xs);
  }
  ln_kernel<<<NROWS / 4, 256, 0, stream>>>(Xs, out, fn_g, fn_b);
}

// Round 10
// 875.472 us; speedup vs baseline: 1.9323x; 1.0302x over previous
//
#include <hip/hip_runtime.h>
#include <math.h>

// Problem constants
#define BB 16
#define LL 5000
#define DIN 12
#define HH 256
#define NN 32
#define NLAYER 4
#define LC 128               // chunk length (last chunk per batch row = 8)
#define NCH 40               // chunks per batch row (39*128 + 8 = 5000)
#define TAIL 8               // length of last chunk
#define COLS (BB*NCH)        // 640 chunk-columns; col = b*40 + pt
#define NROWS (BB*LL)        // 80000 token rows
#define KU 192               // Ubig inner dim: 128 (tau) + 64 (state re/im)

typedef __attribute__((ext_vector_type(8))) _Float16 f16x8;
typedef __attribute__((ext_vector_type(4))) float f32x4;

// fast tanh-GELU (matches jax.nn.gelu approximate): a*sigmoid(2*inner)
__device__ __forceinline__ float fast_gelu(float a) {
  float z = fmaf(0.0713548163f * a, a * a, 1.5957691216f * a);
  float e = __expf(-z);
  return a * __builtin_amdgcn_rcpf(1.0f + e);
}

__device__ __forceinline__ unsigned pk2h(float a, float b) {
  union { _Float16 h[2]; unsigned u; } x;
  x.h[0] = (_Float16)a; x.h[1] = (_Float16)b;
  return x.u;
}

__device__ __forceinline__ float2 upk2(unsigned u) {
  union { unsigned u; _Float16 h[2]; } x;
  x.u = u;
  return make_float2((float)x.h[0], (float)x.h[1]);
}

// ---------------------------------------------------------------------------
// Per-layer precompute (LC=128):
//   Tc[h][t][k] : k<128 -> Toeplitz K[t-k] (+D diag); k>=128 -> Bnd[t][n2]
//   V[h][n2][tau] = {Re,Im}(w^{127-tau});  WLc[h][n2] = w^128
// ---------------------------------------------------------------------------
__global__ __launch_bounds__(128) void paramT_kernel(
    const float* __restrict__ log_dt, const float* __restrict__ logA_re,
    const float* __restrict__ A_im, const float* __restrict__ Cp,
    const float* __restrict__ Dv, int l,
    _Float16* __restrict__ Tc, _Float16* __restrict__ V, float* __restrict__ WLc) {
  int h = blockIdx.x;
  int t = threadIdx.x;           // 0..127
  __shared__ float s_are[NN], s_aim[NN], s_cre[NN], s_cim[NN];
  __shared__ float s_K[128];
  if (t < NN) {
    int n = t;
    int idx = (l * HH + h) * NN + n;
    float dt = expf(log_dt[l * HH + h]);
    float Are = -expf(logA_re[idx]);
    float Aim = A_im[idx];
    float are = Are * dt, aim = Aim * dt;
    float e = expf(are);
    float wre = e * cosf(aim), wim = e * sinf(aim);
    float cr = Cp[2 * idx], ci = Cp[2 * idx + 1];
    float nre = wre - 1.0f, nim = wim;
    float tre = cr * nre - ci * nim;
    float tim = cr * nim + ci * nre;
    float inv = 1.0f / (Are * Are + Aim * Aim);
    s_are[n] = are; s_aim[n] = aim;
    s_cre[n] = 2.0f * (tre * Are + tim * Aim) * inv;
    s_cim[n] = 2.0f * (tim * Are - tre * Aim) * inv;
    float eL = expf(128.0f * are);
    float ang = 128.0f * aim;
    WLc[h * 64 + 2 * n] = eL * cosf(ang);
    WLc[h * 64 + 2 * n + 1] = eL * sinf(ang);
  }
  __syncthreads();
  {
    float ksum = 0.0f;
    unsigned* brow = (unsigned*)(Tc + ((size_t)h * 128 + t) * KU + 128);
    for (int n = 0; n < NN; n++) {
      float are = s_are[n], aim = s_aim[n];
      float cre = s_cre[n], cim = s_cim[n];
      float ft = (float)t;
      float E = expf(are * ft);
      float a = aim * ft;
      float wtre = E * cosf(a), wtim = E * sinf(a);        // w^t
      ksum = fmaf(cre, wtre, ksum);
      ksum = fmaf(-cim, wtim, ksum);
      float ew = expf(are);
      float wre = ew * cosf(aim), wim = ew * sinf(aim);    // w
      float wpre = wtre * wre - wtim * wim;                // w^{t+1}
      float wpim = wtre * wim + wtim * wre;
      float bre = cre * wpre - cim * wpim;
      float bim = -(cre * wpim + cim * wpre);
      brow[n] = pk2h(bre, bim);
      float fk = (float)(127 - t);
      float E2 = expf(are * fk);
      float a2 = aim * fk;
      V[((size_t)h * 64 + 2 * n) * 128 + t] = (_Float16)(E2 * cosf(a2));
      V[((size_t)h * 64 + 2 * n + 1) * 128 + t] = (_Float16)(E2 * sinf(a2));
    }
    s_K[t] = ksum;
  }
  __syncthreads();
  float D = Dv[l * HH + h];
  unsigned* row = (unsigned*)(Tc + ((size_t)h * 128 + t) * KU);
  for (int q = 0; q < 64; q++) {
    float v0 = 0.0f, v1 = 0.0f;
    int d0 = t - 2 * q;
    int d1 = d0 - 1;
    if (d0 >= 0) v0 = s_K[d0] + (d0 == 0 ? D : 0.0f);
    if (d1 >= 0) v1 = s_K[d1] + (d1 == 0 ? D : 0.0f);
    row[q] = pk2h(v0, v1);
  }
}

// ---------------------------------------------------------------------------
// W_glu transpose+cast to fp16: Wt[l][col(512)][k(256)]
// ---------------------------------------------------------------------------
__global__ __launch_bounds__(256) void wt_kernel(
    const float* __restrict__ W, _Float16* __restrict__ Wt) {
  int gid = blockIdx.x * 256 + threadIdx.x;
  int l = gid >> 9, col = gid & 511;
  const float* w = W + (size_t)l * HH * 512 + col;
  _Float16* o = Wt + (size_t)gid * HH;
  for (int k = 0; k < HH; k++) o[k] = (_Float16)(w[(size_t)k * 512]);
}

// ---------------------------------------------------------------------------
// Input projection -> fp16 stream.
// ---------------------------------------------------------------------------
__global__ __launch_bounds__(256) void proj_kernel(
    const float* __restrict__ x, const float* __restrict__ Win,
    const float* __restrict__ bin, _Float16* __restrict__ X) {
  int tp = threadIdx.x & 127, rs = threadIdx.x >> 7;
  int h0 = 2 * tp;
  float w0[DIN], w1[DIN];
#pragma unroll
  for (int k = 0; k < DIN; k++) {
    w0[k] = Win[k * HH + h0];
    w1[k] = Win[k * HH + h0 + 1];
  }
  float b0 = bin[h0], b1 = bin[h0 + 1];
  for (int row = blockIdx.x * 2 + rs; row < NROWS; row += gridDim.x * 2) {
    float a0 = b0, a1 = b1;
#pragma unroll
    for (int k = 0; k < DIN; k++) {
      float xv = x[(size_t)row * DIN + k];
      a0 = fmaf(xv, w0[k], a0);
      a1 = fmaf(xv, w1[k], a1);
    }
    *(unsigned*)(X + (size_t)row * HH + h0) = pk2h(a0, a1);
  }
}

// ---------------------------------------------------------------------------
// Final LayerNorm: fp16 stream in, f32 out.
// ---------------------------------------------------------------------------
__global__ __launch_bounds__(256) void ln_kernel(
    const _Float16* __restrict__ in, float* __restrict__ out,
    const float* __restrict__ g, const float* __restrict__ b) {
  int wave = threadIdx.x >> 6, lane = threadIdx.x & 63;
  int row = blockIdx.x * 4 + wave;
  uint2 pv = *(const uint2*)(in + (size_t)row * HH + 4 * lane);
  float2 v01 = upk2(pv.x), v23 = upk2(pv.y);
  float s = v01.x + v01.y + v23.x + v23.y;
  float q = v01.x * v01.x + v01.y * v01.y + v23.x * v23.x + v23.y * v23.y;
#pragma unroll
  for (int m = 1; m < 64; m <<= 1) { s += __shfl_xor(s, m); q += __shfl_xor(q, m); }
  float mean = s * (1.0f / HH);
  float var = q * (1.0f / HH) - mean * mean;
  float rstd = rsqrtf(var + 1e-5f);
  float4 gg = ((const float4*)g)[lane];
  float4 bb = ((const float4*)b)[lane];
  float4 o;
  o.x = (v01.x - mean) * rstd * gg.x + bb.x;
  o.y = (v01.y - mean) * rstd * gg.y + bb.y;
  o.z = (v23.x - mean) * rstd * gg.z + bb.z;
  o.w = (v23.y - mean) * rstd * gg.w + bb.w;
  ((float4*)(out + (size_t)row * HH))[lane] = o;
}

// ---------------------------------------------------------------------------
// Per-layer LN (in place on fp16 stream: x -> z) + transposed fp16 export
// U[h][col][tau]. Ut split into two 64-tau halves (33 KB LDS -> 4 blocks/CU).
// ---------------------------------------------------------------------------
__global__ __launch_bounds__(256) void lnU_kernel(
    _Float16* __restrict__ stream, _Float16* __restrict__ U,
    const float* __restrict__ g, const float* __restrict__ b) {
  __shared__ unsigned short Ut[64][260];   // [tau-local][h], padded stride
  int col = blockIdx.x;
  int bI = col / NCH, cI = col % NCH;
  int len = (cI == NCH - 1) ? TAIL : 128;
  int wave = threadIdx.x >> 6, lane = threadIdx.x & 63;
  float4 gg = ((const float4*)g)[lane];
  float4 bv = ((const float4*)b)[lane];
  size_t base = ((size_t)bI * LL + (size_t)cI * 128) * HH;
#pragma unroll
  for (int half = 0; half < 2; half++) {
    if (half) __syncthreads();           // previous export done before overwrite
    int t0 = half * 64;
    int lenh = len - t0;
    lenh = lenh < 0 ? 0 : (lenh > 64 ? 64 : lenh);
    for (int idx = threadIdx.x; idx < (64 - lenh) * 260; idx += 256) {
      int r = idx / 260;
      Ut[lenh + r][idx - r * 260] = 0;
    }
    for (int it = 0; it < 16; it++) {
      int tl = it * 4 + wave;
      if (tl < lenh) {
        int tau = t0 + tl;
        uint2 pv = *(const uint2*)(stream + base + (size_t)tau * HH + 4 * lane);
        float2 v01 = upk2(pv.x), v23 = upk2(pv.y);
        float s = v01.x + v01.y + v23.x + v23.y;
        float q = v01.x * v01.x + v01.y * v01.y + v23.x * v23.x + v23.y * v23.y;
#pragma unroll
        for (int m = 1; m < 64; m <<= 1) { s += __shfl_xor(s, m); q += __shfl_xor(q, m); }
        float mean = s * (1.0f / HH);
        float var = q * (1.0f / HH) - mean * mean;
        float rstd = rsqrtf(var + 1e-5f);
        float o0 = (v01.x - mean) * rstd * gg.x + bv.x;
        float o1 = (v01.y - mean) * rstd * gg.y + bv.y;
        float o2 = (v23.x - mean) * rstd * gg.z + bv.z;
        float o3 = (v23.y - mean) * rstd * gg.w + bv.w;
        uint2 p;
        p.x = pk2h(o0, o1);
        p.y = pk2h(o2, o3);
        *(uint2*)(stream + base + (size_t)tau * HH + 4 * lane) = p;  // residual = z
        *(uint2*)&Ut[tl][4 * lane] = p;
      }
    }
    __syncthreads();
    // export this half: per h, 32 u32 words (64 tau)
    for (int rep = 0; rep < 8; rep++) {
      int linear = rep * 256 + threadIdx.x;
      int h = linear >> 3, ub = linear & 7;
      unsigned* dst = (unsigned*)(U + ((size_t)h * COLS + col) * KU) + half * 32;
#pragma unroll
      for (int s2 = 0; s2 < 4; s2++) {
        int u = ub + s2 * 8;
        dst[u] = (unsigned)Ut[2 * u][h] | ((unsigned)Ut[2 * u + 1][h] << 16);
      }
    }
  }
}

// ---------------------------------------------------------------------------
// gemmAC: fused chunk-state GEMM + serial combine. Block (h, b):
//   P[n2=64][c=40] = V[h](64x128) @ U[h][b*40+c](128-tau)   (MFMA, f32 acc)
//   then lanes 0..31 scan c=0..39: carry' = w^128*carry + P[:,c], writing the
//   exclusive-prefix carry (fp16) into U[h][b*40+c][128+n2].
// Eliminates the P buffer (42 MB/layer HBM) and the combine kernel.
// ---------------------------------------------------------------------------
__global__ __launch_bounds__(256) void gemmAC_kernel(
    const _Float16* __restrict__ V, _Float16* __restrict__ U,
    const float* __restrict__ WLc) {
  __shared__ float smf[4096];                 // 16384 B
  _Float16* As = (_Float16*)smf;              // 64*72 fp16 = 9216 B
  _Float16* Bs = As + 64 * 72;                // 48*72 fp16 = 6912 B
  float* Ps = smf;                            // alias: 64*49 f32 = 12544 B
  int h = blockIdx.x, b = blockIdx.y;
  int t = threadIdx.x;
  int w = t >> 6, lane = t & 63, lr = lane & 15, quad = lane >> 4;
  f32x4 acc[3];
#pragma unroll
  for (int j = 0; j < 3; j++) acc[j] = (f32x4)(0.0f);

  for (int kt = 0; kt < 128; kt += 64) {
#pragma unroll
    for (int i = 0; i < 2; i++) {            // A: V[h], 64 rows x 64 k
      int idx = t + 256 * i;
      int m = idx >> 3, q = idx & 7;
      *(uint4*)&As[m * 72 + q * 8] =
          *(const uint4*)(V + ((size_t)h * 64 + m) * 128 + kt + q * 8);
    }
#pragma unroll
    for (int i = 0; i < 2; i++) {            // B: U cols b*40..+39, pad to 48
      int idx = t + 256 * i;
      if (idx < 384) {
        int jj = idx >> 3, q = idx & 7;
        uint4 v = make_uint4(0u, 0u, 0u, 0u);
        if (jj < NCH)
          v = *(const uint4*)(U + ((size_t)h * COLS + (size_t)b * NCH + jj) * KU + kt + q * 8);
        *(uint4*)&Bs[jj * 72 + q * 8] = v;
      }
    }
    __syncthreads();
#pragma unroll
    for (int ks = 0; ks < 2; ks++) {
      f16x8 af = *(const f16x8*)&As[(w * 16 + lr) * 72 + ks * 32 + quad * 8];
#pragma unroll
      for (int j = 0; j < 3; j++) {
        f16x8 bf = *(const f16x8*)&Bs[(j * 16 + lr) * 72 + ks * 32 + quad * 8];
        acc[j] = __builtin_amdgcn_mfma_f32_16x16x32_f16(af, bf, acc[j], 0, 0, 0);
      }
    }
    __syncthreads();
  }
  // Stage P (f32) into Ps[n2][49] (stride 49 -> scan reads 2-way/free)
#pragma unroll
  for (int j = 0; j < 3; j++)
#pragma unroll
    for (int r = 0; r < 4; r++)
      Ps[(w * 16 + quad * 4 + r) * 49 + j * 16 + lr] = acc[j][r];
  __syncthreads();

  if (t < 32) {
    int n = t;
    float wre = WLc[h * 64 + 2 * n], wim = WLc[h * 64 + 2 * n + 1];
    float cre = 0.0f, cim = 0.0f;
    _Float16* u = U + ((size_t)h * COLS + (size_t)b * NCH) * KU + 128 + 2 * n;
    for (int c = 0; c < NCH; c++) {
      float vre = Ps[(2 * n) * 49 + c];
      float vim = Ps[(2 * n + 1) * 49 + c];
      *(unsigned*)(u + (size_t)c * KU) = pk2h(cre, cim);
      float nre = fmaf(wre, cre, vre) - wim * cim;
      float nim = fmaf(wre, cim, vim) + wim * cre;
      cre = nre; cim = nim;
    }
  }
}

// ---------------------------------------------------------------------------
// gemmC: per h, Y[t=128][col] = Tc[h](128x192) @ [u; s0](192 x col), fused
// GELU, fp16 out Yt[h][col][t]. 128-col B-tile.
// ---------------------------------------------------------------------------
__global__ __launch_bounds__(256) void gemmC_kernel(
    const _Float16* __restrict__ Tc, const _Float16* __restrict__ U,
    _Float16* __restrict__ Yt) {
  __shared__ _Float16 As[128 * 72];
  __shared__ _Float16 Bs[128 * 72];
  int h = blockIdx.x, c0 = blockIdx.y * 128;
  int t = threadIdx.x;
  int w = t >> 6, lane = t & 63, lr = lane & 15, quad = lane >> 4;
  f32x4 acc[2][8];
#pragma unroll
  for (int i = 0; i < 2; i++)
#pragma unroll
    for (int j = 0; j < 8; j++) acc[i][j] = (f32x4)(0.0f);

  for (int kt = 0; kt < KU; kt += 64) {
#pragma unroll
    for (int i = 0; i < 4; i++) {
      int idx = t + 256 * i;
      int m = idx >> 3, q = idx & 7;
      *(uint4*)&As[m * 72 + q * 8] =
          *(const uint4*)(Tc + ((size_t)h * 128 + m) * KU + kt + q * 8);
    }
#pragma unroll
    for (int i = 0; i < 4; i++) {
      int idx = t + 256 * i;
      int jj = idx >> 3, q = idx & 7;
      *(uint4*)&Bs[jj * 72 + q * 8] =
          *(const uint4*)(U + ((size_t)h * COLS + c0 + jj) * KU + kt + q * 8);
    }
    __syncthreads();
#pragma unroll
    for (int ks = 0; ks < 2; ks++) {
      f16x8 af[2], bf[8];
#pragma unroll
      for (int i = 0; i < 2; i++)
        af[i] = *(const f16x8*)&As[(w * 32 + i * 16 + lr) * 72 + ks * 32 + quad * 8];
#pragma unroll
      for (int j = 0; j < 8; j++)
        bf[j] = *(const f16x8*)&Bs[(j * 16 + lr) * 72 + ks * 32 + quad * 8];
#pragma unroll
      for (int i = 0; i < 2; i++)
#pragma unroll
        for (int j = 0; j < 8; j++)
          acc[i][j] = __builtin_amdgcn_mfma_f32_16x16x32_f16(af[i], bf[j], acc[i][j], 0, 0, 0);
    }
    __syncthreads();
  }
#pragma unroll
  for (int i = 0; i < 2; i++) {
#pragma unroll
    for (int j = 0; j < 8; j++) {
      int tb = w * 32 + i * 16 + quad * 4;
      int colx = c0 + j * 16 + lr;
      f32x4 a = acc[i][j];
      uint2 r;
      r.x = pk2h(fast_gelu(a[0]), fast_gelu(a[1]));
      r.y = pk2h(fast_gelu(a[2]), fast_gelu(a[3]));
      *(uint2*)(Yt + ((size_t)h * COLS + colx) * 128 + tb) = r;
    }
  }
}

// ---------------------------------------------------------------------------
// GLU FFN via fp16 MFMA (unchanged from round 8). A operand read from
// Yt[h][col][t], transposed into LDS As[t][h] (swizzled), all 64 lanes
// writing 4 b32 each. Stream holds z; X = g1*sigmoid(g2) + z in place,
// LDS-staged coalesced epilogue.
// ---------------------------------------------------------------------------
__global__ __launch_bounds__(256) void gemm_glu_mfma(
    const _Float16* __restrict__ Yt, const _Float16* __restrict__ Wt,
    const float* __restrict__ bg, _Float16* __restrict__ Xio) {
  __shared__ uint4 smemq[2304];                 // 36864 B
  _Float16* As = (_Float16*)smemq;              // 128 t x 64 h swizzled, 16384 B
  _Float16* Bs = (_Float16*)smemq + 128 * 64;   // 128 col x 72, 18432 B
  float* gl = (float*)smemq;                    // epilogue alias: 34816 B
  int t = threadIdx.x;
  int col = blockIdx.x;                         // 0..639
  int bI = col / NCH, pt = col % NCH;
  int len = (pt == NCH - 1) ? TAIL : 128;
  size_t row0 = (size_t)bI * LL + (size_t)pt * 128;
  int c0 = blockIdx.y * 64;
  int w = t >> 6, lane = t & 63;
  int lr = lane & 15, quad = lane >> 4;
  int rh = w & 1, ch = w >> 1;
  int oct = lane & 15, hq = lane >> 4;
  int godd = hq & 1;
  int jbase = godd * 4;
  int goct = (oct + (oct >> 3)) & 7;
  f32x4 acc[4][4];
#pragma unroll
  for (int i = 0; i < 4; i++)
#pragma unroll
    for (int j = 0; j < 4; j++) acc[i][j] = (f32x4)(0.0f);

  int jb[4] = {ch * 32, ch * 32 + 16, 64 + ch * 32, 80 + ch * 32};

  for (int kt = 0; kt < HH; kt += 64) {
    // --- A: transpose-stage Yt[kt..kt+63][col][0..127] into As[t][h] ---
#pragma unroll
    for (int p = 0; p < 4; p++) {
      int hl = p * 16 + w * 4 + hq;   // 0..63 (tile-local h)
      uint4 v = *(const uint4*)(Yt + ((size_t)(kt + hl) * COLS + col) * 128 + oct * 8);
      uint4 pv;
      pv.x = __shfl_xor((int)v.x, 16);
      pv.y = __shfl_xor((int)v.y, 16);
      pv.z = __shfl_xor((int)v.z, 16);
      pv.w = __shfl_xor((int)v.w, 16);
      unsigned a0 = godd ? pv.z : v.x;
      unsigned a1 = godd ? pv.w : v.y;
      unsigned b0 = godd ? v.z : pv.x;
      unsigned b1 = godd ? v.w : pv.y;
      unsigned p0 = (a0 & 0xffffu) | (b0 << 16);
      unsigned p1 = (a0 >> 16) | (b0 & 0xffff0000u);
      unsigned p2 = (a1 & 0xffffu) | (b1 << 16);
      unsigned p3 = (a1 >> 16) | (b1 & 0xffff0000u);
      int soc = (hl >> 3) ^ goct;
      char* basep = (char*)As + oct * 1024 + (hl & 6) * 2;
      { int j = jbase;     *(unsigned*)(basep + j * 128 + ((soc ^ j) * 16)) = p0; }
      { int j = jbase + 1; *(unsigned*)(basep + j * 128 + ((soc ^ j) * 16)) = p1; }
      { int j = jbase + 2; *(unsigned*)(basep + j * 128 + ((soc ^ j) * 16)) = p2; }
      { int j = jbase + 3; *(unsigned*)(basep + j * 128 + ((soc ^ j) * 16)) = p3; }
    }
    // --- B: Wt staging (padded stride 72) ---
#pragma unroll
    for (int i = 0; i < 4; i++) {
      int idx = t + 256 * i;
      int jj = idx >> 3, q = idx & 7;
      int colw = (jj < 64) ? (c0 + jj) : (192 + c0 + jj);
      *(uint4*)&Bs[jj * 72 + q * 8] =
          *(const uint4*)(Wt + (size_t)colw * HH + kt + q * 8);
    }
    __syncthreads();
#pragma unroll
    for (int ks = 0; ks < 2; ks++) {
      f16x8 af[4], bf[4];
#pragma unroll
      for (int i = 0; i < 4; i++) {
        int tt = rh * 64 + i * 16 + lr;
        int ttg = tt >> 3;
        int so = (ks * 4 + quad) ^ (tt & 7) ^ ((ttg + (ttg >> 3)) & 7);
        af[i] = *(const f16x8*)((const char*)As + tt * 128 + so * 16);
      }
#pragma unroll
      for (int j = 0; j < 4; j++)
        bf[j] = *(const f16x8*)&Bs[(jb[j] + lr) * 72 + ks * 32 + quad * 8];
#pragma unroll
      for (int i = 0; i < 4; i++)
#pragma unroll
        for (int j = 0; j < 4; j++)
          acc[i][j] = __builtin_amdgcn_mfma_f32_16x16x32_f16(af[i], bf[j], acc[i][j], 0, 0, 0);
    }
    __syncthreads();
  }

  // Stage g = g1*sigmoid(g2) into gl[128][68] (f32)
#pragma unroll
  for (int i = 0; i < 4; i++) {
#pragma unroll
    for (int r = 0; r < 4; r++) {
      int rowl = rh * 64 + i * 16 + quad * 4 + r;
#pragma unroll
      for (int jp = 0; jp < 2; jp++) {
        int hl = ch * 32 + jp * 16 + lr;
        int h = c0 + hl;
        float g1 = acc[i][jp][r] + bg[h];
        float g2 = acc[i][jp + 2][r] + bg[256 + h];
        float sig = __builtin_amdgcn_rcpf(1.0f + __expf(-g2));
        gl[rowl * 68 + hl] = g1 * sig;
      }
    }
  }
  __syncthreads();

  // Coalesced residual-add pass (guard tail rows)
#pragma unroll
  for (int rep = 0; rep < 4; rep++) {
    int lin = rep * 256 + t;
    int rowl = lin >> 3, hc = lin & 7;
    if (rowl < len) {
      size_t row = row0 + rowl;
      int hb = c0 + hc * 8;
      uint4 zv = *(const uint4*)(Xio + row * HH + hb);
      float2 z01 = upk2(zv.x), z23 = upk2(zv.y), z45 = upk2(zv.z), z67 = upk2(zv.w);
      const float* gp = &gl[rowl * 68 + hc * 8];
      uint4 r;
      r.x = pk2h(gp[0] + z01.x, gp[1] + z01.y);
      r.y = pk2h(gp[2] + z23.x, gp[3] + z23.y);
      r.z = pk2h(gp[4] + z45.x, gp[5] + z45.y);
      r.w = pk2h(gp[6] + z67.x, gp[7] + z67.y);
      *(uint4*)(Xio + row * HH + hb) = r;
    }
  }
}

// ---------------------------------------------------------------------------
extern "C" void kernel_launch(void* const* d_in, const int* in_sizes, int n_in,
                              void* d_out, int out_size, void* d_ws, size_t ws_size,
                              hipStream_t stream) {
  const float* x      = (const float*)d_in[0];
  const float* Win    = (const float*)d_in[1];
  const float* bin    = (const float*)d_in[2];
  const float* ln_g   = (const float*)d_in[3];
  const float* ln_b   = (const float*)d_in[4];
  const float* log_dt = (const float*)d_in[5];
  const float* logA   = (const float*)d_in[6];
  const float* A_im   = (const float*)d_in[7];
  const float* Cp     = (const float*)d_in[8];
  const float* Dv     = (const float*)d_in[9];
  const float* Wglu   = (const float*)d_in[10];
  const float* bglu   = (const float*)d_in[11];
  const float* fn_g   = (const float*)d_in[12];
  const float* fn_b   = (const float*)d_in[13];
  float* out = (float*)d_out;
  float* ws = (float*)d_ws;

  // Workspace layout (float units; unchanged)
  _Float16* Xs = (_Float16*)ws;                        // fp16 token stream
  float* Pf = ws + (size_t)NROWS * HH;                 // Yt region
  _Float16* Tc = (_Float16*)(Pf + (size_t)HH * COLS * 64);
  _Float16* V  = Tc + (size_t)HH * 128 * KU;
  _Float16* U  = V + (size_t)HH * 64 * 128;
  _Float16* Wt = U + (size_t)HH * COLS * KU;
  float* WLc = (float*)(Wt + (size_t)NLAYER * 512 * HH);
  _Float16* Yt  = (_Float16*)Pf;                       // fp16 [h][col][128]

  wt_kernel<<<(NLAYER * 512) / 256, 256, 0, stream>>>(Wglu, Wt);
  proj_kernel<<<2048, 256, 0, stream>>>(x, Win, bin, Xs);

  for (int l = 0; l < NLAYER; l++) {
    paramT_kernel<<<HH, 128, 0, stream>>>(log_dt, logA, A_im, Cp, Dv, l, Tc, V, WLc);
    lnU_kernel<<<COLS, 256, 0, stream>>>(Xs, U, ln_g + l * HH, ln_b + l * HH);
    gemmAC_kernel<<<dim3(HH, BB), 256, 0, stream>>>(V, U, WLc);
    gemmC_kernel<<<dim3(HH, COLS / 128), 256, 0, stream>>>(Tc, U, Yt);
    gemm_glu_mfma<<<dim3(COLS, 4), 256, 0, stream>>>(
        Yt, Wt + (size_t)l * 512 * HH, bglu + (size_t)l * 2 * HH, Xs);
  }
  ln_kernel<<<NROWS / 4, 256, 0, stream>>>(Xs, out, fn_g, fn_b);
}

// Round 11
// 845.709 us; speedup vs baseline: 2.0003x; 1.0352x over previous
//
#include <hip/hip_runtime.h>
#include <math.h>

// Problem constants
#define BB 16
#define LL 5000
#define DIN 12
#define HH 256
#define NN 32
#define NLAYER 4
#define LC 128               // chunk length (last chunk per batch row = 8)
#define NCH 40               // chunks per batch row (39*128 + 8 = 5000)
#define TAIL 8               // length of last chunk
#define COLS (BB*NCH)        // 640 chunk-columns; col = b*40 + pt
#define NROWS (BB*LL)        // 80000 token rows
#define KU 192               // Ubig inner dim: 128 (tau) + 64 (state re/im)

typedef __attribute__((ext_vector_type(8))) _Float16 f16x8;
typedef __attribute__((ext_vector_type(4))) float f32x4;

// fast tanh-GELU (matches jax.nn.gelu approximate): a*sigmoid(2*inner)
__device__ __forceinline__ float fast_gelu(float a) {
  float z = fmaf(0.0713548163f * a, a * a, 1.5957691216f * a);
  float e = __expf(-z);
  return a * __builtin_amdgcn_rcpf(1.0f + e);
}

__device__ __forceinline__ unsigned pk2h(float a, float b) {
  union { _Float16 h[2]; unsigned u; } x;
  x.h[0] = (_Float16)a; x.h[1] = (_Float16)b;
  return x.u;
}

__device__ __forceinline__ float2 upk2(unsigned u) {
  union { unsigned u; _Float16 h[2]; } x;
  x.u = u;
  return make_float2((float)x.h[0], (float)x.h[1]);
}

// ---------------------------------------------------------------------------
// Per-layer precompute (LC=128):
//   Tc[h][t][k] : k<128 -> Toeplitz K[t-k] (+D diag); k>=128 -> Bnd[t][n2]
//   V[h][n2][tau] = {Re,Im}(w^{127-tau});  WLc[h][n2] = w^128
// ---------------------------------------------------------------------------
__global__ __launch_bounds__(128) void paramT_kernel(
    const float* __restrict__ log_dt, const float* __restrict__ logA_re,
    const float* __restrict__ A_im, const float* __restrict__ Cp,
    const float* __restrict__ Dv, int l,
    _Float16* __restrict__ Tc, _Float16* __restrict__ V, float* __restrict__ WLc) {
  int h = blockIdx.x;
  int t = threadIdx.x;           // 0..127
  __shared__ float s_are[NN], s_aim[NN], s_cre[NN], s_cim[NN];
  __shared__ float s_K[128];
  if (t < NN) {
    int n = t;
    int idx = (l * HH + h) * NN + n;
    float dt = expf(log_dt[l * HH + h]);
    float Are = -expf(logA_re[idx]);
    float Aim = A_im[idx];
    float are = Are * dt, aim = Aim * dt;
    float e = expf(are);
    float wre = e * cosf(aim), wim = e * sinf(aim);
    float cr = Cp[2 * idx], ci = Cp[2 * idx + 1];
    float nre = wre - 1.0f, nim = wim;
    float tre = cr * nre - ci * nim;
    float tim = cr * nim + ci * nre;
    float inv = 1.0f / (Are * Are + Aim * Aim);
    s_are[n] = are; s_aim[n] = aim;
    s_cre[n] = 2.0f * (tre * Are + tim * Aim) * inv;
    s_cim[n] = 2.0f * (tim * Are - tre * Aim) * inv;
    float eL = expf(128.0f * are);
    float ang = 128.0f * aim;
    WLc[h * 64 + 2 * n] = eL * cosf(ang);
    WLc[h * 64 + 2 * n + 1] = eL * sinf(ang);
  }
  __syncthreads();
  {
    float ksum = 0.0f;
    unsigned* brow = (unsigned*)(Tc + ((size_t)h * 128 + t) * KU + 128);
    for (int n = 0; n < NN; n++) {
      float are = s_are[n], aim = s_aim[n];
      float cre = s_cre[n], cim = s_cim[n];
      float ft = (float)t;
      float E = expf(are * ft);
      float a = aim * ft;
      float wtre = E * cosf(a), wtim = E * sinf(a);        // w^t
      ksum = fmaf(cre, wtre, ksum);
      ksum = fmaf(-cim, wtim, ksum);
      float ew = expf(are);
      float wre = ew * cosf(aim), wim = ew * sinf(aim);    // w
      float wpre = wtre * wre - wtim * wim;                // w^{t+1}
      float wpim = wtre * wim + wtim * wre;
      float bre = cre * wpre - cim * wpim;
      float bim = -(cre * wpim + cim * wpre);
      brow[n] = pk2h(bre, bim);
      float fk = (float)(127 - t);
      float E2 = expf(are * fk);
      float a2 = aim * fk;
      V[((size_t)h * 64 + 2 * n) * 128 + t] = (_Float16)(E2 * cosf(a2));
      V[((size_t)h * 64 + 2 * n + 1) * 128 + t] = (_Float16)(E2 * sinf(a2));
    }
    s_K[t] = ksum;
  }
  __syncthreads();
  float D = Dv[l * HH + h];
  unsigned* row = (unsigned*)(Tc + ((size_t)h * 128 + t) * KU);
  for (int q = 0; q < 64; q++) {
    float v0 = 0.0f, v1 = 0.0f;
    int d0 = t - 2 * q;
    int d1 = d0 - 1;
    if (d0 >= 0) v0 = s_K[d0] + (d0 == 0 ? D : 0.0f);
    if (d1 >= 0) v1 = s_K[d1] + (d1 == 0 ? D : 0.0f);
    row[q] = pk2h(v0, v1);
  }
}

// ---------------------------------------------------------------------------
// W_glu transpose+cast to fp16: Wt[l][col(512)][k(256)]
// ---------------------------------------------------------------------------
__global__ __launch_bounds__(256) void wt_kernel(
    const float* __restrict__ W, _Float16* __restrict__ Wt) {
  int gid = blockIdx.x * 256 + threadIdx.x;
  int l = gid >> 9, col = gid & 511;
  const float* w = W + (size_t)l * HH * 512 + col;
  _Float16* o = Wt + (size_t)gid * HH;
  for (int k = 0; k < HH; k++) o[k] = (_Float16)(w[(size_t)k * 512]);
}

// ---------------------------------------------------------------------------
// Input projection -> fp16 stream.
// ---------------------------------------------------------------------------
__global__ __launch_bounds__(256) void proj_kernel(
    const float* __restrict__ x, const float* __restrict__ Win,
    const float* __restrict__ bin, _Float16* __restrict__ X) {
  int tp = threadIdx.x & 127, rs = threadIdx.x >> 7;
  int h0 = 2 * tp;
  float w0[DIN], w1[DIN];
#pragma unroll
  for (int k = 0; k < DIN; k++) {
    w0[k] = Win[k * HH + h0];
    w1[k] = Win[k * HH + h0 + 1];
  }
  float b0 = bin[h0], b1 = bin[h0 + 1];
  for (int row = blockIdx.x * 2 + rs; row < NROWS; row += gridDim.x * 2) {
    float a0 = b0, a1 = b1;
#pragma unroll
    for (int k = 0; k < DIN; k++) {
      float xv = x[(size_t)row * DIN + k];
      a0 = fmaf(xv, w0[k], a0);
      a1 = fmaf(xv, w1[k], a1);
    }
    *(unsigned*)(X + (size_t)row * HH + h0) = pk2h(a0, a1);
  }
}

// ---------------------------------------------------------------------------
// Final LayerNorm: fp16 stream in, f32 out.
// ---------------------------------------------------------------------------
__global__ __launch_bounds__(256) void ln_kernel(
    const _Float16* __restrict__ in, float* __restrict__ out,
    const float* __restrict__ g, const float* __restrict__ b) {
  int wave = threadIdx.x >> 6, lane = threadIdx.x & 63;
  int row = blockIdx.x * 4 + wave;
  uint2 pv = *(const uint2*)(in + (size_t)row * HH + 4 * lane);
  float2 v01 = upk2(pv.x), v23 = upk2(pv.y);
  float s = v01.x + v01.y + v23.x + v23.y;
  float q = v01.x * v01.x + v01.y * v01.y + v23.x * v23.x + v23.y * v23.y;
#pragma unroll
  for (int m = 1; m < 64; m <<= 1) { s += __shfl_xor(s, m); q += __shfl_xor(q, m); }
  float mean = s * (1.0f / HH);
  float var = q * (1.0f / HH) - mean * mean;
  float rstd = rsqrtf(var + 1e-5f);
  float4 gg = ((const float4*)g)[lane];
  float4 bb = ((const float4*)b)[lane];
  float4 o;
  o.x = (v01.x - mean) * rstd * gg.x + bb.x;
  o.y = (v01.y - mean) * rstd * gg.y + bb.y;
  o.z = (v23.x - mean) * rstd * gg.z + bb.z;
  o.w = (v23.y - mean) * rstd * gg.w + bb.w;
  ((float4*)(out + (size_t)row * HH))[lane] = o;
}

// ---------------------------------------------------------------------------
// Per-layer LN (in place on fp16 stream: x -> z) + transposed fp16 export
// U[h][col][tau]. Ut split into two 64-tau halves (33 KB LDS -> 4 blocks/CU).
// ---------------------------------------------------------------------------
__global__ __launch_bounds__(256) void lnU_kernel(
    _Float16* __restrict__ stream, _Float16* __restrict__ U,
    const float* __restrict__ g, const float* __restrict__ b) {
  __shared__ unsigned short Ut[64][260];   // [tau-local][h], padded stride
  int col = blockIdx.x;
  int bI = col / NCH, cI = col % NCH;
  int len = (cI == NCH - 1) ? TAIL : 128;
  int wave = threadIdx.x >> 6, lane = threadIdx.x & 63;
  float4 gg = ((const float4*)g)[lane];
  float4 bv = ((const float4*)b)[lane];
  size_t base = ((size_t)bI * LL + (size_t)cI * 128) * HH;
#pragma unroll
  for (int half = 0; half < 2; half++) {
    if (half) __syncthreads();           // previous export done before overwrite
    int t0 = half * 64;
    int lenh = len - t0;
    lenh = lenh < 0 ? 0 : (lenh > 64 ? 64 : lenh);
    for (int idx = threadIdx.x; idx < (64 - lenh) * 260; idx += 256) {
      int r = idx / 260;
      Ut[lenh + r][idx - r * 260] = 0;
    }
    for (int it = 0; it < 16; it++) {
      int tl = it * 4 + wave;
      if (tl < lenh) {
        int tau = t0 + tl;
        uint2 pv = *(const uint2*)(stream + base + (size_t)tau * HH + 4 * lane);
        float2 v01 = upk2(pv.x), v23 = upk2(pv.y);
        float s = v01.x + v01.y + v23.x + v23.y;
        float q = v01.x * v01.x + v01.y * v01.y + v23.x * v23.x + v23.y * v23.y;
#pragma unroll
        for (int m = 1; m < 64; m <<= 1) { s += __shfl_xor(s, m); q += __shfl_xor(q, m); }
        float mean = s * (1.0f / HH);
        float var = q * (1.0f / HH) - mean * mean;
        float rstd = rsqrtf(var + 1e-5f);
        float o0 = (v01.x - mean) * rstd * gg.x + bv.x;
        float o1 = (v01.y - mean) * rstd * gg.y + bv.y;
        float o2 = (v23.x - mean) * rstd * gg.z + bv.z;
        float o3 = (v23.y - mean) * rstd * gg.w + bv.w;
        uint2 p;
        p.x = pk2h(o0, o1);
        p.y = pk2h(o2, o3);
        *(uint2*)(stream + base + (size_t)tau * HH + 4 * lane) = p;  // residual = z
        *(uint2*)&Ut[tl][4 * lane] = p;
      }
    }
    __syncthreads();
    // export this half: per h, 32 u32 words (64 tau)
    for (int rep = 0; rep < 8; rep++) {
      int linear = rep * 256 + threadIdx.x;
      int h = linear >> 3, ub = linear & 7;
      unsigned* dst = (unsigned*)(U + ((size_t)h * COLS + col) * KU) + half * 32;
#pragma unroll
      for (int s2 = 0; s2 < 4; s2++) {
        int u = ub + s2 * 8;
        dst[u] = (unsigned)Ut[2 * u][h] | ((unsigned)Ut[2 * u + 1][h] << 16);
      }
    }
  }
}

// ---------------------------------------------------------------------------
// gemmACC: fully fused chunk-state GEMM + serial combine + output GEMM.
// Block (h, b):
//   1) Stage [u_tau] (40 cols pad 48, k=0..127) ONCE into Bs[48][200].
//   2) P[n2=64][c] = V[h](64x128) @ u_tau (MFMA), staged to LDS Ps[64][49].
//   3) Lanes 0..31 scan c=0..39 (carry' = w^128*carry + P[:,c]), writing the
//      exclusive-prefix carry (fp16) into Bs[c][128+n2] — state stays in LDS.
//   4) Y[t=128][c] = Tc[h](128x192) @ Bs[c][0..191], fused GELU -> Yt.
// Eliminates gemmC's U re-read (63 MB/layer) + U-state write (21 MB/layer).
// ---------------------------------------------------------------------------
__global__ __launch_bounds__(256) void gemmACC_kernel(
    const _Float16* __restrict__ V, const _Float16* __restrict__ Tc,
    const _Float16* __restrict__ U, const float* __restrict__ WLc,
    _Float16* __restrict__ Yt) {
  __shared__ uint4 smemq[2352];               // 37632 B
  _Float16* As = (_Float16*)smemq;            // 128*72 fp16 = 18432 B (V/Tc tiles; Ps alias)
  _Float16* Bs = As + 128 * 72;               // 48*200 fp16 = 19200 B ([u_tau ; s0])
  float* Ps = (float*)As;                     // 64*49 f32 = 12544 B
  int h = blockIdx.x, b = blockIdx.y;
  int t = threadIdx.x;
  int w = t >> 6, lane = t & 63, lr = lane & 15, quad = lane >> 4;

  // 1) Stage B tau: 48 cols x 128 k (pad cols 40..47 zero). 16B per lane.
#pragma unroll
  for (int i = 0; i < 3; i++) {
    int idx = t + 256 * i;                    // 0..767
    int jj = idx >> 4, q = idx & 15;
    uint4 v = make_uint4(0u, 0u, 0u, 0u);
    if (jj < NCH)
      v = *(const uint4*)(U + ((size_t)h * COLS + (size_t)b * NCH + jj) * KU + q * 8);
    *(uint4*)&Bs[jj * 200 + q * 8] = v;
  }

  // 2) gemmA: P = V[h] @ u_tau
  f32x4 accA[3];
#pragma unroll
  for (int j = 0; j < 3; j++) accA[j] = (f32x4)(0.0f);
  for (int kt = 0; kt < 2; kt++) {
#pragma unroll
    for (int i = 0; i < 2; i++) {             // V: 64 rows x 64 k
      int idx = t + 256 * i;
      int m = idx >> 3, q = idx & 7;
      *(uint4*)&As[m * 72 + q * 8] =
          *(const uint4*)(V + ((size_t)h * 64 + m) * 128 + kt * 64 + q * 8);
    }
    __syncthreads();
#pragma unroll
    for (int ks = 0; ks < 2; ks++) {
      f16x8 af = *(const f16x8*)&As[(w * 16 + lr) * 72 + ks * 32 + quad * 8];
#pragma unroll
      for (int j = 0; j < 3; j++) {
        f16x8 bf = *(const f16x8*)&Bs[(j * 16 + lr) * 200 + kt * 64 + ks * 32 + quad * 8];
        accA[j] = __builtin_amdgcn_mfma_f32_16x16x32_f16(af, bf, accA[j], 0, 0, 0);
      }
    }
    __syncthreads();
  }
  // P -> Ps[n2][49] (stride 49 -> scan reads 2-way/free)
#pragma unroll
  for (int j = 0; j < 3; j++)
#pragma unroll
    for (int r = 0; r < 4; r++)
      Ps[(w * 16 + quad * 4 + r) * 49 + j * 16 + lr] = accA[j][r];
  __syncthreads();

  // 3) scan -> state into Bs[c][128+n2] (fp16); pad cols zeroed
  if (t < 32) {
    int n = t;
    float wre = WLc[h * 64 + 2 * n], wim = WLc[h * 64 + 2 * n + 1];
    float cre = 0.0f, cim = 0.0f;
    for (int c = 0; c < NCH; c++) {
      float vre = Ps[(2 * n) * 49 + c];
      float vim = Ps[(2 * n + 1) * 49 + c];
      *(unsigned*)&Bs[c * 200 + 128 + 2 * n] = pk2h(cre, cim);
      float nre = fmaf(wre, cre, vre) - wim * cim;
      float nim = fmaf(wre, cim, vim) + wim * cre;
      cre = nre; cim = nim;
    }
#pragma unroll
    for (int c = NCH; c < 48; c++)
      *(unsigned*)&Bs[c * 200 + 128 + 2 * n] = 0u;
  }
  __syncthreads();

  // 4) gemmC: Y = Tc[h] @ [u_tau; s0], fused GELU -> Yt
  f32x4 accC[2][3];
#pragma unroll
  for (int i = 0; i < 2; i++)
#pragma unroll
    for (int j = 0; j < 3; j++) accC[i][j] = (f32x4)(0.0f);
  for (int kt = 0; kt < 3; kt++) {
#pragma unroll
    for (int i = 0; i < 4; i++) {             // Tc: 128 rows x 64 k
      int idx = t + 256 * i;
      int m = idx >> 3, q = idx & 7;
      *(uint4*)&As[m * 72 + q * 8] =
          *(const uint4*)(Tc + ((size_t)h * 128 + m) * KU + kt * 64 + q * 8);
    }
    __syncthreads();
#pragma unroll
    for (int ks = 0; ks < 2; ks++) {
      f16x8 af[2], bf[3];
#pragma unroll
      for (int i = 0; i < 2; i++)
        af[i] = *(const f16x8*)&As[(w * 32 + i * 16 + lr) * 72 + ks * 32 + quad * 8];
#pragma unroll
      for (int j = 0; j < 3; j++)
        bf[j] = *(const f16x8*)&Bs[(j * 16 + lr) * 200 + kt * 64 + ks * 32 + quad * 8];
#pragma unroll
      for (int i = 0; i < 2; i++)
#pragma unroll
        for (int j = 0; j < 3; j++)
          accC[i][j] = __builtin_amdgcn_mfma_f32_16x16x32_f16(af[i], bf[j], accC[i][j], 0, 0, 0);
    }
    __syncthreads();
  }
#pragma unroll
  for (int i = 0; i < 2; i++) {
#pragma unroll
    for (int j = 0; j < 3; j++) {
      int tb = w * 32 + i * 16 + quad * 4;
      int cl = j * 16 + lr;
      if (cl < NCH) {
        f32x4 a = accC[i][j];
        uint2 r;
        r.x = pk2h(fast_gelu(a[0]), fast_gelu(a[1]));
        r.y = pk2h(fast_gelu(a[2]), fast_gelu(a[3]));
        *(uint2*)(Yt + ((size_t)h * COLS + (size_t)b * NCH + cl) * 128 + tb) = r;
      }
    }
  }
}

// ---------------------------------------------------------------------------
// GLU FFN via fp16 MFMA (unchanged from round 8/10). A operand read from
// Yt[h][col][t], transposed into LDS As[t][h] (swizzled), all 64 lanes
// writing 4 b32 each. Stream holds z; X = g1*sigmoid(g2) + z in place,
// LDS-staged coalesced epilogue.
// ---------------------------------------------------------------------------
__global__ __launch_bounds__(256) void gemm_glu_mfma(
    const _Float16* __restrict__ Yt, const _Float16* __restrict__ Wt,
    const float* __restrict__ bg, _Float16* __restrict__ Xio) {
  __shared__ uint4 smemq[2304];                 // 36864 B
  _Float16* As = (_Float16*)smemq;              // 128 t x 64 h swizzled, 16384 B
  _Float16* Bs = (_Float16*)smemq + 128 * 64;   // 128 col x 72, 18432 B
  float* gl = (float*)smemq;                    // epilogue alias: 34816 B
  int t = threadIdx.x;
  int col = blockIdx.x;                         // 0..639
  int bI = col / NCH, pt = col % NCH;
  int len = (pt == NCH - 1) ? TAIL : 128;
  size_t row0 = (size_t)bI * LL + (size_t)pt * 128;
  int c0 = blockIdx.y * 64;
  int w = t >> 6, lane = t & 63;
  int lr = lane & 15, quad = lane >> 4;
  int rh = w & 1, ch = w >> 1;
  int oct = lane & 15, hq = lane >> 4;
  int godd = hq & 1;
  int jbase = godd * 4;
  int goct = (oct + (oct >> 3)) & 7;
  f32x4 acc[4][4];
#pragma unroll
  for (int i = 0; i < 4; i++)
#pragma unroll
    for (int j = 0; j < 4; j++) acc[i][j] = (f32x4)(0.0f);

  int jb[4] = {ch * 32, ch * 32 + 16, 64 + ch * 32, 80 + ch * 32};

  for (int kt = 0; kt < HH; kt += 64) {
    // --- A: transpose-stage Yt[kt..kt+63][col][0..127] into As[t][h] ---
#pragma unroll
    for (int p = 0; p < 4; p++) {
      int hl = p * 16 + w * 4 + hq;   // 0..63 (tile-local h)
      uint4 v = *(const uint4*)(Yt + ((size_t)(kt + hl) * COLS + col) * 128 + oct * 8);
      uint4 pv;
      pv.x = __shfl_xor((int)v.x, 16);
      pv.y = __shfl_xor((int)v.y, 16);
      pv.z = __shfl_xor((int)v.z, 16);
      pv.w = __shfl_xor((int)v.w, 16);
      unsigned a0 = godd ? pv.z : v.x;
      unsigned a1 = godd ? pv.w : v.y;
      unsigned b0 = godd ? v.z : pv.x;
      unsigned b1 = godd ? v.w : pv.y;
      unsigned p0 = (a0 & 0xffffu) | (b0 << 16);
      unsigned p1 = (a0 >> 16) | (b0 & 0xffff0000u);
      unsigned p2 = (a1 & 0xffffu) | (b1 << 16);
      unsigned p3 = (a1 >> 16) | (b1 & 0xffff0000u);
      int soc = (hl >> 3) ^ goct;
      char* basep = (char*)As + oct * 1024 + (hl & 6) * 2;
      { int j = jbase;     *(unsigned*)(basep + j * 128 + ((soc ^ j) * 16)) = p0; }
      { int j = jbase + 1; *(unsigned*)(basep + j * 128 + ((soc ^ j) * 16)) = p1; }
      { int j = jbase + 2; *(unsigned*)(basep + j * 128 + ((soc ^ j) * 16)) = p2; }
      { int j = jbase + 3; *(unsigned*)(basep + j * 128 + ((soc ^ j) * 16)) = p3; }
    }
    // --- B: Wt staging (padded stride 72) ---
#pragma unroll
    for (int i = 0; i < 4; i++) {
      int idx = t + 256 * i;
      int jj = idx >> 3, q = idx & 7;
      int colw = (jj < 64) ? (c0 + jj) : (192 + c0 + jj);
      *(uint4*)&Bs[jj * 72 + q * 8] =
          *(const uint4*)(Wt + (size_t)colw * HH + kt + q * 8);
    }
    __syncthreads();
#pragma unroll
    for (int ks = 0; ks < 2; ks++) {
      f16x8 af[4], bf[4];
#pragma unroll
      for (int i = 0; i < 4; i++) {
        int tt = rh * 64 + i * 16 + lr;
        int ttg = tt >> 3;
        int so = (ks * 4 + quad) ^ (tt & 7) ^ ((ttg + (ttg >> 3)) & 7);
        af[i] = *(const f16x8*)((const char*)As + tt * 128 + so * 16);
      }
#pragma unroll
      for (int j = 0; j < 4; j++)
        bf[j] = *(const f16x8*)&Bs[(jb[j] + lr) * 72 + ks * 32 + quad * 8];
#pragma unroll
      for (int i = 0; i < 4; i++)
#pragma unroll
        for (int j = 0; j < 4; j++)
          acc[i][j] = __builtin_amdgcn_mfma_f32_16x16x32_f16(af[i], bf[j], acc[i][j], 0, 0, 0);
    }
    __syncthreads();
  }

  // Stage g = g1*sigmoid(g2) into gl[128][68] (f32)
#pragma unroll
  for (int i = 0; i < 4; i++) {
#pragma unroll
    for (int r = 0; r < 4; r++) {
      int rowl = rh * 64 + i * 16 + quad * 4 + r;
#pragma unroll
      for (int jp = 0; jp < 2; jp++) {
        int hl = ch * 32 + jp * 16 + lr;
        int h = c0 + hl;
        float g1 = acc[i][jp][r] + bg[h];
        float g2 = acc[i][jp + 2][r] + bg[256 + h];
        float sig = __builtin_amdgcn_rcpf(1.0f + __expf(-g2));
        gl[rowl * 68 + hl] = g1 * sig;
      }
    }
  }
  __syncthreads();

  // Coalesced residual-add pass (guard tail rows)
#pragma unroll
  for (int rep = 0; rep < 4; rep++) {
    int lin = rep * 256 + t;
    int rowl = lin >> 3, hc = lin & 7;
    if (rowl < len) {
      size_t row = row0 + rowl;
      int hb = c0 + hc * 8;
      uint4 zv = *(const uint4*)(Xio + row * HH + hb);
      float2 z01 = upk2(zv.x), z23 = upk2(zv.y), z45 = upk2(zv.z), z67 = upk2(zv.w);
      const float* gp = &gl[rowl * 68 + hc * 8];
      uint4 r;
      r.x = pk2h(gp[0] + z01.x, gp[1] + z01.y);
      r.y = pk2h(gp[2] + z23.x, gp[3] + z23.y);
      r.z = pk2h(gp[4] + z45.x, gp[5] + z45.y);
      r.w = pk2h(gp[6] + z67.x, gp[7] + z67.y);
      *(uint4*)(Xio + row * HH + hb) = r;
    }
  }
}

// ---------------------------------------------------------------------------
extern "C" void kernel_launch(void* const* d_in, const int* in_sizes, int n_in,
                              void* d_out, int out_size, void* d_ws, size_t ws_size,
                              hipStream_t stream) {
  const float* x      = (const float*)d_in[0];
  const float* Win    = (const float*)d_in[1];
  const float* bin    = (const float*)d_in[2];
  const float* ln_g   = (const float*)d_in[3];
  const float* ln_b   = (const float*)d_in[4];
  const float* log_dt = (const float*)d_in[5];
  const float* logA   = (const float*)d_in[6];
  const float* A_im   = (const float*)d_in[7];
  const float* Cp     = (const float*)d_in[8];
  const float* Dv     = (const float*)d_in[9];
  const float* Wglu   = (const float*)d_in[10];
  const float* bglu   = (const float*)d_in[11];
  const float* fn_g   = (const float*)d_in[12];
  const float* fn_b   = (const float*)d_in[13];
  float* out = (float*)d_out;
  float* ws = (float*)d_ws;

  // Workspace layout (float units; unchanged)
  _Float16* Xs = (_Float16*)ws;                        // fp16 token stream
  float* Pf = ws + (size_t)NROWS * HH;                 // Yt region
  _Float16* Tc = (_Float16*)(Pf + (size_t)HH * COLS * 64);
  _Float16* V  = Tc + (size_t)HH * 128 * KU;
  _Float16* U  = V + (size_t)HH * 64 * 128;
  _Float16* Wt = U + (size_t)HH * COLS * KU;
  float* WLc = (float*)(Wt + (size_t)NLAYER * 512 * HH);
  _Float16* Yt  = (_Float16*)Pf;                       // fp16 [h][col][128]

  wt_kernel<<<(NLAYER * 512) / 256, 256, 0, stream>>>(Wglu, Wt);
  proj_kernel<<<2048, 256, 0, stream>>>(x, Win, bin, Xs);

  for (int l = 0; l < NLAYER; l++) {
    paramT_kernel<<<HH, 128, 0, stream>>>(log_dt, logA, A_im, Cp, Dv, l, Tc, V, WLc);
    lnU_kernel<<<COLS, 256, 0, stream>>>(Xs, U, ln_g + l * HH, ln_b + l * HH);
    gemmACC_kernel<<<dim3(HH, BB), 256, 0, stream>>>(V, Tc, U, WLc, Yt);
    gemm_glu_mfma<<<dim3(COLS, 4), 256, 0, stream>>>(
        Yt, Wt + (size_t)l * 512 * HH, bglu + (size_t)l * 2 * HH, Xs);
  }
  ln_kernel<<<NROWS / 4, 256, 0, stream>>>(Xs, out, fn_g, fn_b);
}